// Round 1
// 1959.902 us; speedup vs baseline: 1.9588x; 1.9588x over previous
//
#include <hip/hip_runtime.h>
#include <stdint.h>

// ---------------------------------------------------------------------------
// GatedLinearAttention (b=4, T=2048, D=2048, H=8, dk=128, dv=256, CHUNK=128)
// Round: dv-split scan. The exact recurrence is parallel across dv columns:
//   S_t[:,j] = e^{gk_t} (.) S_{t-1}[:,j] + k_t^T v_t[j]
// so split dv=256 into 8 slices of 32 -> 256 blocks = 1 per CU (was 32 blocks,
// Occupancy 6%). LayerNorm needs all 256 dv -> scan emits o (fp16) + per-slice
// fp32 partial sum/sumsq; ln_gate combines, normalizes, gates, and rewrites
// o fp16 -> OG bf16 IN PLACE (same element size/layout).
//
// ws layout (112.5 MiB):
//   QK f32 [0,64Mi)      [q | k/16] fp32 [8192][2048]; reused as final-C
//   V bf16 [64Mi,96Mi)   v [8192][2048]
//   WtA    [96Mi,104Mi)  weight^T hi-plane bf16 (idle during scan ->
//                        Psum/Pss fp32 partials live at [96Mi,+4Mi) then)
//   WtB    [104Mi,112Mi) weight^T lo-plane
//   xg1    [112Mi,+512K) x@Wkg1 fp32
// d_out scratch: G bf16 [0,32Mi); o fp16 -> OG bf16 [32Mi,64Mi); final C last.
// ---------------------------------------------------------------------------

typedef unsigned short u16;
typedef unsigned int u32;
typedef __bf16 bf16x8 __attribute__((ext_vector_type(8)));
typedef float f32x4 __attribute__((ext_vector_type(4)));

__device__ __forceinline__ u16 f2bf(float f) {
  u32 u = __float_as_uint(f);
  u32 r = (u + 0x7fffu + ((u >> 16) & 1u)) >> 16;   // RNE
  return (u16)r;
}
__device__ __forceinline__ float bf2f(u16 s) {
  return __uint_as_float(((u32)s) << 16);
}
__device__ __forceinline__ u16 f2h(float f) {
  _Float16 h = (_Float16)f;                          // RNE fp32->fp16
  return __builtin_bit_cast(u16, h);
}
__device__ __forceinline__ float h2f(u16 u) {
  return (float)__builtin_bit_cast(_Float16, u);
}

// async global->LDS, 16B/lane. LDS dest = wave-uniform base + lane*16.
__device__ __forceinline__ void load_lds16(const void* g, void* l) {
  auto gp = (const __attribute__((address_space(1))) u32*)(uintptr_t)g;
  auto lp = (__attribute__((address_space(3))) u32*)(u32)(uintptr_t)l;
  __builtin_amdgcn_global_load_lds(gp, lp, 16, 0, 0);
}
__device__ __forceinline__ bf16x8 ldf(const u16* p) { return *(const bf16x8*)p; }

// ---------------------------------------------------------------------------
// weight transpose + hi/lo bf16 split: for n,k: v = src[k][n]*scale;
// hi = bf16(v), lo = bf16(v - hi).
__global__ __launch_bounds__(256) void tpose_pair(const float* __restrict__ src,
                                                  u16* __restrict__ dhi,
                                                  u16* __restrict__ dlo,
                                                  int srcRows, int srcStride,
                                                  float scale) {
  __shared__ float tile[32][33];
  const int tx = threadIdx.x, ty = threadIdx.y;     // block (32,8)
  const int n0 = blockIdx.x * 32, k0 = blockIdx.y * 32;
#pragma unroll
  for (int j = 0; j < 4; ++j) {
    int k = k0 + ty + j * 8;
    tile[ty + j * 8][tx] = src[(size_t)k * srcStride + n0 + tx] * scale;
  }
  __syncthreads();
#pragma unroll
  for (int j = 0; j < 4; ++j) {
    int n = n0 + ty + j * 8;
    float f = tile[tx][ty + j * 8];
    u16 h = f2bf(f);
    size_t idx = (size_t)n * srcRows + k0 + tx;
    dhi[idx] = h;
    dlo[idx] = f2bf(f - bf2f(h));
  }
}

// ---------------------------------------------------------------------------
// Pair GEMM: C[M,N] = A_f32[M,K] @ (Bhi+Blo)[N,K]^T with in-kernel A hi/lo
// split. COMBOS=3: hh+hl+lh (fp32-grade); COMBOS=1: hh only (plain bf16).
// OUTF32: 1 -> fp32 C, 0 -> bf16 C. 128x128 tile, BK=32.
template <int COMBOS, int OUTF32>
__global__ __launch_bounds__(256) void gemm_f32a(const float* __restrict__ A,
                                                 const u16* __restrict__ Bhi,
                                                 const u16* __restrict__ Blo,
                                                 void* __restrict__ C,
                                                 int M, int N, int K) {
  __shared__ u16 Ah[128 * 32];
  __shared__ u16 Al[128 * 32];
  __shared__ u16 Bh[128 * 32];
  __shared__ u16 Bl[128 * 32];
  const int tid = threadIdx.x;
  const int wave = tid >> 6, lane = tid & 63;
  const int wm = wave >> 1, wn = wave & 1;
  const int qu = lane >> 4, ln = lane & 15;
  const int m0 = blockIdx.y * 128, n0 = blockIdx.x * 128;
  const int arow = tid >> 1, akof = (tid & 1) << 4;   // 16 fp32 per thread
  const int crow = tid >> 2, ckof = (tid & 3) << 3;
  f32x4 acc[4][4] = {};
  for (int kt = 0; kt < K; kt += 32) {
    // B: async staging (hi, and lo if used)
#pragma unroll
    for (int r = 0; r < 2; ++r) {
      const int row = crow + r * 64;
      load_lds16(Bhi + (size_t)(n0 + row) * K + kt + ckof, Bh + (size_t)(r * 256 + wave * 64) * 8);
      if (COMBOS == 3)
        load_lds16(Blo + (size_t)(n0 + row) * K + kt + ckof, Bl + (size_t)(r * 256 + wave * 64) * 8);
    }
    // A: fp32 load -> hi/lo split -> LDS
    {
      const float* src = A + (size_t)(m0 + arow) * K + kt + akof;
      float va[16];
#pragma unroll
      for (int j = 0; j < 16; j += 4) {
        float4 f4 = *(const float4*)(src + j);
        va[j] = f4.x; va[j + 1] = f4.y; va[j + 2] = f4.z; va[j + 3] = f4.w;
      }
      u16 hi[16], lo[16];
#pragma unroll
      for (int j = 0; j < 16; ++j) {
        hi[j] = f2bf(va[j]);
        lo[j] = f2bf(va[j] - bf2f(hi[j]));
      }
      u32 ph[8];
#pragma unroll
      for (int j = 0; j < 8; ++j) ph[j] = (u32)hi[2 * j] | ((u32)hi[2 * j + 1] << 16);
      *(uint4*)&Ah[arow * 32 + akof] = make_uint4(ph[0], ph[1], ph[2], ph[3]);
      *(uint4*)&Ah[arow * 32 + akof + 8] = make_uint4(ph[4], ph[5], ph[6], ph[7]);
      if (COMBOS == 3) {
#pragma unroll
        for (int j = 0; j < 8; ++j) ph[j] = (u32)lo[2 * j] | ((u32)lo[2 * j + 1] << 16);
        *(uint4*)&Al[arow * 32 + akof] = make_uint4(ph[0], ph[1], ph[2], ph[3]);
        *(uint4*)&Al[arow * 32 + akof + 8] = make_uint4(ph[4], ph[5], ph[6], ph[7]);
      }
    }
    __syncthreads();
    bf16x8 ah[4], bh[4], al[4], bl[4];
#pragma unroll
    for (int t = 0; t < 4; ++t) {
      ah[t] = ldf(&Ah[(wm * 64 + t * 16 + ln) * 32 + qu * 8]);
      bh[t] = ldf(&Bh[(wn * 64 + t * 16 + ln) * 32 + qu * 8]);
      if (COMBOS == 3) {
        al[t] = ldf(&Al[(wm * 64 + t * 16 + ln) * 32 + qu * 8]);
        bl[t] = ldf(&Bl[(wn * 64 + t * 16 + ln) * 32 + qu * 8]);
      }
    }
#pragma unroll
    for (int ti = 0; ti < 4; ++ti)
#pragma unroll
      for (int tj = 0; tj < 4; ++tj) {
        acc[ti][tj] = __builtin_amdgcn_mfma_f32_16x16x32_bf16(ah[ti], bh[tj], acc[ti][tj], 0, 0, 0);
        if (COMBOS == 3) {
          acc[ti][tj] = __builtin_amdgcn_mfma_f32_16x16x32_bf16(ah[ti], bl[tj], acc[ti][tj], 0, 0, 0);
          acc[ti][tj] = __builtin_amdgcn_mfma_f32_16x16x32_bf16(al[ti], bh[tj], acc[ti][tj], 0, 0, 0);
        }
      }
    __syncthreads();
  }
#pragma unroll
  for (int ti = 0; ti < 4; ++ti)
#pragma unroll
    for (int tj = 0; tj < 4; ++tj) {
      const int rowb = m0 + wm * 64 + ti * 16 + qu * 4;   // C/D: row=(lane>>4)*4+reg
      const int col = n0 + wn * 64 + tj * 16 + ln;        //      col=lane&15
#pragma unroll
      for (int r = 0; r < 4; ++r) {
        size_t idx = (size_t)(rowb + r) * N + col;
        if (OUTF32) ((float*)C)[idx] = acc[ti][tj][r];
        else        ((u16*)C)[idx] = f2bf(acc[ti][tj][r]);
      }
    }
}

// ---------------------------------------------------------------------------
// Plain bf16-A GEMM (final projection): C_f32[M,N] = A_bf16 @ Bt^T.
__global__ __launch_bounds__(256) void gemm_bt(const u16* __restrict__ A,
                                               const u16* __restrict__ Bt,
                                               float* __restrict__ C,
                                               int M, int N, int K) {
  __shared__ u16 As[128 * 32];
  __shared__ u16 Bs[128 * 32];
  const int tid = threadIdx.x;
  const int wave = tid >> 6, lane = tid & 63;
  const int wm = wave >> 1, wn = wave & 1;
  const int qu = lane >> 4, ln = lane & 15;
  const int m0 = blockIdx.y * 128, n0 = blockIdx.x * 128;
  const int crow = tid >> 2, ckof = (tid & 3) << 3;
  f32x4 acc[4][4] = {};
  for (int kt = 0; kt < K; kt += 32) {
#pragma unroll
    for (int r = 0; r < 2; ++r) {
      const int row = crow + r * 64;
      load_lds16(A + (size_t)(m0 + row) * K + kt + ckof, As + (size_t)(r * 256 + wave * 64) * 8);
      load_lds16(Bt + (size_t)(n0 + row) * K + kt + ckof, Bs + (size_t)(r * 256 + wave * 64) * 8);
    }
    __syncthreads();
    bf16x8 af[4], bfr[4];
#pragma unroll
    for (int t = 0; t < 4; ++t) {
      af[t] = ldf(&As[(wm * 64 + t * 16 + ln) * 32 + qu * 8]);
      bfr[t] = ldf(&Bs[(wn * 64 + t * 16 + ln) * 32 + qu * 8]);
    }
#pragma unroll
    for (int ti = 0; ti < 4; ++ti)
#pragma unroll
      for (int tj = 0; tj < 4; ++tj)
        acc[ti][tj] = __builtin_amdgcn_mfma_f32_16x16x32_bf16(af[ti], bfr[tj], acc[ti][tj], 0, 0, 0);
    __syncthreads();
  }
#pragma unroll
  for (int ti = 0; ti < 4; ++ti)
#pragma unroll
    for (int tj = 0; tj < 4; ++tj) {
      const int rowb = m0 + wm * 64 + ti * 16 + qu * 4;
      const int col = n0 + wn * 64 + tj * 16 + ln;
#pragma unroll
      for (int r = 0; r < 4; ++r)
        C[(size_t)(rowb + r) * N + col] = acc[ti][tj][r];
    }
}

// ---------------------------------------------------------------------------
// xg1[8192,16] = x[8192,2048] @ Wkg1[2048,16]   (fp32, tiled)
__global__ __launch_bounds__(256) void xg1_gemm(const float* __restrict__ x,
                                                const float* __restrict__ W1,
                                                float* __restrict__ xg1) {
  __shared__ float xs[64][40];   // 160 B row stride: float4-aligned
  __shared__ float ws2[32][16];
  const int tid = threadIdx.x;
  const int r0 = blockIdx.x * 64;
  const int col = tid & 15, rsub = tid >> 4;
  float acc[4] = {0.f, 0.f, 0.f, 0.f};
  for (int kt = 0; kt < 2048; kt += 32) {
#pragma unroll
    for (int j = 0; j < 2; ++j) {
      int c = j * 256 + tid;
      int row = c >> 3, kk = (c & 7) << 2;
      *(float4*)&xs[row][kk] = *(const float4*)&x[(size_t)(r0 + row) * 2048 + kt + kk];
    }
#pragma unroll
    for (int j = 0; j < 2; ++j) {
      int c = j * 256 + tid;
      ws2[c >> 4][c & 15] = W1[(size_t)(kt + (c >> 4)) * 16 + (c & 15)];
    }
    __syncthreads();
#pragma unroll
    for (int kk = 0; kk < 32; ++kk) {
      float wv = ws2[kk][col];
#pragma unroll
      for (int j = 0; j < 4; ++j) acc[j] += xs[rsub + j * 16][kk] * wv;
    }
    __syncthreads();
  }
#pragma unroll
  for (int j = 0; j < 4; ++j) xg1[(size_t)(r0 + rsub + j * 16) * 16 + col] = acc[j];
}

// ---------------------------------------------------------------------------
// dv-split exact GLA scan. Grid 256 = 32 (b,h)-groups x 8 dv-slices.
// blockIdx mapping g=bi&31, slice=bi>>5 puts a group's 8 slices on one XCD
// (round-robin dispatch) so shared q/k strip reads hit that XCD's L2.
// 512 threads: scan layout dk_g=tid&15 (8 dk each) x dv_g=tid>>4 (1 dv each).
// Q/K/E LDS rows are chunk-de-interleaved (even float4-chunks first):
// thread g reads its 8 dk as float4 @ [4g] and [64+4g] -> 16 lanes x 16B =
// 256B contiguous = 2-way bank aliasing (free), vs 4-way for linear rows.
__global__ __launch_bounds__(512, 2) void gla_scan(const float* __restrict__ QK,
                                                   const u16* __restrict__ V,
                                                   const float* __restrict__ xg1,
                                                   const float* __restrict__ W2,
                                                   const float* __restrict__ b2,
                                                   u16* __restrict__ Oh,        // fp16 o out
                                                   float* __restrict__ Psum,
                                                   float* __restrict__ Pss) {
  __shared__ float Qs[16][128];
  __shared__ float Ks[16][128];
  __shared__ float Es[16][128];
  __shared__ u16 Vs[16][32];
  __shared__ float Os[16][32];
  __shared__ float xg1s[16][16];
  const int tid = threadIdx.x;
  const int bi = blockIdx.x;
  const int g = bi & 31, slice = bi >> 5;
  const int b = g >> 3, h = g & 7;
  const int dk_g = tid & 15, dv_g = tid >> 4;       // scan-phase layout
  const int te = tid >> 5, d0e = (tid & 31) << 2;   // stage/E-phase layout
  // Wkg2 column slice (16 x 4) pinned in registers: no LDS traffic in gk FMAs
  float4 w2r[16];
#pragma unroll
  for (int k = 0; k < 16; ++k)
    w2r[k] = *(const float4*)&W2[(size_t)k * 1024 + h * 128 + d0e];
  const float4 b2r = *(const float4*)&b2[h * 128 + d0e];
  const int pbs = ((d0e >> 3) << 2) + ((d0e >> 2) & 1) * 64;  // de-interleave dst
  float S[8] = {};
  for (int strip = 0; strip < 128; ++strip) {
    const int t0 = b * 2048 + strip * 16;
    // ---- stage q,k (fp32, de-interleaved), v slice (bf16), xg1
    {
      const size_t gq = (size_t)(t0 + te) * 2048 + h * 128 + d0e;
      float4 q4 = *(const float4*)&QK[gq];
      float4 k4 = *(const float4*)&QK[gq + 1024];
      *(float4*)&Qs[te][pbs] = q4;
      *(float4*)&Ks[te][pbs] = k4;
    }
    if (tid < 128) {
      int row = tid >> 3, c0 = (tid & 7) << 2;
      *(ushort4*)&Vs[row][c0] =
          *(const ushort4*)&V[(size_t)(t0 + row) * 2048 + h * 256 + slice * 32 + c0];
    } else if (tid < 192) {
      int t = (tid - 128) >> 2, k0 = (tid & 3) << 2;
      *(float4*)&xg1s[t][k0] = *(const float4*)&xg1[(size_t)(t0 + t) * 16 + k0];
    }
    __syncthreads();
    // ---- E = exp(log_sigmoid(xg1@W2 + b2) / 16), 4 values per thread
    {
      float4 z = b2r;
#pragma unroll
      for (int k = 0; k < 16; ++k) {
        float xk = xg1s[te][k];
        z.x += xk * w2r[k].x; z.y += xk * w2r[k].y;
        z.z += xk * w2r[k].z; z.w += xk * w2r[k].w;
      }
      float4 e;
      e.x = expf((fminf(z.x, 0.f) - log1pf(expf(-fabsf(z.x)))) * 0.0625f);
      e.y = expf((fminf(z.y, 0.f) - log1pf(expf(-fabsf(z.y)))) * 0.0625f);
      e.z = expf((fminf(z.z, 0.f) - log1pf(expf(-fabsf(z.z)))) * 0.0625f);
      e.w = expf((fminf(z.w, 0.f) - log1pf(expf(-fabsf(z.w)))) * 0.0625f);
      *(float4*)&Es[te][pbs] = e;
    }
    __syncthreads();
    // ---- exact recurrence, 16 tokens; S rows = 8 dk, 1 dv per thread
    for (int tt = 0; tt < 16; ++tt) {
      float4 ea = *(const float4*)&Es[tt][dk_g * 4];
      float4 eb = *(const float4*)&Es[tt][64 + dk_g * 4];
      float4 qa = *(const float4*)&Qs[tt][dk_g * 4];
      float4 qb = *(const float4*)&Qs[tt][64 + dk_g * 4];
      float4 ka = *(const float4*)&Ks[tt][dk_g * 4];
      float4 kb = *(const float4*)&Ks[tt][64 + dk_g * 4];
      float vv = bf2f(Vs[tt][dv_g]);
      float p;
      S[0] = ea.x * S[0] + ka.x * vv;  p  = qa.x * S[0];
      S[1] = ea.y * S[1] + ka.y * vv;  p += qa.y * S[1];
      S[2] = ea.z * S[2] + ka.z * vv;  p += qa.z * S[2];
      S[3] = ea.w * S[3] + ka.w * vv;  p += qa.w * S[3];
      S[4] = eb.x * S[4] + kb.x * vv;  p += qb.x * S[4];
      S[5] = eb.y * S[5] + kb.y * vv;  p += qb.y * S[5];
      S[6] = eb.z * S[6] + kb.z * vv;  p += qb.z * S[6];
      S[7] = eb.w * S[7] + kb.w * vv;  p += qb.w * S[7];
      p += __shfl_xor(p, 1, 64);
      p += __shfl_xor(p, 2, 64);
      p += __shfl_xor(p, 4, 64);
      p += __shfl_xor(p, 8, 64);
      if (dk_g == 0) Os[tt][dv_g] = p;
    }
    __syncthreads();
    // ---- emit o fp16 + per-slice LN partials (fp32 sums pre-rounding)
    {
      const int ts = tid >> 5, dvs = tid & 31;
      float val = Os[ts][dvs];
      float s = val, ss = val * val;
#pragma unroll
      for (int off = 1; off < 32; off <<= 1) {
        s += __shfl_xor(s, off, 64);
        ss += __shfl_xor(ss, off, 64);
      }
      Oh[(size_t)(t0 + ts) * 2048 + h * 256 + slice * 32 + dvs] = f2h(val);
      if (dvs == 0) {
        size_t pidx = ((size_t)(t0 + ts) * 8 + h) * 8 + slice;
        Psum[pidx] = s;
        Pss[pidx] = ss;
      }
    }
    // no barrier needed here: next stage only writes Qs/Ks/Vs/xg1s (not Os),
    // and the post-stage barrier orders E/scan writes after this phase.
  }
}

// ---------------------------------------------------------------------------
// LayerNorm(256, from fp32 partials) + silu(g) gate.
// Reads o fp16, overwrites IN PLACE with OG bf16 (same element size/layout).
__global__ __launch_bounds__(256) void ln_gate(u16* __restrict__ O,
                                               const float* __restrict__ Psum,
                                               const float* __restrict__ Pss,
                                               const u16* __restrict__ G,
                                               const float* __restrict__ bg) {
  const int tglob = blockIdx.x;        // token row 0..8191
  const int tid = threadIdx.x;
  const int c0 = tid << 3;             // 8 elements per thread
  const int h = c0 >> 8;
  const size_t pb = ((size_t)tglob * 8 + h) * 8;
  const float4 s0 = *(const float4*)&Psum[pb];
  const float4 s1 = *(const float4*)&Psum[pb + 4];
  const float4 q0 = *(const float4*)&Pss[pb];
  const float4 q1 = *(const float4*)&Pss[pb + 4];
  const float s = s0.x + s0.y + s0.z + s0.w + s1.x + s1.y + s1.z + s1.w;
  const float ss = q0.x + q0.y + q0.z + q0.w + q1.x + q1.y + q1.z + q1.w;
  const float mean = s * (1.f / 256.f);
  const float rstd = rsqrtf(ss * (1.f / 256.f) - mean * mean + 1e-5f);
  const size_t base = (size_t)tglob * 2048 + c0;
  ushort4 oa = *(const ushort4*)&O[base];
  ushort4 ob = *(const ushort4*)&O[base + 4];
  ushort4 ga = *(const ushort4*)&G[base];
  ushort4 gb = *(const ushort4*)&G[base + 4];
  float4 bga = *(const float4*)&bg[c0];
  float4 bgb = *(const float4*)&bg[c0 + 4];
  auto one = [&](u16 ou, u16 gu, float bgv) -> u16 {
    float o = (h2f(ou) - mean) * rstd;
    float gg = bf2f(gu) + bgv;
    return f2bf(o * gg / (1.f + expf(-gg)));
  };
  ushort4 ra, rb;
  ra.x = one(oa.x, ga.x, bga.x);
  ra.y = one(oa.y, ga.y, bga.y);
  ra.z = one(oa.z, ga.z, bga.z);
  ra.w = one(oa.w, ga.w, bga.w);
  rb.x = one(ob.x, gb.x, bgb.x);
  rb.y = one(ob.y, gb.y, bgb.y);
  rb.z = one(ob.z, gb.z, bgb.z);
  rb.w = one(ob.w, gb.w, bgb.w);
  *(ushort4*)&O[base] = ra;
  *(ushort4*)&O[base + 4] = rb;
}

// ---------------------------------------------------------------------------
extern "C" void kernel_launch(void* const* d_in, const int* in_sizes, int n_in,
                              void* d_out, int out_size, void* d_ws, size_t ws_size,
                              hipStream_t stream) {
  (void)in_sizes; (void)n_in; (void)out_size;
  if (ws_size < 117964800ull) return;   // fail soft (round 2 proved >= 126.6MB)

  const float* x    = (const float*)d_in[0];
  const float* Wq   = (const float*)d_in[1];
  const float* Wk   = (const float*)d_in[2];
  const float* Wkg1 = (const float*)d_in[3];
  const float* Wkg2 = (const float*)d_in[4];
  const float* bkg2 = (const float*)d_in[5];
  const float* Wv   = (const float*)d_in[6];
  const float* Wg   = (const float*)d_in[7];
  const float* bg   = (const float*)d_in[8];
  const float* Wo   = (const float*)d_in[9];

  char* ws = (char*)d_ws;
  float* QK  = (float*)(ws + 0);           // 64 MiB fp32 [q|k/16]; later final-C
  u16*   V   = (u16*)(ws + 67108864);      // 32 MiB bf16
  u16*   WtA = (u16*)(ws + 100663296);     //  8 MiB hi
  u16*   WtB = (u16*)(ws + 109051904);     //  8 MiB lo
  float* xg1 = (float*)(ws + 117440512);   // 0.5 MiB
  float* Cf  = QK;                         // final GEMM C (QK dead by then)
  // LN partials live in the WtA region, which is idle between the g-projection
  // transpose (before scan) and the Wo transpose (after ln_gate).
  float* Psum = (float*)(ws + 100663296);             // 2 MiB
  float* Pss  = (float*)(ws + 100663296 + 2097152);   // 2 MiB

  u16* G  = (u16*)d_out;                   // d_out [0,32Mi)
  u16* Oh = (u16*)d_out + 16777216;        // d_out [32Mi,64Mi): o fp16 -> OG bf16

  dim3 tb(32, 8);

  xg1_gemm<<<dim3(128), dim3(256), 0, stream>>>(x, Wkg1, xg1);

  // [q|k] pair projection, fp32 out (Wk folded with (D/H)^-0.5 = 1/16, exact pow2)
  tpose_pair<<<dim3(32, 64), tb, 0, stream>>>(Wq, WtA,               WtB,               2048, 1024, 1.0f);
  tpose_pair<<<dim3(32, 64), tb, 0, stream>>>(Wk, WtA + 1024 * 2048, WtB + 1024 * 2048, 2048, 1024, 0.0625f);
  gemm_f32a<3, 1><<<dim3(16, 64), dim3(256), 0, stream>>>(x, WtA, WtB, (void*)QK, 8192, 2048, 2048);

  // v pair projection, bf16 out
  tpose_pair<<<dim3(64, 64), tb, 0, stream>>>(Wv, WtA, WtB, 2048, 2048, 1.0f);
  gemm_f32a<3, 0><<<dim3(16, 64), dim3(256), 0, stream>>>(x, WtA, WtB, (void*)V, 8192, 2048, 2048);

  // g projection (plain bf16 quality suffices for the gate)
  tpose_pair<<<dim3(64, 64), tb, 0, stream>>>(Wg, WtA, WtB, 2048, 2048, 1.0f);
  gemm_f32a<1, 0><<<dim3(16, 64), dim3(256), 0, stream>>>(x, WtA, WtA, (void*)G, 8192, 2048, 2048);

  // dv-split exact scan (256 blocks = 1/CU) + split-off LN/gate
  gla_scan<<<dim3(256), dim3(512), 0, stream>>>(QK, V, xg1, Wkg2, bkg2, Oh, Psum, Pss);
  ln_gate<<<dim3(8192), dim3(256), 0, stream>>>(Oh, Psum, Pss, G, bg);

  // final projection: OG bf16 @ Wo^T -> fp32, then d2d to d_out
  tpose_pair<<<dim3(64, 64), tb, 0, stream>>>(Wo, WtA, WtB, 2048, 2048, 1.0f);
  gemm_bt<<<dim3(16, 64), dim3(256), 0, stream>>>(Oh, WtA, Cf, 8192, 2048, 2048);
  hipMemcpyAsync(d_out, Cf, 67108864ull, hipMemcpyDeviceToDevice, stream);
}

// Round 2
// 1426.973 us; speedup vs baseline: 2.6903x; 1.3735x over previous
//
#include <hip/hip_runtime.h>
#include <stdint.h>

// ---------------------------------------------------------------------------
// GatedLinearAttention (b=4, T=2048, D=2048, H=8, dk=128, dv=256, CHUNK=128)
// Round: chunked-GLA on MFMA. Exact identity: with KE = k*exp(-gkc),
// QD = q*exp(gkc), dl = exp(gkc_last):
//   A = tril(QD @ KE^T); o_intra = A @ V
//   W = KE^T @ V;  S_c = dl (.) (S_{c-1} + W_c);  o_inter = QD_c @ S_{c-1}
// gla_decor: cumsum gk + decorate q,k (fp32->bf16 hi/lo, in place over QK).
// gla_intra: A (3-combo) + masked o_intra (2-combo) per (b,h,chunk).
// gla_inter: serial 16-chunk scan per (b,h,dv-slice): o_inter (3-combo via
//            S hi/lo split) RMW'd into fp16 o; W (2-combo); S fp32 in LDS.
// ln_gate: LayerNorm sums via segmented shuffles (no partials) + silu gate.
//
// ws layout (112.5 MiB guard unchanged):
//   QK [0,64Mi)      fp32 [q | k/16] [8192][2048]; after gla_decor each row
//                    becomes u16 planes [QDh|QDl|KEh|KEl] x1024; reused as C
//   V  [64Mi,96Mi)   bf16 [8192][2048]
//   WtA [96Mi,104Mi) weight^T hi-plane; WtB [104Mi,112Mi) lo-plane
//   dl  at WtB base (idle between G-gemm and Wo-transpose), 256KB fp32
//   xg1 [112Mi,+512K)
// d_out scratch: G bf16 [0,32Mi); o fp16 -> OG bf16 [32Mi,64Mi); final C last.
// ---------------------------------------------------------------------------

typedef unsigned short u16;
typedef unsigned int u32;
typedef __bf16 bf16x8 __attribute__((ext_vector_type(8)));
typedef float f32x4 __attribute__((ext_vector_type(4)));

__device__ __forceinline__ u16 f2bf(float f) {
  u32 u = __float_as_uint(f);
  u32 r = (u + 0x7fffu + ((u >> 16) & 1u)) >> 16;   // RNE
  return (u16)r;
}
__device__ __forceinline__ float bf2f(u16 s) {
  return __uint_as_float(((u32)s) << 16);
}
__device__ __forceinline__ u16 f2h(float f) {
  _Float16 h = (_Float16)f;                          // RNE fp32->fp16
  return __builtin_bit_cast(u16, h);
}
__device__ __forceinline__ float h2f(u16 u) {
  return (float)__builtin_bit_cast(_Float16, u);
}

// async global->LDS, 16B/lane. LDS dest = wave-uniform base + lane*16.
__device__ __forceinline__ void load_lds16(const void* g, void* l) {
  auto gp = (const __attribute__((address_space(1))) u32*)(uintptr_t)g;
  auto lp = (__attribute__((address_space(3))) u32*)(u32)(uintptr_t)l;
  __builtin_amdgcn_global_load_lds(gp, lp, 16, 0, 0);
}
__device__ __forceinline__ bf16x8 ldf(const u16* p) { return *(const bf16x8*)p; }

// scatter 8 u16 (from one uint4) down an LDS column with given row stride
__device__ __forceinline__ void scat8(u16* dst, int stride, uint4 v) {
  dst[0]          = (u16)v.x; dst[stride]     = (u16)(v.x >> 16);
  dst[2 * stride] = (u16)v.y; dst[3 * stride] = (u16)(v.y >> 16);
  dst[4 * stride] = (u16)v.z; dst[5 * stride] = (u16)(v.z >> 16);
  dst[6 * stride] = (u16)v.w; dst[7 * stride] = (u16)(v.w >> 16);
}

// ---------------------------------------------------------------------------
// weight transpose + hi/lo bf16 split
__global__ __launch_bounds__(256) void tpose_pair(const float* __restrict__ src,
                                                  u16* __restrict__ dhi,
                                                  u16* __restrict__ dlo,
                                                  int srcRows, int srcStride,
                                                  float scale) {
  __shared__ float tile[32][33];
  const int tx = threadIdx.x, ty = threadIdx.y;     // block (32,8)
  const int n0 = blockIdx.x * 32, k0 = blockIdx.y * 32;
#pragma unroll
  for (int j = 0; j < 4; ++j) {
    int k = k0 + ty + j * 8;
    tile[ty + j * 8][tx] = src[(size_t)k * srcStride + n0 + tx] * scale;
  }
  __syncthreads();
#pragma unroll
  for (int j = 0; j < 4; ++j) {
    int n = n0 + ty + j * 8;
    float f = tile[tx][ty + j * 8];
    u16 h = f2bf(f);
    size_t idx = (size_t)n * srcRows + k0 + tx;
    dhi[idx] = h;
    dlo[idx] = f2bf(f - bf2f(h));
  }
}

// ---------------------------------------------------------------------------
// Pair GEMM: C[M,N] = A_f32[M,K] @ (Bhi+Blo)[N,K]^T, in-kernel A hi/lo split.
template <int COMBOS, int OUTF32>
__global__ __launch_bounds__(256) void gemm_f32a(const float* __restrict__ A,
                                                 const u16* __restrict__ Bhi,
                                                 const u16* __restrict__ Blo,
                                                 void* __restrict__ C,
                                                 int M, int N, int K) {
  __shared__ u16 Ah[128 * 32];
  __shared__ u16 Al[128 * 32];
  __shared__ u16 Bh[128 * 32];
  __shared__ u16 Bl[128 * 32];
  const int tid = threadIdx.x;
  const int wave = tid >> 6, lane = tid & 63;
  const int wm = wave >> 1, wn = wave & 1;
  const int qu = lane >> 4, ln = lane & 15;
  const int m0 = blockIdx.y * 128, n0 = blockIdx.x * 128;
  const int arow = tid >> 1, akof = (tid & 1) << 4;
  const int crow = tid >> 2, ckof = (tid & 3) << 3;
  f32x4 acc[4][4] = {};
  for (int kt = 0; kt < K; kt += 32) {
#pragma unroll
    for (int r = 0; r < 2; ++r) {
      const int row = crow + r * 64;
      load_lds16(Bhi + (size_t)(n0 + row) * K + kt + ckof, Bh + (size_t)(r * 256 + wave * 64) * 8);
      if (COMBOS == 3)
        load_lds16(Blo + (size_t)(n0 + row) * K + kt + ckof, Bl + (size_t)(r * 256 + wave * 64) * 8);
    }
    {
      const float* src = A + (size_t)(m0 + arow) * K + kt + akof;
      float va[16];
#pragma unroll
      for (int j = 0; j < 16; j += 4) {
        float4 f4 = *(const float4*)(src + j);
        va[j] = f4.x; va[j + 1] = f4.y; va[j + 2] = f4.z; va[j + 3] = f4.w;
      }
      u16 hi[16], lo[16];
#pragma unroll
      for (int j = 0; j < 16; ++j) {
        hi[j] = f2bf(va[j]);
        lo[j] = f2bf(va[j] - bf2f(hi[j]));
      }
      u32 ph[8];
#pragma unroll
      for (int j = 0; j < 8; ++j) ph[j] = (u32)hi[2 * j] | ((u32)hi[2 * j + 1] << 16);
      *(uint4*)&Ah[arow * 32 + akof] = make_uint4(ph[0], ph[1], ph[2], ph[3]);
      *(uint4*)&Ah[arow * 32 + akof + 8] = make_uint4(ph[4], ph[5], ph[6], ph[7]);
      if (COMBOS == 3) {
#pragma unroll
        for (int j = 0; j < 8; ++j) ph[j] = (u32)lo[2 * j] | ((u32)lo[2 * j + 1] << 16);
        *(uint4*)&Al[arow * 32 + akof] = make_uint4(ph[0], ph[1], ph[2], ph[3]);
        *(uint4*)&Al[arow * 32 + akof + 8] = make_uint4(ph[4], ph[5], ph[6], ph[7]);
      }
    }
    __syncthreads();
    bf16x8 ah[4], bh[4], al[4], bl[4];
#pragma unroll
    for (int t = 0; t < 4; ++t) {
      ah[t] = ldf(&Ah[(wm * 64 + t * 16 + ln) * 32 + qu * 8]);
      bh[t] = ldf(&Bh[(wn * 64 + t * 16 + ln) * 32 + qu * 8]);
      if (COMBOS == 3) {
        al[t] = ldf(&Al[(wm * 64 + t * 16 + ln) * 32 + qu * 8]);
        bl[t] = ldf(&Bl[(wn * 64 + t * 16 + ln) * 32 + qu * 8]);
      }
    }
#pragma unroll
    for (int ti = 0; ti < 4; ++ti)
#pragma unroll
      for (int tj = 0; tj < 4; ++tj) {
        acc[ti][tj] = __builtin_amdgcn_mfma_f32_16x16x32_bf16(ah[ti], bh[tj], acc[ti][tj], 0, 0, 0);
        if (COMBOS == 3) {
          acc[ti][tj] = __builtin_amdgcn_mfma_f32_16x16x32_bf16(ah[ti], bl[tj], acc[ti][tj], 0, 0, 0);
          acc[ti][tj] = __builtin_amdgcn_mfma_f32_16x16x32_bf16(al[ti], bh[tj], acc[ti][tj], 0, 0, 0);
        }
      }
    __syncthreads();
  }
#pragma unroll
  for (int ti = 0; ti < 4; ++ti)
#pragma unroll
    for (int tj = 0; tj < 4; ++tj) {
      const int rowb = m0 + wm * 64 + ti * 16 + qu * 4;
      const int col = n0 + wn * 64 + tj * 16 + ln;
#pragma unroll
      for (int r = 0; r < 4; ++r) {
        size_t idx = (size_t)(rowb + r) * N + col;
        if (OUTF32) ((float*)C)[idx] = acc[ti][tj][r];
        else        ((u16*)C)[idx] = f2bf(acc[ti][tj][r]);
      }
    }
}

// ---------------------------------------------------------------------------
// Plain bf16-A GEMM (final projection)
__global__ __launch_bounds__(256) void gemm_bt(const u16* __restrict__ A,
                                               const u16* __restrict__ Bt,
                                               float* __restrict__ C,
                                               int M, int N, int K) {
  __shared__ u16 As[128 * 32];
  __shared__ u16 Bs[128 * 32];
  const int tid = threadIdx.x;
  const int wave = tid >> 6, lane = tid & 63;
  const int wm = wave >> 1, wn = wave & 1;
  const int qu = lane >> 4, ln = lane & 15;
  const int m0 = blockIdx.y * 128, n0 = blockIdx.x * 128;
  const int crow = tid >> 2, ckof = (tid & 3) << 3;
  f32x4 acc[4][4] = {};
  for (int kt = 0; kt < K; kt += 32) {
#pragma unroll
    for (int r = 0; r < 2; ++r) {
      const int row = crow + r * 64;
      load_lds16(A + (size_t)(m0 + row) * K + kt + ckof, As + (size_t)(r * 256 + wave * 64) * 8);
      load_lds16(Bt + (size_t)(n0 + row) * K + kt + ckof, Bs + (size_t)(r * 256 + wave * 64) * 8);
    }
    __syncthreads();
    bf16x8 af[4], bfr[4];
#pragma unroll
    for (int t = 0; t < 4; ++t) {
      af[t] = ldf(&As[(wm * 64 + t * 16 + ln) * 32 + qu * 8]);
      bfr[t] = ldf(&Bs[(wn * 64 + t * 16 + ln) * 32 + qu * 8]);
    }
#pragma unroll
    for (int ti = 0; ti < 4; ++ti)
#pragma unroll
      for (int tj = 0; tj < 4; ++tj)
        acc[ti][tj] = __builtin_amdgcn_mfma_f32_16x16x32_bf16(af[ti], bfr[tj], acc[ti][tj], 0, 0, 0);
    __syncthreads();
  }
#pragma unroll
  for (int ti = 0; ti < 4; ++ti)
#pragma unroll
    for (int tj = 0; tj < 4; ++tj) {
      const int rowb = m0 + wm * 64 + ti * 16 + qu * 4;
      const int col = n0 + wn * 64 + tj * 16 + ln;
#pragma unroll
      for (int r = 0; r < 4; ++r)
        C[(size_t)(rowb + r) * N + col] = acc[ti][tj][r];
    }
}

// ---------------------------------------------------------------------------
// xg1[8192,16] = x[8192,2048] @ Wkg1[2048,16]   (fp32, tiled)
__global__ __launch_bounds__(256) void xg1_gemm(const float* __restrict__ x,
                                                const float* __restrict__ W1,
                                                float* __restrict__ xg1) {
  __shared__ float xs[64][40];
  __shared__ float ws2[32][16];
  const int tid = threadIdx.x;
  const int r0 = blockIdx.x * 64;
  const int col = tid & 15, rsub = tid >> 4;
  float acc[4] = {0.f, 0.f, 0.f, 0.f};
  for (int kt = 0; kt < 2048; kt += 32) {
#pragma unroll
    for (int j = 0; j < 2; ++j) {
      int c = j * 256 + tid;
      int row = c >> 3, kk = (c & 7) << 2;
      *(float4*)&xs[row][kk] = *(const float4*)&x[(size_t)(r0 + row) * 2048 + kt + kk];
    }
#pragma unroll
    for (int j = 0; j < 2; ++j) {
      int c = j * 256 + tid;
      ws2[c >> 4][c & 15] = W1[(size_t)(kt + (c >> 4)) * 16 + (c & 15)];
    }
    __syncthreads();
#pragma unroll
    for (int kk = 0; kk < 32; ++kk) {
      float wv = ws2[kk][col];
#pragma unroll
      for (int j = 0; j < 4; ++j) acc[j] += xs[rsub + j * 16][kk] * wv;
    }
    __syncthreads();
  }
#pragma unroll
  for (int j = 0; j < 4; ++j) xg1[(size_t)(r0 + rsub + j * 16) * 16 + col] = acc[j];
}

// ---------------------------------------------------------------------------
// gla_decor: per (b,chunk): gk = log_sigmoid(xg1@W2+b2)/16, gkc = cumsum;
// decorate QD = q*exp(gkc), KE = k*exp(-gkc), split to bf16 hi/lo IN PLACE
// over the fp32 QK row (u16 planes [QDh|QDl|KEh|KEl]); dl = exp(gkc_last).
// Grid 64 = (b,n); 1024 threads = global col (h*128+d). LDS-tile staging of
// 8-token strips makes the in-place overwrite safe.
__global__ __launch_bounds__(1024) void gla_decor(float* __restrict__ QK,
                                                  const float* __restrict__ xg1,
                                                  const float* __restrict__ W2,
                                                  const float* __restrict__ b2,
                                                  float* __restrict__ dl) {
  __shared__ float xg1s[128][16];   // 8KB
  __shared__ float qks[8][2048];    // 64KB
  const int tid = threadIdx.x;
  const int bi = blockIdx.x;
  const int b = bi >> 4, n = bi & 15;
  const int t0 = b * 2048 + n * 128;
  u16* QKu = (u16*)QK;
  float w2r[16];
#pragma unroll
  for (int k = 0; k < 16; ++k) w2r[k] = W2[k * 1024 + tid];
  const float b2r = b2[tid];
#pragma unroll
  for (int r = 0; r < 2; ++r) {
    int e = r * 1024 + tid;
    xg1s[e >> 4][e & 15] = xg1[(size_t)(t0 + (e >> 4)) * 16 + (e & 15)];
  }
  float acc = 0.f;
  for (int tt = 0; tt < 16; ++tt) {
    __syncthreads();   // prev-tile LDS reads done (also covers xg1s first use)
#pragma unroll
    for (int r = 0; r < 4; ++r) {
      int e4 = r * 1024 + tid;
      int row = e4 >> 9, col = (e4 & 511) << 2;
      *(float4*)&qks[row][col] = *(const float4*)&QK[(size_t)(t0 + tt * 8 + row) * 2048 + col];
    }
    __syncthreads();
#pragma unroll
    for (int tq = 0; tq < 8; ++tq) {
      const int t = tt * 8 + tq;
      float z = b2r;
#pragma unroll
      for (int kk = 0; kk < 16; ++kk) z += xg1s[t][kk] * w2r[kk];
      float gk = (fminf(z, 0.f) - log1pf(expf(-fabsf(z)))) * 0.0625f;
      acc += gk;
      float ep = expf(acc), em = expf(-acc);
      float qd = qks[tq][tid] * ep;
      float ke = qks[tq][1024 + tid] * em;
      u16 qh = f2bf(qd), kh = f2bf(ke);
      u16* dst = QKu + (size_t)(t0 + t) * 4096;
      dst[tid]        = qh;
      dst[1024 + tid] = f2bf(qd - bf2f(qh));
      dst[2048 + tid] = kh;
      dst[3072 + tid] = f2bf(ke - bf2f(kh));
    }
  }
  const int h = tid >> 7, d = tid & 127;
  dl[((size_t)(b * 8 + h) * 16 + n) * 128 + d] = expf(acc);
}

// ---------------------------------------------------------------------------
// gla_intra: per (b,h,chunk): A = tril(QD@KE^T) (3-combo), o_intra = A@V^T-
// staged (2-combo) -> Oh fp16. Am kept in LDS with XOR row-swizzle
// (idx = i*128 + (j ^ ((i&15)<<3))) so phase-C a-frag ds_read_b128 is ~2-way.
__global__ __launch_bounds__(256) void gla_intra(const u16* __restrict__ QKu,
                                                 const u16* __restrict__ V,
                                                 u16* __restrict__ Oh) {
  // pool: phase A stage planes [0,16384) u16; Am hi [0,16384) lo [16384,32768);
  //       VTs [32768, 32768+7168) = [128][56] u16 pad
  __shared__ u16 pool[39936];   // 79872 B -> 2 blocks/CU
  const int tid = threadIdx.x;
  const int bi = blockIdx.x;
  const int n = bi & 15, h = (bi >> 4) & 7, b = bi >> 7;
  const int t0 = b * 2048 + n * 128;
  const int wave = tid >> 6, lane = tid & 63;
  const int wm = wave >> 1, wn = wave & 1;
  const int qu = lane >> 4, ln = lane & 15;
  const int crow = tid >> 2, ckof = (tid & 3) << 3;
  u16* Qh = pool;
  u16* Ql = pool + 4096;
  u16* Kh = pool + 8192;
  u16* Kl = pool + 12288;
  u16* Amh = pool;
  u16* Aml = pool + 16384;
  u16* VTs = pool + 32768;
  // ---- phase A: A = QD @ KE^T  (3-combo hi/lo)
  f32x4 acc[4][4] = {};
  for (int kt = 0; kt < 128; kt += 32) {
#pragma unroll
    for (int r = 0; r < 2; ++r) {
      const int row = crow + r * 64;
      const size_t gb = (size_t)(t0 + row) * 4096 + h * 128 + kt + ckof;
      load_lds16(QKu + gb,        Qh + (size_t)(r * 256 + wave * 64) * 8);
      load_lds16(QKu + gb + 1024, Ql + (size_t)(r * 256 + wave * 64) * 8);
      load_lds16(QKu + gb + 2048, Kh + (size_t)(r * 256 + wave * 64) * 8);
      load_lds16(QKu + gb + 3072, Kl + (size_t)(r * 256 + wave * 64) * 8);
    }
    __syncthreads();
    bf16x8 ah[4], al[4], bh[4], bl[4];
#pragma unroll
    for (int t = 0; t < 4; ++t) {
      ah[t] = ldf(&Qh[(wm * 64 + t * 16 + ln) * 32 + qu * 8]);
      al[t] = ldf(&Ql[(wm * 64 + t * 16 + ln) * 32 + qu * 8]);
      bh[t] = ldf(&Kh[(wn * 64 + t * 16 + ln) * 32 + qu * 8]);
      bl[t] = ldf(&Kl[(wn * 64 + t * 16 + ln) * 32 + qu * 8]);
    }
#pragma unroll
    for (int ti = 0; ti < 4; ++ti)
#pragma unroll
      for (int tj = 0; tj < 4; ++tj) {
        acc[ti][tj] = __builtin_amdgcn_mfma_f32_16x16x32_bf16(ah[ti], bh[tj], acc[ti][tj], 0, 0, 0);
        acc[ti][tj] = __builtin_amdgcn_mfma_f32_16x16x32_bf16(ah[ti], bl[tj], acc[ti][tj], 0, 0, 0);
        acc[ti][tj] = __builtin_amdgcn_mfma_f32_16x16x32_bf16(al[ti], bh[tj], acc[ti][tj], 0, 0, 0);
      }
    __syncthreads();
  }
  // ---- phase B: causal mask + hi/lo split -> Am (swizzled), aliases stage
#pragma unroll
  for (int ti = 0; ti < 4; ++ti)
#pragma unroll
    for (int tj = 0; tj < 4; ++tj) {
      const int ib = wm * 64 + ti * 16 + qu * 4;
      const int j = wn * 64 + tj * 16 + ln;
#pragma unroll
      for (int r = 0; r < 4; ++r) {
        const int i = ib + r;
        float v = (j <= i) ? acc[ti][tj][r] : 0.f;
        u16 hi = f2bf(v);
        const int idx = i * 128 + (j ^ ((i & 15) << 3));
        Amh[idx] = hi;
        Aml[idx] = f2bf(v - bf2f(hi));
      }
    }
  // ---- phase C: o_intra = Am @ V^T (2-combo), two dv-halves of 128
  for (int half = 0; half < 2; ++half) {
    f32x4 acc2[4][4] = {};
    for (int kt = 0; kt < 128; kt += 32) {
      __syncthreads();   // Am visible (first iter) / prev VTs reads done
      {  // stage VTs[dv][t] transposed from V, pad 56
        const int j = tid & 31, dvg = tid >> 5;
#pragma unroll
        for (int rr = 0; rr < 2; ++rr) {
          const int dg = dvg + rr * 8;
          uint4 pv = *(const uint4*)(V + (size_t)(t0 + kt + j) * 2048 + h * 256 + half * 128 + dg * 8);
          scat8(VTs + (dg * 8) * 56 + j, 56, pv);
        }
      }
      __syncthreads();
      bf16x8 amh[4], aml[4], bv[4];
#pragma unroll
      for (int t = 0; t < 4; ++t) {
        const int i = wm * 64 + t * 16 + ln;
        const int cof = (kt + qu * 8) ^ ((i & 15) << 3);
        amh[t] = ldf(&Amh[i * 128 + cof]);
        aml[t] = ldf(&Aml[i * 128 + cof]);
        bv[t] = ldf(&VTs[(wn * 64 + t * 16 + ln) * 56 + qu * 8]);
      }
#pragma unroll
      for (int ti = 0; ti < 4; ++ti)
#pragma unroll
        for (int tj = 0; tj < 4; ++tj) {
          acc2[ti][tj] = __builtin_amdgcn_mfma_f32_16x16x32_bf16(amh[ti], bv[tj], acc2[ti][tj], 0, 0, 0);
          acc2[ti][tj] = __builtin_amdgcn_mfma_f32_16x16x32_bf16(aml[ti], bv[tj], acc2[ti][tj], 0, 0, 0);
        }
    }
#pragma unroll
    for (int ti = 0; ti < 4; ++ti)
#pragma unroll
      for (int tj = 0; tj < 4; ++tj)
#pragma unroll
        for (int r = 0; r < 4; ++r) {
          const int i = wm * 64 + ti * 16 + qu * 4 + r;
          const int col = half * 128 + wn * 64 + tj * 16 + ln;
          Oh[(size_t)(t0 + i) * 2048 + h * 256 + col] = f2h(acc2[ti][tj][r]);
        }
  }
}

// ---------------------------------------------------------------------------
// gla_inter: serial 16-chunk scan. Grid 256 = (dv-slice 0..7)x(b,h).
// Per chunk: split S->hi/lo; o_inter = QD_c @ S^T-rows (3-combo) RMW'd into
// Oh fp16; W^T = VT @ KET (2-combo, chunk-local LDS transposes of V,KE);
// S = dl (.) (S + W) in fp32 LDS.
__global__ __launch_bounds__(256) void gla_inter(const u16* __restrict__ QKu,
                                                 const u16* __restrict__ V,
                                                 const float* __restrict__ dl,
                                                 u16* __restrict__ Oh) {
  __shared__ float STf[32 * 128];     // 16KB  S (fp32 master), [dv][d]
  __shared__ u16 STh[32 * 136];       // 8.5KB (pad 136 -> 2-way reads)
  __shared__ u16 STl[32 * 136];
  __shared__ u16 QDs0[128 * 32];      // 8KB
  __shared__ u16 QDs1[128 * 32];
  __shared__ u16 KTh[128 * 56];       // 14KB (pad 56)
  __shared__ u16 KTl[128 * 56];
  __shared__ u16 VTs2[32 * 56];       // 3.5KB
  __shared__ float dls[128];
  const int tid = threadIdx.x;
  const int bi = blockIdx.x;
  const int sl = bi >> 5, g = bi & 31, b = g >> 3, h = g & 7;
  const int wave = tid >> 6, lane = tid & 63;
  const int qu = lane >> 4, ln = lane & 15;
  const int crow = tid >> 2, ckof = (tid & 3) << 3;
  const int bh16 = (b * 8 + h) * 16;
  for (int e = tid; e < 4096; e += 256) STf[e] = 0.f;
  for (int c = 0; c < 16; ++c) {
    const int t0 = b * 2048 + c * 128;
    if (tid < 128) dls[tid] = dl[(size_t)(bh16 + c) * 128 + tid];
    __syncthreads();   // B1: dls + STf(zero/update) visible
    if (c > 0) {
      // split S -> hi/lo planes
      for (int e = tid; e < 4096; e += 256) {
        const int row = e >> 7, col = e & 127;
        float v = STf[e];
        u16 hi = f2bf(v);
        STh[row * 136 + col] = hi;
        STl[row * 136 + col] = f2bf(v - bf2f(hi));
      }
      __syncthreads();
      // o_inter = QD_c @ S_prev (3-combo)
      f32x4 aco[2][2] = {};
      for (int kt = 0; kt < 128; kt += 32) {
#pragma unroll
        for (int r = 0; r < 2; ++r) {
          const int row = crow + r * 64;
          const size_t gb = (size_t)(t0 + row) * 4096 + h * 128 + kt + ckof;
          load_lds16(QKu + gb,        QDs0 + (size_t)(r * 256 + wave * 64) * 8);
          load_lds16(QKu + gb + 1024, QDs1 + (size_t)(r * 256 + wave * 64) * 8);
        }
        __syncthreads();
        bf16x8 qh[2], ql[2], sh[2], slo[2];
#pragma unroll
        for (int t = 0; t < 2; ++t) {
          const int ar = wave * 32 + t * 16 + ln;
          qh[t] = ldf(&QDs0[ar * 32 + qu * 8]);
          ql[t] = ldf(&QDs1[ar * 32 + qu * 8]);
          const int br = t * 16 + ln;
          sh[t]  = ldf(&STh[br * 136 + kt + qu * 8]);
          slo[t] = ldf(&STl[br * 136 + kt + qu * 8]);
        }
#pragma unroll
        for (int ti = 0; ti < 2; ++ti)
#pragma unroll
          for (int tj = 0; tj < 2; ++tj) {
            aco[ti][tj] = __builtin_amdgcn_mfma_f32_16x16x32_bf16(qh[ti], sh[tj], aco[ti][tj], 0, 0, 0);
            aco[ti][tj] = __builtin_amdgcn_mfma_f32_16x16x32_bf16(qh[ti], slo[tj], aco[ti][tj], 0, 0, 0);
            aco[ti][tj] = __builtin_amdgcn_mfma_f32_16x16x32_bf16(ql[ti], sh[tj], aco[ti][tj], 0, 0, 0);
          }
        __syncthreads();
      }
      // RMW Oh += o_inter (fp16; each cell owned by exactly one lane)
#pragma unroll
      for (int ti = 0; ti < 2; ++ti)
#pragma unroll
        for (int tj = 0; tj < 2; ++tj)
#pragma unroll
          for (int r = 0; r < 4; ++r) {
            const int i = wave * 32 + ti * 16 + qu * 4 + r;
            const int dv = tj * 16 + ln;
            u16* p = Oh + (size_t)(t0 + i) * 2048 + h * 256 + sl * 32 + dv;
            *p = f2h(h2f(*p) + aco[ti][tj][r]);
          }
    }
    // W^T = VT @ KET (2-combo), K = tokens
    f32x4 acw[2][2] = {};
    for (int kt = 0; kt < 128; kt += 32) {
      __syncthreads();   // prev frag reads done
      {  // stage KE (hi/lo) transposed [d][t], pad 56
        const int t = tid & 31, dg0 = tid >> 5;
#pragma unroll
        for (int rr = 0; rr < 2; ++rr) {
          const int dg = dg0 + rr * 8;
          const size_t gb = (size_t)(t0 + kt + t) * 4096 + 2048 + h * 128 + dg * 8;
          uint4 ph = *(const uint4*)(QKu + gb);
          uint4 pl = *(const uint4*)(QKu + gb + 1024);
          scat8(KTh + (dg * 8) * 56 + t, 56, ph);
          scat8(KTl + (dg * 8) * 56 + t, 56, pl);
        }
        if (tid < 128) {  // stage V slice transposed [dv][t]
          const int t2 = tid & 31, vg = tid >> 5;
          uint4 pv = *(const uint4*)(V + (size_t)(t0 + kt + t2) * 2048 + h * 256 + sl * 32 + vg * 8);
          scat8(VTs2 + (vg * 8) * 56 + t2, 56, pv);
        }
      }
      __syncthreads();
      bf16x8 av[2], kh[2], kl[2];
#pragma unroll
      for (int t = 0; t < 2; ++t) {
        av[t] = ldf(&VTs2[(t * 16 + ln) * 56 + qu * 8]);
        const int dr = wave * 32 + t * 16 + ln;
        kh[t] = ldf(&KTh[dr * 56 + qu * 8]);
        kl[t] = ldf(&KTl[dr * 56 + qu * 8]);
      }
#pragma unroll
      for (int ti = 0; ti < 2; ++ti)
#pragma unroll
        for (int tj = 0; tj < 2; ++tj) {
          acw[ti][tj] = __builtin_amdgcn_mfma_f32_16x16x32_bf16(av[ti], kh[tj], acw[ti][tj], 0, 0, 0);
          acw[ti][tj] = __builtin_amdgcn_mfma_f32_16x16x32_bf16(av[ti], kl[tj], acw[ti][tj], 0, 0, 0);
        }
    }
    // S = dl (.) (S + W)   (each (dv,d) owned by one lane)
#pragma unroll
    for (int ti = 0; ti < 2; ++ti)
#pragma unroll
      for (int tj = 0; tj < 2; ++tj)
#pragma unroll
        for (int r = 0; r < 4; ++r) {
          const int dv = ti * 16 + qu * 4 + r;
          const int d = wave * 32 + tj * 16 + ln;
          const int e = dv * 128 + d;
          STf[e] = dls[d] * (STf[e] + acw[ti][tj][r]);
        }
    __syncthreads();   // B4: S update visible before next chunk's split/dls
  }
}

// ---------------------------------------------------------------------------
// LayerNorm(256) + silu(g) gate; sums via segmented in-wave shuffles
// (head = 32-lane group). Reads o fp16, rewrites IN PLACE as OG bf16.
__global__ __launch_bounds__(256) void ln_gate(u16* __restrict__ O,
                                               const u16* __restrict__ G,
                                               const float* __restrict__ bg) {
  const int tglob = blockIdx.x;        // token row 0..8191
  const int tid = threadIdx.x;
  const int c0 = tid << 3;             // 8 elements per thread
  const size_t base = (size_t)tglob * 2048 + c0;
  ushort4 oa = *(const ushort4*)&O[base];
  ushort4 ob = *(const ushort4*)&O[base + 4];
  float f0 = h2f(oa.x), f1 = h2f(oa.y), f2 = h2f(oa.z), f3 = h2f(oa.w);
  float f4 = h2f(ob.x), f5 = h2f(ob.y), f6 = h2f(ob.z), f7 = h2f(ob.w);
  float s = f0 + f1 + f2 + f3 + f4 + f5 + f6 + f7;
  float ss = f0 * f0 + f1 * f1 + f2 * f2 + f3 * f3 + f4 * f4 + f5 * f5 + f6 * f6 + f7 * f7;
#pragma unroll
  for (int off = 1; off <= 16; off <<= 1) {
    s += __shfl_xor(s, off, 64);
    ss += __shfl_xor(ss, off, 64);
  }
  const float mean = s * (1.f / 256.f);
  const float rstd = rsqrtf(ss * (1.f / 256.f) - mean * mean + 1e-5f);
  ushort4 ga = *(const ushort4*)&G[base];
  ushort4 gb4 = *(const ushort4*)&G[base + 4];
  float4 bga = *(const float4*)&bg[c0];
  float4 bgb = *(const float4*)&bg[c0 + 4];
  auto one = [&](float ov, u16 gu, float bgv) -> u16 {
    float gg = bf2f(gu) + bgv;
    return f2bf((ov - mean) * rstd * (gg / (1.f + expf(-gg))));
  };
  ushort4 ra, rb;
  ra.x = one(f0, ga.x, bga.x);  ra.y = one(f1, ga.y, bga.y);
  ra.z = one(f2, ga.z, bga.z);  ra.w = one(f3, ga.w, bga.w);
  rb.x = one(f4, gb4.x, bgb.x); rb.y = one(f5, gb4.y, bgb.y);
  rb.z = one(f6, gb4.z, bgb.z); rb.w = one(f7, gb4.w, bgb.w);
  *(ushort4*)&O[base] = ra;
  *(ushort4*)&O[base + 4] = rb;
}

// ---------------------------------------------------------------------------
extern "C" void kernel_launch(void* const* d_in, const int* in_sizes, int n_in,
                              void* d_out, int out_size, void* d_ws, size_t ws_size,
                              hipStream_t stream) {
  (void)in_sizes; (void)n_in; (void)out_size;
  if (ws_size < 117964800ull) return;   // fail soft

  const float* x    = (const float*)d_in[0];
  const float* Wq   = (const float*)d_in[1];
  const float* Wk   = (const float*)d_in[2];
  const float* Wkg1 = (const float*)d_in[3];
  const float* Wkg2 = (const float*)d_in[4];
  const float* bkg2 = (const float*)d_in[5];
  const float* Wv   = (const float*)d_in[6];
  const float* Wg   = (const float*)d_in[7];
  const float* bg   = (const float*)d_in[8];
  const float* Wo   = (const float*)d_in[9];

  char* ws = (char*)d_ws;
  float* QK  = (float*)(ws + 0);           // 64 MiB fp32 -> decorated u16 planes
  u16*   QKu = (u16*)QK;
  u16*   V   = (u16*)(ws + 67108864);      // 32 MiB bf16
  u16*   WtA = (u16*)(ws + 100663296);     //  8 MiB hi
  u16*   WtB = (u16*)(ws + 109051904);     //  8 MiB lo
  float* xg1 = (float*)(ws + 117440512);   // 0.5 MiB
  float* Cf  = QK;                         // final GEMM C (decorated dead by then)
  // dl lives in the WtB region (idle between G-gemm and Wo transpose)
  float* dl  = (float*)(ws + 109051904);   // 256 KiB

  u16* G  = (u16*)d_out;                   // d_out [0,32Mi)
  u16* Oh = (u16*)d_out + 16777216;        // d_out [32Mi,64Mi): o fp16 -> OG bf16

  dim3 tb(32, 8);

  xg1_gemm<<<dim3(128), dim3(256), 0, stream>>>(x, Wkg1, xg1);

  // [q|k] pair projection, fp32 out (Wk folded with (D/H)^-0.5 = 1/16)
  tpose_pair<<<dim3(32, 64), tb, 0, stream>>>(Wq, WtA,               WtB,               2048, 1024, 1.0f);
  tpose_pair<<<dim3(32, 64), tb, 0, stream>>>(Wk, WtA + 1024 * 2048, WtB + 1024 * 2048, 2048, 1024, 0.0625f);
  gemm_f32a<3, 1><<<dim3(16, 64), dim3(256), 0, stream>>>(x, WtA, WtB, (void*)QK, 8192, 2048, 2048);

  // v pair projection, bf16 out
  tpose_pair<<<dim3(64, 64), tb, 0, stream>>>(Wv, WtA, WtB, 2048, 2048, 1.0f);
  gemm_f32a<3, 0><<<dim3(16, 64), dim3(256), 0, stream>>>(x, WtA, WtB, (void*)V, 8192, 2048, 2048);

  // g projection (plain bf16 quality suffices for the gate)
  tpose_pair<<<dim3(64, 64), tb, 0, stream>>>(Wg, WtA, WtB, 2048, 2048, 1.0f);
  gemm_f32a<1, 0><<<dim3(16, 64), dim3(256), 0, stream>>>(x, WtA, WtA, (void*)G, 8192, 2048, 2048);

  // chunked GLA on MFMA
  gla_decor<<<dim3(64), dim3(1024), 0, stream>>>(QK, xg1, Wkg2, bkg2, dl);
  gla_intra<<<dim3(512), dim3(256), 0, stream>>>(QKu, V, Oh);
  gla_inter<<<dim3(256), dim3(256), 0, stream>>>(QKu, V, dl, Oh);
  ln_gate<<<dim3(8192), dim3(256), 0, stream>>>(Oh, G, bg);

  // final projection: OG bf16 @ Wo^T -> fp32, then d2d to d_out
  tpose_pair<<<dim3(64, 64), tb, 0, stream>>>(Wo, WtA, WtB, 2048, 2048, 1.0f);
  gemm_bt<<<dim3(16, 64), dim3(256), 0, stream>>>(Oh, WtA, Cf, 8192, 2048, 2048);
  hipMemcpyAsync(d_out, Cf, 67108864ull, hipMemcpyDeviceToDevice, stream);
}

// Round 3
// 1313.570 us; speedup vs baseline: 2.9226x; 1.0863x over previous
//
#include <hip/hip_runtime.h>
#include <stdint.h>

// ---------------------------------------------------------------------------
// GatedLinearAttention (b=4, T=2048, D=2048, H=8, dk=128, dv=256, CHUNK=128)
// Round: parallel gla_decor via interleaved hi/lo in-place layout.
// Decorated QK row (4096 u16 = 8192 B, same bytes as the fp32 row):
//   u32[c]        = QDh(c) | QDl(c)<<16   c in 0..1023   (q half)
//   u32[1024+c]   = KEh(c) | KEl(c)<<16                  (k half)
// Every decor thread reads+writes ONLY its own 4 bytes -> column-split blocks
// are race-free: grid 512 = (b,chunk) x 8 head-groups (was 64 blocks / 316us).
// Consumers unpack hi/lo at frag-read time via v_perm_b32; LDS staging windows
// are source-swizzled (chunk ^= row&7) so interleaved ds_read_b128 stays 2-way.
//
// ws layout (112.5 MiB guard unchanged):
//   QK [0,64Mi)      fp32 [q | k/16] [8192][2048] -> interleaved u32 planes
//   V  [64Mi,96Mi)   bf16 [8192][2048]
//   WtA [96Mi,104Mi) weight^T hi-plane; WtB [104Mi,112Mi) lo-plane
//   dl  at WtB base (idle between G-gemm and Wo-transpose), 256KB fp32
//   xg1 [112Mi,+512K)
// d_out scratch: G bf16 [0,32Mi); o fp16 -> OG bf16 [32Mi,64Mi); final C last.
// ---------------------------------------------------------------------------

typedef unsigned short u16;
typedef unsigned int u32;
typedef __bf16 bf16x8 __attribute__((ext_vector_type(8)));
typedef float f32x4 __attribute__((ext_vector_type(4)));

__device__ __forceinline__ u16 f2bf(float f) {
  u32 u = __float_as_uint(f);
  u32 r = (u + 0x7fffu + ((u >> 16) & 1u)) >> 16;   // RNE
  return (u16)r;
}
__device__ __forceinline__ float bf2f(u16 s) {
  return __uint_as_float(((u32)s) << 16);
}
__device__ __forceinline__ u16 f2h(float f) {
  _Float16 h = (_Float16)f;                          // RNE fp32->fp16
  return __builtin_bit_cast(u16, h);
}
__device__ __forceinline__ float h2f(u16 u) {
  return (float)__builtin_bit_cast(_Float16, u);
}

// async global->LDS, 16B/lane. LDS dest = wave-uniform base + lane*16.
__device__ __forceinline__ void load_lds16(const void* g, void* l) {
  auto gp = (const __attribute__((address_space(1))) u32*)(uintptr_t)g;
  auto lp = (__attribute__((address_space(3))) u32*)(u32)(uintptr_t)l;
  __builtin_amdgcn_global_load_lds(gp, lp, 16, 0, 0);
}
__device__ __forceinline__ bf16x8 ldf(const u16* p) { return *(const bf16x8*)p; }

// unpack 8 interleaved (hi,lo) u16 pairs (two uint4) -> hi/lo bf16x8 vectors
__device__ __forceinline__ void unpk(uint4 w0, uint4 w1, bf16x8& hi, bf16x8& lo) {
  union U { uint4 u; bf16x8 v; } a, b;
  a.u.x = __builtin_amdgcn_perm(w0.y, w0.x, 0x05040100u);
  a.u.y = __builtin_amdgcn_perm(w0.w, w0.z, 0x05040100u);
  a.u.z = __builtin_amdgcn_perm(w1.y, w1.x, 0x05040100u);
  a.u.w = __builtin_amdgcn_perm(w1.w, w1.z, 0x05040100u);
  b.u.x = __builtin_amdgcn_perm(w0.y, w0.x, 0x07060302u);
  b.u.y = __builtin_amdgcn_perm(w0.w, w0.z, 0x07060302u);
  b.u.z = __builtin_amdgcn_perm(w1.y, w1.x, 0x07060302u);
  b.u.w = __builtin_amdgcn_perm(w1.w, w1.z, 0x07060302u);
  hi = a.v;
  lo = b.v;
}

// ---------------------------------------------------------------------------
// weight transpose + hi/lo bf16 split
__global__ __launch_bounds__(256) void tpose_pair(const float* __restrict__ src,
                                                  u16* __restrict__ dhi,
                                                  u16* __restrict__ dlo,
                                                  int srcRows, int srcStride,
                                                  float scale) {
  __shared__ float tile[32][33];
  const int tx = threadIdx.x, ty = threadIdx.y;     // block (32,8)
  const int n0 = blockIdx.x * 32, k0 = blockIdx.y * 32;
#pragma unroll
  for (int j = 0; j < 4; ++j) {
    int k = k0 + ty + j * 8;
    tile[ty + j * 8][tx] = src[(size_t)k * srcStride + n0 + tx] * scale;
  }
  __syncthreads();
#pragma unroll
  for (int j = 0; j < 4; ++j) {
    int n = n0 + ty + j * 8;
    float f = tile[tx][ty + j * 8];
    u16 h = f2bf(f);
    size_t idx = (size_t)n * srcRows + k0 + tx;
    dhi[idx] = h;
    dlo[idx] = f2bf(f - bf2f(h));
  }
}

// ---------------------------------------------------------------------------
// Pair GEMM: C[M,N] = A_f32[M,K] @ (Bhi+Blo)[N,K]^T, in-kernel A hi/lo split.
template <int COMBOS, int OUTF32>
__global__ __launch_bounds__(256) void gemm_f32a(const float* __restrict__ A,
                                                 const u16* __restrict__ Bhi,
                                                 const u16* __restrict__ Blo,
                                                 void* __restrict__ C,
                                                 int M, int N, int K) {
  __shared__ u16 Ah[128 * 32];
  __shared__ u16 Al[128 * 32];
  __shared__ u16 Bh[128 * 32];
  __shared__ u16 Bl[128 * 32];
  const int tid = threadIdx.x;
  const int wave = tid >> 6, lane = tid & 63;
  const int wm = wave >> 1, wn = wave & 1;
  const int qu = lane >> 4, ln = lane & 15;
  const int m0 = blockIdx.y * 128, n0 = blockIdx.x * 128;
  const int arow = tid >> 1, akof = (tid & 1) << 4;
  const int crow = tid >> 2, ckof = (tid & 3) << 3;
  f32x4 acc[4][4] = {};
  for (int kt = 0; kt < K; kt += 32) {
#pragma unroll
    for (int r = 0; r < 2; ++r) {
      const int row = crow + r * 64;
      load_lds16(Bhi + (size_t)(n0 + row) * K + kt + ckof, Bh + (size_t)(r * 256 + wave * 64) * 8);
      if (COMBOS == 3)
        load_lds16(Blo + (size_t)(n0 + row) * K + kt + ckof, Bl + (size_t)(r * 256 + wave * 64) * 8);
    }
    {
      const float* src = A + (size_t)(m0 + arow) * K + kt + akof;
      float va[16];
#pragma unroll
      for (int j = 0; j < 16; j += 4) {
        float4 f4 = *(const float4*)(src + j);
        va[j] = f4.x; va[j + 1] = f4.y; va[j + 2] = f4.z; va[j + 3] = f4.w;
      }
      u16 hi[16], lo[16];
#pragma unroll
      for (int j = 0; j < 16; ++j) {
        hi[j] = f2bf(va[j]);
        lo[j] = f2bf(va[j] - bf2f(hi[j]));
      }
      u32 ph[8];
#pragma unroll
      for (int j = 0; j < 8; ++j) ph[j] = (u32)hi[2 * j] | ((u32)hi[2 * j + 1] << 16);
      *(uint4*)&Ah[arow * 32 + akof] = make_uint4(ph[0], ph[1], ph[2], ph[3]);
      *(uint4*)&Ah[arow * 32 + akof + 8] = make_uint4(ph[4], ph[5], ph[6], ph[7]);
      if (COMBOS == 3) {
#pragma unroll
        for (int j = 0; j < 8; ++j) ph[j] = (u32)lo[2 * j] | ((u32)lo[2 * j + 1] << 16);
        *(uint4*)&Al[arow * 32 + akof] = make_uint4(ph[0], ph[1], ph[2], ph[3]);
        *(uint4*)&Al[arow * 32 + akof + 8] = make_uint4(ph[4], ph[5], ph[6], ph[7]);
      }
    }
    __syncthreads();
    bf16x8 ah[4], bh[4], al[4], bl[4];
#pragma unroll
    for (int t = 0; t < 4; ++t) {
      ah[t] = ldf(&Ah[(wm * 64 + t * 16 + ln) * 32 + qu * 8]);
      bh[t] = ldf(&Bh[(wn * 64 + t * 16 + ln) * 32 + qu * 8]);
      if (COMBOS == 3) {
        al[t] = ldf(&Al[(wm * 64 + t * 16 + ln) * 32 + qu * 8]);
        bl[t] = ldf(&Bl[(wn * 64 + t * 16 + ln) * 32 + qu * 8]);
      }
    }
#pragma unroll
    for (int ti = 0; ti < 4; ++ti)
#pragma unroll
      for (int tj = 0; tj < 4; ++tj) {
        acc[ti][tj] = __builtin_amdgcn_mfma_f32_16x16x32_bf16(ah[ti], bh[tj], acc[ti][tj], 0, 0, 0);
        if (COMBOS == 3) {
          acc[ti][tj] = __builtin_amdgcn_mfma_f32_16x16x32_bf16(ah[ti], bl[tj], acc[ti][tj], 0, 0, 0);
          acc[ti][tj] = __builtin_amdgcn_mfma_f32_16x16x32_bf16(al[ti], bh[tj], acc[ti][tj], 0, 0, 0);
        }
      }
    __syncthreads();
  }
#pragma unroll
  for (int ti = 0; ti < 4; ++ti)
#pragma unroll
    for (int tj = 0; tj < 4; ++tj) {
      const int rowb = m0 + wm * 64 + ti * 16 + qu * 4;
      const int col = n0 + wn * 64 + tj * 16 + ln;
#pragma unroll
      for (int r = 0; r < 4; ++r) {
        size_t idx = (size_t)(rowb + r) * N + col;
        if (OUTF32) ((float*)C)[idx] = acc[ti][tj][r];
        else        ((u16*)C)[idx] = f2bf(acc[ti][tj][r]);
      }
    }
}

// ---------------------------------------------------------------------------
// Plain bf16-A GEMM (final projection)
__global__ __launch_bounds__(256) void gemm_bt(const u16* __restrict__ A,
                                               const u16* __restrict__ Bt,
                                               float* __restrict__ C,
                                               int M, int N, int K) {
  __shared__ u16 As[128 * 32];
  __shared__ u16 Bs[128 * 32];
  const int tid = threadIdx.x;
  const int wave = tid >> 6, lane = tid & 63;
  const int wm = wave >> 1, wn = wave & 1;
  const int qu = lane >> 4, ln = lane & 15;
  const int m0 = blockIdx.y * 128, n0 = blockIdx.x * 128;
  const int crow = tid >> 2, ckof = (tid & 3) << 3;
  f32x4 acc[4][4] = {};
  for (int kt = 0; kt < K; kt += 32) {
#pragma unroll
    for (int r = 0; r < 2; ++r) {
      const int row = crow + r * 64;
      load_lds16(A + (size_t)(m0 + row) * K + kt + ckof, As + (size_t)(r * 256 + wave * 64) * 8);
      load_lds16(Bt + (size_t)(n0 + row) * K + kt + ckof, Bs + (size_t)(r * 256 + wave * 64) * 8);
    }
    __syncthreads();
    bf16x8 af[4], bfr[4];
#pragma unroll
    for (int t = 0; t < 4; ++t) {
      af[t] = ldf(&As[(wm * 64 + t * 16 + ln) * 32 + qu * 8]);
      bfr[t] = ldf(&Bs[(wn * 64 + t * 16 + ln) * 32 + qu * 8]);
    }
#pragma unroll
    for (int ti = 0; ti < 4; ++ti)
#pragma unroll
      for (int tj = 0; tj < 4; ++tj)
        acc[ti][tj] = __builtin_amdgcn_mfma_f32_16x16x32_bf16(af[ti], bfr[tj], acc[ti][tj], 0, 0, 0);
    __syncthreads();
  }
#pragma unroll
  for (int ti = 0; ti < 4; ++ti)
#pragma unroll
    for (int tj = 0; tj < 4; ++tj) {
      const int rowb = m0 + wm * 64 + ti * 16 + qu * 4;
      const int col = n0 + wn * 64 + tj * 16 + ln;
#pragma unroll
      for (int r = 0; r < 4; ++r)
        C[(size_t)(rowb + r) * N + col] = acc[ti][tj][r];
    }
}

// ---------------------------------------------------------------------------
// xg1[8192,16] = x[8192,2048] @ Wkg1[2048,16]   (fp32, tiled)
__global__ __launch_bounds__(256) void xg1_gemm(const float* __restrict__ x,
                                                const float* __restrict__ W1,
                                                float* __restrict__ xg1) {
  __shared__ float xs[64][40];
  __shared__ float ws2[32][16];
  const int tid = threadIdx.x;
  const int r0 = blockIdx.x * 64;
  const int col = tid & 15, rsub = tid >> 4;
  float acc[4] = {0.f, 0.f, 0.f, 0.f};
  for (int kt = 0; kt < 2048; kt += 32) {
#pragma unroll
    for (int j = 0; j < 2; ++j) {
      int c = j * 256 + tid;
      int row = c >> 3, kk = (c & 7) << 2;
      *(float4*)&xs[row][kk] = *(const float4*)&x[(size_t)(r0 + row) * 2048 + kt + kk];
    }
#pragma unroll
    for (int j = 0; j < 2; ++j) {
      int c = j * 256 + tid;
      ws2[c >> 4][c & 15] = W1[(size_t)(kt + (c >> 4)) * 16 + (c & 15)];
    }
    __syncthreads();
#pragma unroll
    for (int kk = 0; kk < 32; ++kk) {
      float wv = ws2[kk][col];
#pragma unroll
      for (int j = 0; j < 4; ++j) acc[j] += xs[rsub + j * 16][kk] * wv;
    }
    __syncthreads();
  }
#pragma unroll
  for (int j = 0; j < 4; ++j) xg1[(size_t)(r0 + rsub + j * 16) * 16 + col] = acc[j];
}

// ---------------------------------------------------------------------------
// gla_decor: grid 512 = (b * 16 + n) * 8 + headgroup; 256 threads =
// 128 q-cols + 128 k-cols of that head. Each thread reads its fp32 value and
// overwrites THE SAME 4 bytes with (hi | lo<<16) -> fully race-free in-place.
// gk cumsum duplicated on q and k threads (16 FMA + logsig per token, cheap).
__global__ __launch_bounds__(256) void gla_decor(float* __restrict__ QK,
                                                 const float* __restrict__ xg1,
                                                 const float* __restrict__ W2,
                                                 const float* __restrict__ b2,
                                                 float* __restrict__ dl) {
  __shared__ float xg1s[128][16];   // 8KB
  const int tid = threadIdx.x;
  const int bi = blockIdx.x;
  const int b = bi >> 7, n = (bi >> 3) & 15, g = bi & 7;
  const int t0 = b * 2048 + n * 128;
  const bool isK = tid >= 128;
  const int ci = tid & 127;
  const int col = g * 128 + ci;            // global col 0..1023
  u32* base = (u32*)QK + (size_t)t0 * 2048 + (isK ? 1024 : 0) + col;
  float w2r[16];
#pragma unroll
  for (int k = 0; k < 16; ++k) w2r[k] = W2[k * 1024 + col];
  const float b2r = b2[col];
  for (int e = tid; e < 2048; e += 256)
    xg1s[e >> 4][e & 15] = xg1[(size_t)(t0 + (e >> 4)) * 16 + (e & 15)];
  __syncthreads();
  float acc = 0.f;
  const float sgn = isK ? -1.f : 1.f;
  for (int s = 0; s < 128; s += 16) {
    float qv[16];
#pragma unroll
    for (int j = 0; j < 16; ++j) qv[j] = __uint_as_float(base[(size_t)(s + j) * 2048]);
    u32 ov[16];
#pragma unroll
    for (int j = 0; j < 16; ++j) {
      float z = b2r;
#pragma unroll
      for (int kk = 0; kk < 16; ++kk) z += xg1s[s + j][kk] * w2r[kk];
      float gk = (fminf(z, 0.f) - log1pf(expf(-fabsf(z)))) * 0.0625f;
      acc += gk;
      float e = expf(sgn * acc);
      float v = qv[j] * e;
      u16 h = f2bf(v);
      u16 l = f2bf(v - bf2f(h));
      ov[j] = (u32)h | ((u32)l << 16);
    }
#pragma unroll
    for (int j = 0; j < 16; ++j) base[(size_t)(s + j) * 2048] = ov[j];
  }
  if (isK) dl[((size_t)(b * 8 + g) * 16 + n) * 128 + ci] = expf(acc);
}

// ---------------------------------------------------------------------------
// gla_intra: per (b,h,chunk): A = tril(QD@KE^T) (3-combo), o_intra = A@V^T
// (2-combo) -> Oh fp16. Q/K staged as interleaved windows, source-swizzled
// (chunk ^ row&7); frag reads unpack hi/lo via v_perm (2-way bank aliasing).
__global__ __launch_bounds__(256) void gla_intra(const u16* __restrict__ QKu,
                                                 const u16* __restrict__ V,
                                                 u16* __restrict__ Oh) {
  // pool: stage Qi [0,8192) u16, Ki [8192,16384); Amh [0,16384) Aml [16384,32768);
  //       VTs [32768, 32768+7168) = [128][56] u16 pad
  __shared__ u16 pool[39936];   // 79872 B -> 2 blocks/CU
  const int tid = threadIdx.x;
  const int bi = blockIdx.x;
  const int n = bi & 15, h = (bi >> 4) & 7, b = bi >> 7;
  const int t0 = b * 2048 + n * 128;
  const int wave = tid >> 6, lane = tid & 63;
  const int wm = wave >> 1, wn = wave & 1;
  const int qu = lane >> 4, ln = lane & 15;
  const int srow = tid >> 3, schk = tid & 7;
  const int sc = ((schk ^ (srow & 7)) << 3);   // swizzled source u16 offset
  u16* Qi = pool;
  u16* Ki = pool + 8192;
  u16* Amh = pool;
  u16* Aml = pool + 16384;
  u16* VTs = pool + 32768;
  // ---- phase A: A = QD @ KE^T  (3-combo hi/lo)
  f32x4 acc[4][4] = {};
  for (int kt = 0; kt < 128; kt += 32) {
#pragma unroll
    for (int r = 0; r < 4; ++r) {
      const int row = srow + r * 32;
      const size_t gb = (size_t)(t0 + row) * 4096 + h * 256 + 2 * kt + sc;
      load_lds16(QKu + gb,        Qi + (r * 32 + wave * 8) * 64);
      load_lds16(QKu + gb + 2048, Ki + (r * 32 + wave * 8) * 64);
    }
    __syncthreads();
    bf16x8 ah[4], al[4], bh[4], bl[4];
#pragma unroll
    for (int t = 0; t < 4; ++t) {
      const int i = wm * 64 + t * 16 + ln;
      const u16* pQ = &Qi[i * 64];
      uint4 w0 = *(const uint4*)&pQ[((2 * qu) ^ (i & 7)) << 3];
      uint4 w1 = *(const uint4*)&pQ[((2 * qu + 1) ^ (i & 7)) << 3];
      unpk(w0, w1, ah[t], al[t]);
      const int j = wn * 64 + t * 16 + ln;
      const u16* pK = &Ki[j * 64];
      uint4 y0 = *(const uint4*)&pK[((2 * qu) ^ (j & 7)) << 3];
      uint4 y1 = *(const uint4*)&pK[((2 * qu + 1) ^ (j & 7)) << 3];
      unpk(y0, y1, bh[t], bl[t]);
    }
#pragma unroll
    for (int ti = 0; ti < 4; ++ti)
#pragma unroll
      for (int tj = 0; tj < 4; ++tj) {
        acc[ti][tj] = __builtin_amdgcn_mfma_f32_16x16x32_bf16(ah[ti], bh[tj], acc[ti][tj], 0, 0, 0);
        acc[ti][tj] = __builtin_amdgcn_mfma_f32_16x16x32_bf16(ah[ti], bl[tj], acc[ti][tj], 0, 0, 0);
        acc[ti][tj] = __builtin_amdgcn_mfma_f32_16x16x32_bf16(al[ti], bh[tj], acc[ti][tj], 0, 0, 0);
      }
    __syncthreads();
  }
  // ---- phase B: causal mask + hi/lo split -> Am (swizzled), aliases stage
#pragma unroll
  for (int ti = 0; ti < 4; ++ti)
#pragma unroll
    for (int tj = 0; tj < 4; ++tj) {
      const int ib = wm * 64 + ti * 16 + qu * 4;
      const int j = wn * 64 + tj * 16 + ln;
#pragma unroll
      for (int r = 0; r < 4; ++r) {
        const int i = ib + r;
        float v = (j <= i) ? acc[ti][tj][r] : 0.f;
        u16 hi = f2bf(v);
        const int idx = i * 128 + (j ^ ((i & 15) << 3));
        Amh[idx] = hi;
        Aml[idx] = f2bf(v - bf2f(hi));
      }
    }
  // ---- phase C: o_intra = Am @ V^T (2-combo), two dv-halves of 128
  for (int half = 0; half < 2; ++half) {
    f32x4 acc2[4][4] = {};
    for (int kt = 0; kt < 128; kt += 32) {
      __syncthreads();   // Am visible (first iter) / prev VTs reads done
      {  // stage VTs[dv][t] transposed from V, pad 56
        const int j = tid & 31, dvg = tid >> 5;
#pragma unroll
        for (int rr = 0; rr < 2; ++rr) {
          const int dg = dvg + rr * 8;
          uint4 pv = *(const uint4*)(V + (size_t)(t0 + kt + j) * 2048 + h * 256 + half * 128 + dg * 8);
          u16* dst = VTs + (dg * 8) * 56 + j;
          dst[0]      = (u16)pv.x; dst[56]      = (u16)(pv.x >> 16);
          dst[2 * 56] = (u16)pv.y; dst[3 * 56]  = (u16)(pv.y >> 16);
          dst[4 * 56] = (u16)pv.z; dst[5 * 56]  = (u16)(pv.z >> 16);
          dst[6 * 56] = (u16)pv.w; dst[7 * 56]  = (u16)(pv.w >> 16);
        }
      }
      __syncthreads();
      bf16x8 amh[4], aml[4], bv[4];
#pragma unroll
      for (int t = 0; t < 4; ++t) {
        const int i = wm * 64 + t * 16 + ln;
        const int cof = (kt + qu * 8) ^ ((i & 15) << 3);
        amh[t] = ldf(&Amh[i * 128 + cof]);
        aml[t] = ldf(&Aml[i * 128 + cof]);
        bv[t] = ldf(&VTs[(wn * 64 + t * 16 + ln) * 56 + qu * 8]);
      }
#pragma unroll
      for (int ti = 0; ti < 4; ++ti)
#pragma unroll
        for (int tj = 0; tj < 4; ++tj) {
          acc2[ti][tj] = __builtin_amdgcn_mfma_f32_16x16x32_bf16(amh[ti], bv[tj], acc2[ti][tj], 0, 0, 0);
          acc2[ti][tj] = __builtin_amdgcn_mfma_f32_16x16x32_bf16(aml[ti], bv[tj], acc2[ti][tj], 0, 0, 0);
        }
    }
#pragma unroll
    for (int ti = 0; ti < 4; ++ti)
#pragma unroll
      for (int tj = 0; tj < 4; ++tj)
#pragma unroll
        for (int r = 0; r < 4; ++r) {
          const int i = wm * 64 + ti * 16 + qu * 4 + r;
          const int col = half * 128 + wn * 64 + tj * 16 + ln;
          Oh[(size_t)(t0 + i) * 2048 + h * 256 + col] = f2h(acc2[ti][tj][r]);
        }
  }
}

// ---------------------------------------------------------------------------
// gla_inter: serial 16-chunk scan. Grid 256 = (dv-slice 0..7)x(b,h).
// Per chunk: split S->hi/lo; o_inter = QD_c @ S^T-rows (3-combo) RMW'd into
// Oh fp16; W^T = VT @ KET (2-combo, chunk-local LDS transposes of V,KE);
// S = dl (.) (S + W) in fp32 LDS. QD staged interleaved+swizzled, perm-unpack.
__global__ __launch_bounds__(256) void gla_inter(const u16* __restrict__ QKu,
                                                 const u16* __restrict__ V,
                                                 const float* __restrict__ dl,
                                                 u16* __restrict__ Oh) {
  __shared__ float STf[32 * 128];     // 16KB  S (fp32 master), [dv][d]
  __shared__ u16 STh[32 * 136];       // 8.5KB (pad 136 -> 2-way reads)
  __shared__ u16 STl[32 * 136];
  __shared__ u16 Qi2[128 * 64];       // 16KB interleaved QD window
  __shared__ u16 KTh[128 * 56];       // 14KB (pad 56)
  __shared__ u16 KTl[128 * 56];
  __shared__ u16 VTs2[32 * 56];       // 3.5KB
  __shared__ float dls[128];
  const int tid = threadIdx.x;
  const int bi = blockIdx.x;
  const int sl = bi >> 5, g = bi & 31, b = g >> 3, h = g & 7;
  const int wave = tid >> 6, lane = tid & 63;
  const int qu = lane >> 4, ln = lane & 15;
  const int srow = tid >> 3, schk = tid & 7;
  const int sc = ((schk ^ (srow & 7)) << 3);
  const int bh16 = (b * 8 + h) * 16;
  for (int e = tid; e < 4096; e += 256) STf[e] = 0.f;
  for (int c = 0; c < 16; ++c) {
    const int t0 = b * 2048 + c * 128;
    if (tid < 128) dls[tid] = dl[(size_t)(bh16 + c) * 128 + tid];
    __syncthreads();   // B1: dls + STf(zero/update) visible
    if (c > 0) {
      // split S -> hi/lo planes
      for (int e = tid; e < 4096; e += 256) {
        const int row = e >> 7, col = e & 127;
        float v = STf[e];
        u16 hi = f2bf(v);
        STh[row * 136 + col] = hi;
        STl[row * 136 + col] = f2bf(v - bf2f(hi));
      }
      __syncthreads();
      // o_inter = QD_c @ S_prev (3-combo)
      f32x4 aco[2][2] = {};
      for (int kt = 0; kt < 128; kt += 32) {
#pragma unroll
        for (int r = 0; r < 4; ++r) {
          const int row = srow + r * 32;
          load_lds16(QKu + (size_t)(t0 + row) * 4096 + h * 256 + 2 * kt + sc,
                     Qi2 + (r * 32 + wave * 8) * 64);
        }
        __syncthreads();
        bf16x8 qh[2], ql[2], sh[2], slo[2];
#pragma unroll
        for (int t = 0; t < 2; ++t) {
          const int ar = wave * 32 + t * 16 + ln;
          const u16* pQ = &Qi2[ar * 64];
          uint4 w0 = *(const uint4*)&pQ[((2 * qu) ^ (ar & 7)) << 3];
          uint4 w1 = *(const uint4*)&pQ[((2 * qu + 1) ^ (ar & 7)) << 3];
          unpk(w0, w1, qh[t], ql[t]);
          const int br = t * 16 + ln;
          sh[t]  = ldf(&STh[br * 136 + kt + qu * 8]);
          slo[t] = ldf(&STl[br * 136 + kt + qu * 8]);
        }
#pragma unroll
        for (int ti = 0; ti < 2; ++ti)
#pragma unroll
          for (int tj = 0; tj < 2; ++tj) {
            aco[ti][tj] = __builtin_amdgcn_mfma_f32_16x16x32_bf16(qh[ti], sh[tj], aco[ti][tj], 0, 0, 0);
            aco[ti][tj] = __builtin_amdgcn_mfma_f32_16x16x32_bf16(qh[ti], slo[tj], aco[ti][tj], 0, 0, 0);
            aco[ti][tj] = __builtin_amdgcn_mfma_f32_16x16x32_bf16(ql[ti], sh[tj], aco[ti][tj], 0, 0, 0);
          }
        __syncthreads();
      }
      // RMW Oh += o_inter (fp16; each cell owned by exactly one lane)
#pragma unroll
      for (int ti = 0; ti < 2; ++ti)
#pragma unroll
        for (int tj = 0; tj < 2; ++tj)
#pragma unroll
          for (int r = 0; r < 4; ++r) {
            const int i = wave * 32 + ti * 16 + qu * 4 + r;
            const int dv = tj * 16 + ln;
            u16* p = Oh + (size_t)(t0 + i) * 2048 + h * 256 + sl * 32 + dv;
            *p = f2h(h2f(*p) + aco[ti][tj][r]);
          }
    }
    // W^T = VT @ KET (2-combo), K = tokens
    f32x4 acw[2][2] = {};
    for (int kt = 0; kt < 128; kt += 32) {
      __syncthreads();   // prev frag reads done
      {  // stage KE (hi/lo from interleaved) transposed [d][t], pad 56
        const int t = tid & 31, dg0 = tid >> 5;
#pragma unroll
        for (int rr = 0; rr < 2; ++rr) {
          const int dg = dg0 + rr * 8;
          const size_t gb = (size_t)(t0 + kt + t) * 4096 + 2048 + h * 256 + dg * 16;
          uint4 w0 = *(const uint4*)(QKu + gb);
          uint4 w1 = *(const uint4*)(QKu + gb + 8);
          u16* dh = KTh + (dg * 8) * 56 + t;
          u16* dL = KTl + (dg * 8) * 56 + t;
          dh[0]      = (u16)w0.x; dL[0]      = (u16)(w0.x >> 16);
          dh[56]     = (u16)w0.y; dL[56]     = (u16)(w0.y >> 16);
          dh[2 * 56] = (u16)w0.z; dL[2 * 56] = (u16)(w0.z >> 16);
          dh[3 * 56] = (u16)w0.w; dL[3 * 56] = (u16)(w0.w >> 16);
          dh[4 * 56] = (u16)w1.x; dL[4 * 56] = (u16)(w1.x >> 16);
          dh[5 * 56] = (u16)w1.y; dL[5 * 56] = (u16)(w1.y >> 16);
          dh[6 * 56] = (u16)w1.z; dL[6 * 56] = (u16)(w1.z >> 16);
          dh[7 * 56] = (u16)w1.w; dL[7 * 56] = (u16)(w1.w >> 16);
        }
        if (tid < 128) {  // stage V slice transposed [dv][t]
          const int t2 = tid & 31, vg = tid >> 5;
          uint4 pv = *(const uint4*)(V + (size_t)(t0 + kt + t2) * 2048 + h * 256 + sl * 32 + vg * 8);
          u16* dst = VTs2 + (vg * 8) * 56 + t2;
          dst[0]      = (u16)pv.x; dst[56]     = (u16)(pv.x >> 16);
          dst[2 * 56] = (u16)pv.y; dst[3 * 56] = (u16)(pv.y >> 16);
          dst[4 * 56] = (u16)pv.z; dst[5 * 56] = (u16)(pv.z >> 16);
          dst[6 * 56] = (u16)pv.w; dst[7 * 56] = (u16)(pv.w >> 16);
        }
      }
      __syncthreads();
      bf16x8 av[2], kh[2], kl[2];
#pragma unroll
      for (int t = 0; t < 2; ++t) {
        av[t] = ldf(&VTs2[(t * 16 + ln) * 56 + qu * 8]);
        const int dr = wave * 32 + t * 16 + ln;
        kh[t] = ldf(&KTh[dr * 56 + qu * 8]);
        kl[t] = ldf(&KTl[dr * 56 + qu * 8]);
      }
#pragma unroll
      for (int ti = 0; ti < 2; ++ti)
#pragma unroll
        for (int tj = 0; tj < 2; ++tj) {
          acw[ti][tj] = __builtin_amdgcn_mfma_f32_16x16x32_bf16(av[ti], kh[tj], acw[ti][tj], 0, 0, 0);
          acw[ti][tj] = __builtin_amdgcn_mfma_f32_16x16x32_bf16(av[ti], kl[tj], acw[ti][tj], 0, 0, 0);
        }
    }
    // S = dl (.) (S + W)   (each (dv,d) owned by one lane)
#pragma unroll
    for (int ti = 0; ti < 2; ++ti)
#pragma unroll
      for (int tj = 0; tj < 2; ++tj)
#pragma unroll
        for (int r = 0; r < 4; ++r) {
          const int dv = ti * 16 + qu * 4 + r;
          const int d = wave * 32 + tj * 16 + ln;
          const int e = dv * 128 + d;
          STf[e] = dls[d] * (STf[e] + acw[ti][tj][r]);
        }
    __syncthreads();   // B4: S update visible before next chunk's split/dls
  }
}

// ---------------------------------------------------------------------------
// LayerNorm(256) + silu(g) gate; sums via segmented in-wave shuffles
// (head = 32-lane group). Reads o fp16, rewrites IN PLACE as OG bf16.
__global__ __launch_bounds__(256) void ln_gate(u16* __restrict__ O,
                                               const u16* __restrict__ G,
                                               const float* __restrict__ bg) {
  const int tglob = blockIdx.x;        // token row 0..8191
  const int tid = threadIdx.x;
  const int c0 = tid << 3;             // 8 elements per thread
  const size_t base = (size_t)tglob * 2048 + c0;
  ushort4 oa = *(const ushort4*)&O[base];
  ushort4 ob = *(const ushort4*)&O[base + 4];
  float f0 = h2f(oa.x), f1 = h2f(oa.y), f2 = h2f(oa.z), f3 = h2f(oa.w);
  float f4 = h2f(ob.x), f5 = h2f(ob.y), f6 = h2f(ob.z), f7 = h2f(ob.w);
  float s = f0 + f1 + f2 + f3 + f4 + f5 + f6 + f7;
  float ss = f0 * f0 + f1 * f1 + f2 * f2 + f3 * f3 + f4 * f4 + f5 * f5 + f6 * f6 + f7 * f7;
#pragma unroll
  for (int off = 1; off <= 16; off <<= 1) {
    s += __shfl_xor(s, off, 64);
    ss += __shfl_xor(ss, off, 64);
  }
  const float mean = s * (1.f / 256.f);
  const float rstd = rsqrtf(ss * (1.f / 256.f) - mean * mean + 1e-5f);
  ushort4 ga = *(const ushort4*)&G[base];
  ushort4 gb4 = *(const ushort4*)&G[base + 4];
  float4 bga = *(const float4*)&bg[c0];
  float4 bgb = *(const float4*)&bg[c0 + 4];
  auto one = [&](float ov, u16 gu, float bgv) -> u16 {
    float gg = bf2f(gu) + bgv;
    return f2bf((ov - mean) * rstd * (gg / (1.f + expf(-gg))));
  };
  ushort4 ra, rb;
  ra.x = one(f0, ga.x, bga.x);  ra.y = one(f1, ga.y, bga.y);
  ra.z = one(f2, ga.z, bga.z);  ra.w = one(f3, ga.w, bga.w);
  rb.x = one(f4, gb4.x, bgb.x); rb.y = one(f5, gb4.y, bgb.y);
  rb.z = one(f6, gb4.z, bgb.z); rb.w = one(f7, gb4.w, bgb.w);
  *(ushort4*)&O[base] = ra;
  *(ushort4*)&O[base + 4] = rb;
}

// ---------------------------------------------------------------------------
extern "C" void kernel_launch(void* const* d_in, const int* in_sizes, int n_in,
                              void* d_out, int out_size, void* d_ws, size_t ws_size,
                              hipStream_t stream) {
  (void)in_sizes; (void)n_in; (void)out_size;
  if (ws_size < 117964800ull) return;   // fail soft

  const float* x    = (const float*)d_in[0];
  const float* Wq   = (const float*)d_in[1];
  const float* Wk   = (const float*)d_in[2];
  const float* Wkg1 = (const float*)d_in[3];
  const float* Wkg2 = (const float*)d_in[4];
  const float* bkg2 = (const float*)d_in[5];
  const float* Wv   = (const float*)d_in[6];
  const float* Wg   = (const float*)d_in[7];
  const float* bg   = (const float*)d_in[8];
  const float* Wo   = (const float*)d_in[9];

  char* ws = (char*)d_ws;
  float* QK  = (float*)(ws + 0);           // 64 MiB fp32 -> interleaved decorated
  u16*   QKu = (u16*)QK;
  u16*   V   = (u16*)(ws + 67108864);      // 32 MiB bf16
  u16*   WtA = (u16*)(ws + 100663296);     //  8 MiB hi
  u16*   WtB = (u16*)(ws + 109051904);     //  8 MiB lo
  float* xg1 = (float*)(ws + 117440512);   // 0.5 MiB
  float* Cf  = QK;                         // final GEMM C (decorated dead by then)
  // dl lives in the WtB region (idle between G-gemm and Wo transpose)
  float* dl  = (float*)(ws + 109051904);   // 256 KiB

  u16* G  = (u16*)d_out;                   // d_out [0,32Mi)
  u16* Oh = (u16*)d_out + 16777216;        // d_out [32Mi,64Mi): o fp16 -> OG bf16

  dim3 tb(32, 8);

  xg1_gemm<<<dim3(128), dim3(256), 0, stream>>>(x, Wkg1, xg1);

  // [q|k] pair projection, fp32 out (Wk folded with (D/H)^-0.5 = 1/16)
  tpose_pair<<<dim3(32, 64), tb, 0, stream>>>(Wq, WtA,               WtB,               2048, 1024, 1.0f);
  tpose_pair<<<dim3(32, 64), tb, 0, stream>>>(Wk, WtA + 1024 * 2048, WtB + 1024 * 2048, 2048, 1024, 0.0625f);
  gemm_f32a<3, 1><<<dim3(16, 64), dim3(256), 0, stream>>>(x, WtA, WtB, (void*)QK, 8192, 2048, 2048);

  // v pair projection, bf16 out
  tpose_pair<<<dim3(64, 64), tb, 0, stream>>>(Wv, WtA, WtB, 2048, 2048, 1.0f);
  gemm_f32a<3, 0><<<dim3(16, 64), dim3(256), 0, stream>>>(x, WtA, WtB, (void*)V, 8192, 2048, 2048);

  // g projection (plain bf16 quality suffices for the gate)
  tpose_pair<<<dim3(64, 64), tb, 0, stream>>>(Wg, WtA, WtB, 2048, 2048, 1.0f);
  gemm_f32a<1, 0><<<dim3(16, 64), dim3(256), 0, stream>>>(x, WtA, WtA, (void*)G, 8192, 2048, 2048);

  // chunked GLA on MFMA
  gla_decor<<<dim3(512), dim3(256), 0, stream>>>(QK, xg1, Wkg2, bkg2, dl);
  gla_intra<<<dim3(512), dim3(256), 0, stream>>>(QKu, V, Oh);
  gla_inter<<<dim3(256), dim3(256), 0, stream>>>(QKu, V, dl, Oh);
  ln_gate<<<dim3(8192), dim3(256), 0, stream>>>(Oh, G, bg);

  // final projection: OG bf16 @ Wo^T -> fp32, then d2d to d_out
  tpose_pair<<<dim3(64, 64), tb, 0, stream>>>(Wo, WtA, WtB, 2048, 2048, 1.0f);
  gemm_bt<<<dim3(16, 64), dim3(256), 0, stream>>>(Oh, WtA, Cf, 8192, 2048, 2048);
  hipMemcpyAsync(d_out, Cf, 67108864ull, hipMemcpyDeviceToDevice, stream);
}

// Round 4
// 1221.718 us; speedup vs baseline: 3.1423x; 1.0752x over previous
//
#include <hip/hip_runtime.h>
#include <stdint.h>

// ---------------------------------------------------------------------------
// GatedLinearAttention (b=4, T=2048, D=2048, H=8, dk=128, dv=256, CHUNK=128)
// Round: pure-async pair GEMMs. x is hi/lo-split ONCE (xsplit -> d_out scratch)
// so projection GEMMs stage all 4 planes via global_load_lds (no VALU split in
// the k-loop), with chunk-XOR swizzle (c ^= (row>>1)&3) applied as pre-swizzled
// global source + XOR'd ds_read -> 2-way bank aliasing (free) instead of 8-way.
//
// ws layout (112.5 MiB guard unchanged):
//   QK [0,64Mi)      fp32 [q | k/16] [8192][2048] -> interleaved decorated u32
//   V  [64Mi,96Mi)   bf16 [8192][2048]
//   WtA [96Mi,104Mi) weight^T hi-plane; WtB [104Mi,112Mi) lo-plane
//   dl  at WtB base (idle between G-gemm and Wo-transpose), 256KB fp32
//   xg1 [112Mi,+512K)
// d_out scratch timeline:
//   [0,32Mi):  xh bf16 (xsplit..g-gemm)  -> Oh fp16/OG bf16 (intra..final)
//   [32Mi,64Mi): xl bf16 (xsplit..v-gemm) -> G bf16 (g-gemm..ln_gate)
//   final C memcpy'd over everything last.
// ---------------------------------------------------------------------------

typedef unsigned short u16;
typedef unsigned int u32;
typedef __bf16 bf16x8 __attribute__((ext_vector_type(8)));
typedef float f32x4 __attribute__((ext_vector_type(4)));

__device__ __forceinline__ u16 f2bf(float f) {
  u32 u = __float_as_uint(f);
  u32 r = (u + 0x7fffu + ((u >> 16) & 1u)) >> 16;   // RNE
  return (u16)r;
}
__device__ __forceinline__ float bf2f(u16 s) {
  return __uint_as_float(((u32)s) << 16);
}
__device__ __forceinline__ u16 f2h(float f) {
  _Float16 h = (_Float16)f;                          // RNE fp32->fp16
  return __builtin_bit_cast(u16, h);
}
__device__ __forceinline__ float h2f(u16 u) {
  return (float)__builtin_bit_cast(_Float16, u);
}

// async global->LDS, 16B/lane. LDS dest = wave-uniform base + lane*16.
__device__ __forceinline__ void load_lds16(const void* g, void* l) {
  auto gp = (const __attribute__((address_space(1))) u32*)(uintptr_t)g;
  auto lp = (__attribute__((address_space(3))) u32*)(u32)(uintptr_t)l;
  __builtin_amdgcn_global_load_lds(gp, lp, 16, 0, 0);
}
__device__ __forceinline__ bf16x8 ldf(const u16* p) { return *(const bf16x8*)p; }

// unpack 8 interleaved (hi,lo) u16 pairs (two uint4) -> hi/lo bf16x8 vectors
__device__ __forceinline__ void unpk(uint4 w0, uint4 w1, bf16x8& hi, bf16x8& lo) {
  union U { uint4 u; bf16x8 v; } a, b;
  a.u.x = __builtin_amdgcn_perm(w0.y, w0.x, 0x05040100u);
  a.u.y = __builtin_amdgcn_perm(w0.w, w0.z, 0x05040100u);
  a.u.z = __builtin_amdgcn_perm(w1.y, w1.x, 0x05040100u);
  a.u.w = __builtin_amdgcn_perm(w1.w, w1.z, 0x05040100u);
  b.u.x = __builtin_amdgcn_perm(w0.y, w0.x, 0x07060302u);
  b.u.y = __builtin_amdgcn_perm(w0.w, w0.z, 0x07060302u);
  b.u.z = __builtin_amdgcn_perm(w1.y, w1.x, 0x07060302u);
  b.u.w = __builtin_amdgcn_perm(w1.w, w1.z, 0x07060302u);
  hi = a.v;
  lo = b.v;
}

// ---------------------------------------------------------------------------
// xsplit: x fp32 -> xh, xl bf16 planes (hi = bf16(v), lo = bf16(v - hi)).
__global__ __launch_bounds__(256) void xsplit(const float* __restrict__ x,
                                              u16* __restrict__ xh,
                                              u16* __restrict__ xl) {
  const size_t i = ((size_t)blockIdx.x * 256 + threadIdx.x) * 8;
  float4 a = *(const float4*)&x[i];
  float4 b = *(const float4*)&x[i + 4];
  ushort4 h0, l0, h1, l1;
  h0.x = f2bf(a.x); l0.x = f2bf(a.x - bf2f(h0.x));
  h0.y = f2bf(a.y); l0.y = f2bf(a.y - bf2f(h0.y));
  h0.z = f2bf(a.z); l0.z = f2bf(a.z - bf2f(h0.z));
  h0.w = f2bf(a.w); l0.w = f2bf(a.w - bf2f(h0.w));
  h1.x = f2bf(b.x); l1.x = f2bf(b.x - bf2f(h1.x));
  h1.y = f2bf(b.y); l1.y = f2bf(b.y - bf2f(h1.y));
  h1.z = f2bf(b.z); l1.z = f2bf(b.z - bf2f(h1.z));
  h1.w = f2bf(b.w); l1.w = f2bf(b.w - bf2f(h1.w));
  *(ushort4*)&xh[i] = h0; *(ushort4*)&xh[i + 4] = h1;
  *(ushort4*)&xl[i] = l0; *(ushort4*)&xl[i + 4] = l1;
}

// ---------------------------------------------------------------------------
// weight transpose + hi/lo bf16 split
__global__ __launch_bounds__(256) void tpose_pair(const float* __restrict__ src,
                                                  u16* __restrict__ dhi,
                                                  u16* __restrict__ dlo,
                                                  int srcRows, int srcStride,
                                                  float scale) {
  __shared__ float tile[32][33];
  const int tx = threadIdx.x, ty = threadIdx.y;     // block (32,8)
  const int n0 = blockIdx.x * 32, k0 = blockIdx.y * 32;
#pragma unroll
  for (int j = 0; j < 4; ++j) {
    int k = k0 + ty + j * 8;
    tile[ty + j * 8][tx] = src[(size_t)k * srcStride + n0 + tx] * scale;
  }
  __syncthreads();
#pragma unroll
  for (int j = 0; j < 4; ++j) {
    int n = n0 + ty + j * 8;
    float f = tile[tx][ty + j * 8];
    u16 h = f2bf(f);
    size_t idx = (size_t)n * srcRows + k0 + tx;
    dhi[idx] = h;
    dlo[idx] = f2bf(f - bf2f(h));
  }
}

// ---------------------------------------------------------------------------
// Pair GEMM, all planes async-staged: C = (Ah+Al)[M,K] @ (Bh+Bl)[N,K]^T,
// 3-combo (hh+hl+lh). Chunk-XOR swizzle on source + read (2-way LDS aliasing).
template <int OUTF32>
__global__ __launch_bounds__(256) void gemm_pair(const u16* __restrict__ Ahp,
                                                 const u16* __restrict__ Alp,
                                                 const u16* __restrict__ Bhp,
                                                 const u16* __restrict__ Blp,
                                                 void* __restrict__ C,
                                                 int M, int N, int K) {
  __shared__ u16 Ah[128 * 32];
  __shared__ u16 Al[128 * 32];
  __shared__ u16 Bh[128 * 32];
  __shared__ u16 Bl[128 * 32];
  const int tid = threadIdx.x;
  const int wave = tid >> 6, lane = tid & 63;
  const int wm = wave >> 1, wn = wave & 1;
  const int qu = lane >> 4, ln = lane & 15;
  const int m0 = blockIdx.y * 128, n0 = blockIdx.x * 128;
  const int crow = tid >> 2;
  const int csw = (((tid & 3) ^ ((crow >> 1) & 3)) << 3);   // swizzled src ofs
  f32x4 acc[4][4] = {};
  for (int kt = 0; kt < K; kt += 32) {
#pragma unroll
    for (int r = 0; r < 2; ++r) {
      const size_t ga = (size_t)(m0 + crow + r * 64) * K + kt + csw;
      const size_t gb = (size_t)(n0 + crow + r * 64) * K + kt + csw;
      const size_t ldst = (size_t)(r * 256 + wave * 64) * 8;
      load_lds16(Ahp + ga, Ah + ldst);
      load_lds16(Alp + ga, Al + ldst);
      load_lds16(Bhp + gb, Bh + ldst);
      load_lds16(Blp + gb, Bl + ldst);
    }
    __syncthreads();
    bf16x8 ah[4], al[4], bh[4], bl[4];
#pragma unroll
    for (int t = 0; t < 4; ++t) {
      const int ia = wm * 64 + t * 16 + ln;
      const int ib = wn * 64 + t * 16 + ln;
      const int ca = ((qu ^ ((ia >> 1) & 3)) << 3);
      const int cb = ((qu ^ ((ib >> 1) & 3)) << 3);
      ah[t] = ldf(&Ah[ia * 32 + ca]);
      al[t] = ldf(&Al[ia * 32 + ca]);
      bh[t] = ldf(&Bh[ib * 32 + cb]);
      bl[t] = ldf(&Bl[ib * 32 + cb]);
    }
#pragma unroll
    for (int ti = 0; ti < 4; ++ti)
#pragma unroll
      for (int tj = 0; tj < 4; ++tj) {
        acc[ti][tj] = __builtin_amdgcn_mfma_f32_16x16x32_bf16(ah[ti], bh[tj], acc[ti][tj], 0, 0, 0);
        acc[ti][tj] = __builtin_amdgcn_mfma_f32_16x16x32_bf16(ah[ti], bl[tj], acc[ti][tj], 0, 0, 0);
        acc[ti][tj] = __builtin_amdgcn_mfma_f32_16x16x32_bf16(al[ti], bh[tj], acc[ti][tj], 0, 0, 0);
      }
    __syncthreads();
  }
#pragma unroll
  for (int ti = 0; ti < 4; ++ti)
#pragma unroll
    for (int tj = 0; tj < 4; ++tj) {
      const int rowb = m0 + wm * 64 + ti * 16 + qu * 4;   // C/D: row=(lane>>4)*4+reg
      const int col = n0 + wn * 64 + tj * 16 + ln;        //      col=lane&15
#pragma unroll
      for (int r = 0; r < 4; ++r) {
        size_t idx = (size_t)(rowb + r) * N + col;
        if (OUTF32) ((float*)C)[idx] = acc[ti][tj][r];
        else        ((u16*)C)[idx] = f2bf(acc[ti][tj][r]);
      }
    }
}

// ---------------------------------------------------------------------------
// Plain bf16-A GEMM (g + final projection): C[M,N] = A_bf16 @ Bt^T, swizzled.
template <int OUTF32>
__global__ __launch_bounds__(256) void gemm_bt(const u16* __restrict__ A,
                                               const u16* __restrict__ Bt,
                                               void* __restrict__ C,
                                               int M, int N, int K) {
  __shared__ u16 As[128 * 32];
  __shared__ u16 Bs[128 * 32];
  const int tid = threadIdx.x;
  const int wave = tid >> 6, lane = tid & 63;
  const int wm = wave >> 1, wn = wave & 1;
  const int qu = lane >> 4, ln = lane & 15;
  const int m0 = blockIdx.y * 128, n0 = blockIdx.x * 128;
  const int crow = tid >> 2;
  const int csw = (((tid & 3) ^ ((crow >> 1) & 3)) << 3);
  f32x4 acc[4][4] = {};
  for (int kt = 0; kt < K; kt += 32) {
#pragma unroll
    for (int r = 0; r < 2; ++r) {
      const size_t ldst = (size_t)(r * 256 + wave * 64) * 8;
      load_lds16(A + (size_t)(m0 + crow + r * 64) * K + kt + csw, As + ldst);
      load_lds16(Bt + (size_t)(n0 + crow + r * 64) * K + kt + csw, Bs + ldst);
    }
    __syncthreads();
    bf16x8 af[4], bfr[4];
#pragma unroll
    for (int t = 0; t < 4; ++t) {
      const int ia = wm * 64 + t * 16 + ln;
      const int ib = wn * 64 + t * 16 + ln;
      af[t] = ldf(&As[ia * 32 + ((qu ^ ((ia >> 1) & 3)) << 3)]);
      bfr[t] = ldf(&Bs[ib * 32 + ((qu ^ ((ib >> 1) & 3)) << 3)]);
    }
#pragma unroll
    for (int ti = 0; ti < 4; ++ti)
#pragma unroll
      for (int tj = 0; tj < 4; ++tj)
        acc[ti][tj] = __builtin_amdgcn_mfma_f32_16x16x32_bf16(af[ti], bfr[tj], acc[ti][tj], 0, 0, 0);
    __syncthreads();
  }
#pragma unroll
  for (int ti = 0; ti < 4; ++ti)
#pragma unroll
    for (int tj = 0; tj < 4; ++tj) {
      const int rowb = m0 + wm * 64 + ti * 16 + qu * 4;
      const int col = n0 + wn * 64 + tj * 16 + ln;
#pragma unroll
      for (int r = 0; r < 4; ++r) {
        size_t idx = (size_t)(rowb + r) * N + col;
        if (OUTF32) ((float*)C)[idx] = acc[ti][tj][r];
        else        ((u16*)C)[idx] = f2bf(acc[ti][tj][r]);
      }
    }
}

// ---------------------------------------------------------------------------
// xg1[8192,16] = x[8192,2048] @ Wkg1[2048,16]   (fp32, tiled)
__global__ __launch_bounds__(256) void xg1_gemm(const float* __restrict__ x,
                                                const float* __restrict__ W1,
                                                float* __restrict__ xg1) {
  __shared__ float xs[64][40];
  __shared__ float ws2[32][16];
  const int tid = threadIdx.x;
  const int r0 = blockIdx.x * 64;
  const int col = tid & 15, rsub = tid >> 4;
  float acc[4] = {0.f, 0.f, 0.f, 0.f};
  for (int kt = 0; kt < 2048; kt += 32) {
#pragma unroll
    for (int j = 0; j < 2; ++j) {
      int c = j * 256 + tid;
      int row = c >> 3, kk = (c & 7) << 2;
      *(float4*)&xs[row][kk] = *(const float4*)&x[(size_t)(r0 + row) * 2048 + kt + kk];
    }
#pragma unroll
    for (int j = 0; j < 2; ++j) {
      int c = j * 256 + tid;
      ws2[c >> 4][c & 15] = W1[(size_t)(kt + (c >> 4)) * 16 + (c & 15)];
    }
    __syncthreads();
#pragma unroll
    for (int kk = 0; kk < 32; ++kk) {
      float wv = ws2[kk][col];
#pragma unroll
      for (int j = 0; j < 4; ++j) acc[j] += xs[rsub + j * 16][kk] * wv;
    }
    __syncthreads();
  }
#pragma unroll
  for (int j = 0; j < 4; ++j) xg1[(size_t)(r0 + rsub + j * 16) * 16 + col] = acc[j];
}

// ---------------------------------------------------------------------------
// gla_decor: grid 512 = (b * 16 + n) * 8 + headgroup; 256 threads =
// 128 q-cols + 128 k-cols of that head. Each thread reads its fp32 value and
// overwrites THE SAME 4 bytes with (hi | lo<<16) -> fully race-free in-place.
__global__ __launch_bounds__(256) void gla_decor(float* __restrict__ QK,
                                                 const float* __restrict__ xg1,
                                                 const float* __restrict__ W2,
                                                 const float* __restrict__ b2,
                                                 float* __restrict__ dl) {
  __shared__ float xg1s[128][16];   // 8KB
  const int tid = threadIdx.x;
  const int bi = blockIdx.x;
  const int b = bi >> 7, n = (bi >> 3) & 15, g = bi & 7;
  const int t0 = b * 2048 + n * 128;
  const bool isK = tid >= 128;
  const int ci = tid & 127;
  const int col = g * 128 + ci;            // global col 0..1023
  u32* base = (u32*)QK + (size_t)t0 * 2048 + (isK ? 1024 : 0) + col;
  float w2r[16];
#pragma unroll
  for (int k = 0; k < 16; ++k) w2r[k] = W2[k * 1024 + col];
  const float b2r = b2[col];
  for (int e = tid; e < 2048; e += 256)
    xg1s[e >> 4][e & 15] = xg1[(size_t)(t0 + (e >> 4)) * 16 + (e & 15)];
  __syncthreads();
  float acc = 0.f;
  const float sgn = isK ? -1.f : 1.f;
  for (int s = 0; s < 128; s += 16) {
    float qv[16];
#pragma unroll
    for (int j = 0; j < 16; ++j) qv[j] = __uint_as_float(base[(size_t)(s + j) * 2048]);
    u32 ov[16];
#pragma unroll
    for (int j = 0; j < 16; ++j) {
      float z = b2r;
#pragma unroll
      for (int kk = 0; kk < 16; ++kk) z += xg1s[s + j][kk] * w2r[kk];
      float gk = (fminf(z, 0.f) - log1pf(expf(-fabsf(z)))) * 0.0625f;
      acc += gk;
      float e = expf(sgn * acc);
      float v = qv[j] * e;
      u16 h = f2bf(v);
      u16 l = f2bf(v - bf2f(h));
      ov[j] = (u32)h | ((u32)l << 16);
    }
#pragma unroll
    for (int j = 0; j < 16; ++j) base[(size_t)(s + j) * 2048] = ov[j];
  }
  if (isK) dl[((size_t)(b * 8 + g) * 16 + n) * 128 + ci] = expf(acc);
}

// ---------------------------------------------------------------------------
// gla_intra: per (b,h,chunk): A = tril(QD@KE^T) (3-combo), o_intra = A@V^T
// (2-combo) -> Oh fp16. Q/K staged as interleaved windows, source-swizzled
// (chunk ^ row&7); frag reads unpack hi/lo via v_perm (2-way bank aliasing).
__global__ __launch_bounds__(256) void gla_intra(const u16* __restrict__ QKu,
                                                 const u16* __restrict__ V,
                                                 u16* __restrict__ Oh) {
  // pool: stage Qi [0,8192) u16, Ki [8192,16384); Amh [0,16384) Aml [16384,32768);
  //       VTs [32768, 32768+7168) = [128][56] u16 pad
  __shared__ u16 pool[39936];   // 79872 B -> 2 blocks/CU
  const int tid = threadIdx.x;
  const int bi = blockIdx.x;
  const int n = bi & 15, h = (bi >> 4) & 7, b = bi >> 7;
  const int t0 = b * 2048 + n * 128;
  const int wave = tid >> 6, lane = tid & 63;
  const int wm = wave >> 1, wn = wave & 1;
  const int qu = lane >> 4, ln = lane & 15;
  const int srow = tid >> 3, schk = tid & 7;
  const int sc = ((schk ^ (srow & 7)) << 3);   // swizzled source u16 offset
  u16* Qi = pool;
  u16* Ki = pool + 8192;
  u16* Amh = pool;
  u16* Aml = pool + 16384;
  u16* VTs = pool + 32768;
  // ---- phase A: A = QD @ KE^T  (3-combo hi/lo)
  f32x4 acc[4][4] = {};
  for (int kt = 0; kt < 128; kt += 32) {
#pragma unroll
    for (int r = 0; r < 4; ++r) {
      const int row = srow + r * 32;
      const size_t gb = (size_t)(t0 + row) * 4096 + h * 256 + 2 * kt + sc;
      load_lds16(QKu + gb,        Qi + (r * 32 + wave * 8) * 64);
      load_lds16(QKu + gb + 2048, Ki + (r * 32 + wave * 8) * 64);
    }
    __syncthreads();
    bf16x8 ah[4], al[4], bh[4], bl[4];
#pragma unroll
    for (int t = 0; t < 4; ++t) {
      const int i = wm * 64 + t * 16 + ln;
      const u16* pQ = &Qi[i * 64];
      uint4 w0 = *(const uint4*)&pQ[((2 * qu) ^ (i & 7)) << 3];
      uint4 w1 = *(const uint4*)&pQ[((2 * qu + 1) ^ (i & 7)) << 3];
      unpk(w0, w1, ah[t], al[t]);
      const int j = wn * 64 + t * 16 + ln;
      const u16* pK = &Ki[j * 64];
      uint4 y0 = *(const uint4*)&pK[((2 * qu) ^ (j & 7)) << 3];
      uint4 y1 = *(const uint4*)&pK[((2 * qu + 1) ^ (j & 7)) << 3];
      unpk(y0, y1, bh[t], bl[t]);
    }
#pragma unroll
    for (int ti = 0; ti < 4; ++ti)
#pragma unroll
      for (int tj = 0; tj < 4; ++tj) {
        acc[ti][tj] = __builtin_amdgcn_mfma_f32_16x16x32_bf16(ah[ti], bh[tj], acc[ti][tj], 0, 0, 0);
        acc[ti][tj] = __builtin_amdgcn_mfma_f32_16x16x32_bf16(ah[ti], bl[tj], acc[ti][tj], 0, 0, 0);
        acc[ti][tj] = __builtin_amdgcn_mfma_f32_16x16x32_bf16(al[ti], bh[tj], acc[ti][tj], 0, 0, 0);
      }
    __syncthreads();
  }
  // ---- phase B: causal mask + hi/lo split -> Am (swizzled), aliases stage
#pragma unroll
  for (int ti = 0; ti < 4; ++ti)
#pragma unroll
    for (int tj = 0; tj < 4; ++tj) {
      const int ib = wm * 64 + ti * 16 + qu * 4;
      const int j = wn * 64 + tj * 16 + ln;
#pragma unroll
      for (int r = 0; r < 4; ++r) {
        const int i = ib + r;
        float v = (j <= i) ? acc[ti][tj][r] : 0.f;
        u16 hi = f2bf(v);
        const int idx = i * 128 + (j ^ ((i & 15) << 3));
        Amh[idx] = hi;
        Aml[idx] = f2bf(v - bf2f(hi));
      }
    }
  // ---- phase C: o_intra = Am @ V^T (2-combo), two dv-halves of 128
  for (int half = 0; half < 2; ++half) {
    f32x4 acc2[4][4] = {};
    for (int kt = 0; kt < 128; kt += 32) {
      __syncthreads();   // Am visible (first iter) / prev VTs reads done
      {  // stage VTs[dv][t] transposed from V, pad 56
        const int j = tid & 31, dvg = tid >> 5;
#pragma unroll
        for (int rr = 0; rr < 2; ++rr) {
          const int dg = dvg + rr * 8;
          uint4 pv = *(const uint4*)(V + (size_t)(t0 + kt + j) * 2048 + h * 256 + half * 128 + dg * 8);
          u16* dst = VTs + (dg * 8) * 56 + j;
          dst[0]      = (u16)pv.x; dst[56]      = (u16)(pv.x >> 16);
          dst[2 * 56] = (u16)pv.y; dst[3 * 56]  = (u16)(pv.y >> 16);
          dst[4 * 56] = (u16)pv.z; dst[5 * 56]  = (u16)(pv.z >> 16);
          dst[6 * 56] = (u16)pv.w; dst[7 * 56]  = (u16)(pv.w >> 16);
        }
      }
      __syncthreads();
      bf16x8 amh[4], aml[4], bv[4];
#pragma unroll
      for (int t = 0; t < 4; ++t) {
        const int i = wm * 64 + t * 16 + ln;
        const int cof = (kt + qu * 8) ^ ((i & 15) << 3);
        amh[t] = ldf(&Amh[i * 128 + cof]);
        aml[t] = ldf(&Aml[i * 128 + cof]);
        bv[t] = ldf(&VTs[(wn * 64 + t * 16 + ln) * 56 + qu * 8]);
      }
#pragma unroll
      for (int ti = 0; ti < 4; ++ti)
#pragma unroll
        for (int tj = 0; tj < 4; ++tj) {
          acc2[ti][tj] = __builtin_amdgcn_mfma_f32_16x16x32_bf16(amh[ti], bv[tj], acc2[ti][tj], 0, 0, 0);
          acc2[ti][tj] = __builtin_amdgcn_mfma_f32_16x16x32_bf16(aml[ti], bv[tj], acc2[ti][tj], 0, 0, 0);
        }
    }
#pragma unroll
    for (int ti = 0; ti < 4; ++ti)
#pragma unroll
      for (int tj = 0; tj < 4; ++tj)
#pragma unroll
        for (int r = 0; r < 4; ++r) {
          const int i = wm * 64 + ti * 16 + qu * 4 + r;
          const int col = half * 128 + wn * 64 + tj * 16 + ln;
          Oh[(size_t)(t0 + i) * 2048 + h * 256 + col] = f2h(acc2[ti][tj][r]);
        }
  }
}

// ---------------------------------------------------------------------------
// gla_inter: serial 16-chunk scan. Grid 256 = (dv-slice 0..7)x(b,h).
__global__ __launch_bounds__(256) void gla_inter(const u16* __restrict__ QKu,
                                                 const u16* __restrict__ V,
                                                 const float* __restrict__ dl,
                                                 u16* __restrict__ Oh) {
  __shared__ float STf[32 * 128];     // 16KB  S (fp32 master), [dv][d]
  __shared__ u16 STh[32 * 136];       // 8.5KB (pad 136 -> 2-way reads)
  __shared__ u16 STl[32 * 136];
  __shared__ u16 Qi2[128 * 64];       // 16KB interleaved QD window
  __shared__ u16 KTh[128 * 56];       // 14KB (pad 56)
  __shared__ u16 KTl[128 * 56];
  __shared__ u16 VTs2[32 * 56];       // 3.5KB
  __shared__ float dls[128];
  const int tid = threadIdx.x;
  const int bi = blockIdx.x;
  const int sl = bi >> 5, g = bi & 31, b = g >> 3, h = g & 7;
  const int wave = tid >> 6, lane = tid & 63;
  const int qu = lane >> 4, ln = lane & 15;
  const int srow = tid >> 3, schk = tid & 7;
  const int sc = ((schk ^ (srow & 7)) << 3);
  const int bh16 = (b * 8 + h) * 16;
  for (int e = tid; e < 4096; e += 256) STf[e] = 0.f;
  for (int c = 0; c < 16; ++c) {
    const int t0 = b * 2048 + c * 128;
    if (tid < 128) dls[tid] = dl[(size_t)(bh16 + c) * 128 + tid];
    __syncthreads();   // B1: dls + STf(zero/update) visible
    if (c > 0) {
      // split S -> hi/lo planes
      for (int e = tid; e < 4096; e += 256) {
        const int row = e >> 7, col = e & 127;
        float v = STf[e];
        u16 hi = f2bf(v);
        STh[row * 136 + col] = hi;
        STl[row * 136 + col] = f2bf(v - bf2f(hi));
      }
      __syncthreads();
      // o_inter = QD_c @ S_prev (3-combo)
      f32x4 aco[2][2] = {};
      for (int kt = 0; kt < 128; kt += 32) {
#pragma unroll
        for (int r = 0; r < 4; ++r) {
          const int row = srow + r * 32;
          load_lds16(QKu + (size_t)(t0 + row) * 4096 + h * 256 + 2 * kt + sc,
                     Qi2 + (r * 32 + wave * 8) * 64);
        }
        __syncthreads();
        bf16x8 qh[2], ql[2], sh[2], slo[2];
#pragma unroll
        for (int t = 0; t < 2; ++t) {
          const int ar = wave * 32 + t * 16 + ln;
          const u16* pQ = &Qi2[ar * 64];
          uint4 w0 = *(const uint4*)&pQ[((2 * qu) ^ (ar & 7)) << 3];
          uint4 w1 = *(const uint4*)&pQ[((2 * qu + 1) ^ (ar & 7)) << 3];
          unpk(w0, w1, qh[t], ql[t]);
          const int br = t * 16 + ln;
          sh[t]  = ldf(&STh[br * 136 + kt + qu * 8]);
          slo[t] = ldf(&STl[br * 136 + kt + qu * 8]);
        }
#pragma unroll
        for (int ti = 0; ti < 2; ++ti)
#pragma unroll
          for (int tj = 0; tj < 2; ++tj) {
            aco[ti][tj] = __builtin_amdgcn_mfma_f32_16x16x32_bf16(qh[ti], sh[tj], aco[ti][tj], 0, 0, 0);
            aco[ti][tj] = __builtin_amdgcn_mfma_f32_16x16x32_bf16(qh[ti], slo[tj], aco[ti][tj], 0, 0, 0);
            aco[ti][tj] = __builtin_amdgcn_mfma_f32_16x16x32_bf16(ql[ti], sh[tj], aco[ti][tj], 0, 0, 0);
          }
        __syncthreads();
      }
      // RMW Oh += o_inter (fp16; each cell owned by exactly one lane)
#pragma unroll
      for (int ti = 0; ti < 2; ++ti)
#pragma unroll
        for (int tj = 0; tj < 2; ++tj)
#pragma unroll
          for (int r = 0; r < 4; ++r) {
            const int i = wave * 32 + ti * 16 + qu * 4 + r;
            const int dv = tj * 16 + ln;
            u16* p = Oh + (size_t)(t0 + i) * 2048 + h * 256 + sl * 32 + dv;
            *p = f2h(h2f(*p) + aco[ti][tj][r]);
          }
    }
    // W^T = VT @ KET (2-combo), K = tokens
    f32x4 acw[2][2] = {};
    for (int kt = 0; kt < 128; kt += 32) {
      __syncthreads();   // prev frag reads done
      {  // stage KE (hi/lo from interleaved) transposed [d][t], pad 56
        const int t = tid & 31, dg0 = tid >> 5;
#pragma unroll
        for (int rr = 0; rr < 2; ++rr) {
          const int dg = dg0 + rr * 8;
          const size_t gb = (size_t)(t0 + kt + t) * 4096 + 2048 + h * 256 + dg * 16;
          uint4 w0 = *(const uint4*)(QKu + gb);
          uint4 w1 = *(const uint4*)(QKu + gb + 8);
          u16* dh = KTh + (dg * 8) * 56 + t;
          u16* dL = KTl + (dg * 8) * 56 + t;
          dh[0]      = (u16)w0.x; dL[0]      = (u16)(w0.x >> 16);
          dh[56]     = (u16)w0.y; dL[56]     = (u16)(w0.y >> 16);
          dh[2 * 56] = (u16)w0.z; dL[2 * 56] = (u16)(w0.z >> 16);
          dh[3 * 56] = (u16)w0.w; dL[3 * 56] = (u16)(w0.w >> 16);
          dh[4 * 56] = (u16)w1.x; dL[4 * 56] = (u16)(w1.x >> 16);
          dh[5 * 56] = (u16)w1.y; dL[5 * 56] = (u16)(w1.y >> 16);
          dh[6 * 56] = (u16)w1.z; dL[6 * 56] = (u16)(w1.z >> 16);
          dh[7 * 56] = (u16)w1.w; dL[7 * 56] = (u16)(w1.w >> 16);
        }
        if (tid < 128) {  // stage V slice transposed [dv][t]
          const int t2 = tid & 31, vg = tid >> 5;
          uint4 pv = *(const uint4*)(V + (size_t)(t0 + kt + t2) * 2048 + h * 256 + sl * 32 + vg * 8);
          u16* dst = VTs2 + (vg * 8) * 56 + t2;
          dst[0]      = (u16)pv.x; dst[56]     = (u16)(pv.x >> 16);
          dst[2 * 56] = (u16)pv.y; dst[3 * 56] = (u16)(pv.y >> 16);
          dst[4 * 56] = (u16)pv.z; dst[5 * 56] = (u16)(pv.z >> 16);
          dst[6 * 56] = (u16)pv.w; dst[7 * 56] = (u16)(pv.w >> 16);
        }
      }
      __syncthreads();
      bf16x8 av[2], kh[2], kl[2];
#pragma unroll
      for (int t = 0; t < 2; ++t) {
        av[t] = ldf(&VTs2[(t * 16 + ln) * 56 + qu * 8]);
        const int dr = wave * 32 + t * 16 + ln;
        kh[t] = ldf(&KTh[dr * 56 + qu * 8]);
        kl[t] = ldf(&KTl[dr * 56 + qu * 8]);
      }
#pragma unroll
      for (int ti = 0; ti < 2; ++ti)
#pragma unroll
        for (int tj = 0; tj < 2; ++tj) {
          acw[ti][tj] = __builtin_amdgcn_mfma_f32_16x16x32_bf16(av[ti], kh[tj], acw[ti][tj], 0, 0, 0);
          acw[ti][tj] = __builtin_amdgcn_mfma_f32_16x16x32_bf16(av[ti], kl[tj], acw[ti][tj], 0, 0, 0);
        }
    }
    // S = dl (.) (S + W)   (each (dv,d) owned by one lane)
#pragma unroll
    for (int ti = 0; ti < 2; ++ti)
#pragma unroll
      for (int tj = 0; tj < 2; ++tj)
#pragma unroll
        for (int r = 0; r < 4; ++r) {
          const int dv = ti * 16 + qu * 4 + r;
          const int d = wave * 32 + tj * 16 + ln;
          const int e = dv * 128 + d;
          STf[e] = dls[d] * (STf[e] + acw[ti][tj][r]);
        }
    __syncthreads();   // B4: S update visible before next chunk's split/dls
  }
}

// ---------------------------------------------------------------------------
// LayerNorm(256) + silu(g) gate; sums via segmented in-wave shuffles
// (head = 32-lane group). Reads o fp16, rewrites IN PLACE as OG bf16.
__global__ __launch_bounds__(256) void ln_gate(u16* __restrict__ O,
                                               const u16* __restrict__ G,
                                               const float* __restrict__ bg) {
  const int tglob = blockIdx.x;        // token row 0..8191
  const int tid = threadIdx.x;
  const int c0 = tid << 3;             // 8 elements per thread
  const size_t base = (size_t)tglob * 2048 + c0;
  ushort4 oa = *(const ushort4*)&O[base];
  ushort4 ob = *(const ushort4*)&O[base + 4];
  float f0 = h2f(oa.x), f1 = h2f(oa.y), f2 = h2f(oa.z), f3 = h2f(oa.w);
  float f4 = h2f(ob.x), f5 = h2f(ob.y), f6 = h2f(ob.z), f7 = h2f(ob.w);
  float s = f0 + f1 + f2 + f3 + f4 + f5 + f6 + f7;
  float ss = f0 * f0 + f1 * f1 + f2 * f2 + f3 * f3 + f4 * f4 + f5 * f5 + f6 * f6 + f7 * f7;
#pragma unroll
  for (int off = 1; off <= 16; off <<= 1) {
    s += __shfl_xor(s, off, 64);
    ss += __shfl_xor(ss, off, 64);
  }
  const float mean = s * (1.f / 256.f);
  const float rstd = rsqrtf(ss * (1.f / 256.f) - mean * mean + 1e-5f);
  ushort4 ga = *(const ushort4*)&G[base];
  ushort4 gb4 = *(const ushort4*)&G[base + 4];
  float4 bga = *(const float4*)&bg[c0];
  float4 bgb = *(const float4*)&bg[c0 + 4];
  auto one = [&](float ov, u16 gu, float bgv) -> u16 {
    float gg = bf2f(gu) + bgv;
    return f2bf((ov - mean) * rstd * (gg / (1.f + expf(-gg))));
  };
  ushort4 ra, rb;
  ra.x = one(f0, ga.x, bga.x);  ra.y = one(f1, ga.y, bga.y);
  ra.z = one(f2, ga.z, bga.z);  ra.w = one(f3, ga.w, bga.w);
  rb.x = one(f4, gb4.x, bgb.x); rb.y = one(f5, gb4.y, bgb.y);
  rb.z = one(f6, gb4.z, bgb.z); rb.w = one(f7, gb4.w, bgb.w);
  *(ushort4*)&O[base] = ra;
  *(ushort4*)&O[base + 4] = rb;
}

// ---------------------------------------------------------------------------
extern "C" void kernel_launch(void* const* d_in, const int* in_sizes, int n_in,
                              void* d_out, int out_size, void* d_ws, size_t ws_size,
                              hipStream_t stream) {
  (void)in_sizes; (void)n_in; (void)out_size;
  if (ws_size < 117964800ull) return;   // fail soft

  const float* x    = (const float*)d_in[0];
  const float* Wq   = (const float*)d_in[1];
  const float* Wk   = (const float*)d_in[2];
  const float* Wkg1 = (const float*)d_in[3];
  const float* Wkg2 = (const float*)d_in[4];
  const float* bkg2 = (const float*)d_in[5];
  const float* Wv   = (const float*)d_in[6];
  const float* Wg   = (const float*)d_in[7];
  const float* bg   = (const float*)d_in[8];
  const float* Wo   = (const float*)d_in[9];

  char* ws = (char*)d_ws;
  float* QK  = (float*)(ws + 0);           // 64 MiB fp32 -> interleaved decorated
  u16*   QKu = (u16*)QK;
  u16*   V   = (u16*)(ws + 67108864);      // 32 MiB bf16
  u16*   WtA = (u16*)(ws + 100663296);     //  8 MiB hi
  u16*   WtB = (u16*)(ws + 109051904);     //  8 MiB lo
  float* xg1 = (float*)(ws + 117440512);   // 0.5 MiB
  float* Cf  = QK;                         // final GEMM C (decorated dead by then)
  float* dl  = (float*)(ws + 109051904);   // 256 KiB (WtB region, idle window)

  // d_out scratch: xh [0,32Mi) then Oh; xl [32Mi,64Mi) then G.
  u16* xh = (u16*)d_out;
  u16* xl = (u16*)d_out + 16777216;
  u16* Oh = (u16*)d_out;                   // after g-gemm (xh dead)
  u16* G  = (u16*)d_out + 16777216;        // after v-gemm (xl dead)

  dim3 tb(32, 8);

  xg1_gemm<<<dim3(128), dim3(256), 0, stream>>>(x, Wkg1, xg1);
  xsplit<<<dim3(8192), dim3(256), 0, stream>>>(x, xh, xl);

  // [q|k] pair projection, fp32 out (Wk folded with (D/H)^-0.5 = 1/16)
  tpose_pair<<<dim3(32, 64), tb, 0, stream>>>(Wq, WtA,               WtB,               2048, 1024, 1.0f);
  tpose_pair<<<dim3(32, 64), tb, 0, stream>>>(Wk, WtA + 1024 * 2048, WtB + 1024 * 2048, 2048, 1024, 0.0625f);
  gemm_pair<1><<<dim3(16, 64), dim3(256), 0, stream>>>(xh, xl, WtA, WtB, (void*)QK, 8192, 2048, 2048);

  // v pair projection, bf16 out
  tpose_pair<<<dim3(64, 64), tb, 0, stream>>>(Wv, WtA, WtB, 2048, 2048, 1.0f);
  gemm_pair<0><<<dim3(16, 64), dim3(256), 0, stream>>>(xh, xl, WtA, WtB, (void*)V, 8192, 2048, 2048);

  // g projection: plain bf16 (xh @ Wg^T) -> G in xl region (xl dead now)
  tpose_pair<<<dim3(64, 64), tb, 0, stream>>>(Wg, WtA, WtB, 2048, 2048, 1.0f);
  gemm_bt<0><<<dim3(16, 64), dim3(256), 0, stream>>>(xh, WtA, (void*)G, 8192, 2048, 2048);

  // chunked GLA on MFMA (xh dead from here; Oh takes its region)
  gla_decor<<<dim3(512), dim3(256), 0, stream>>>(QK, xg1, Wkg2, bkg2, dl);
  gla_intra<<<dim3(512), dim3(256), 0, stream>>>(QKu, V, Oh);
  gla_inter<<<dim3(256), dim3(256), 0, stream>>>(QKu, V, dl, Oh);
  ln_gate<<<dim3(8192), dim3(256), 0, stream>>>(Oh, G, bg);

  // final projection: OG bf16 @ Wo^T -> fp32, then d2d to d_out
  tpose_pair<<<dim3(64, 64), tb, 0, stream>>>(Wo, WtA, WtB, 2048, 2048, 1.0f);
  gemm_bt<1><<<dim3(16, 64), dim3(256), 0, stream>>>(Oh, WtA, (void*)Cf, 8192, 2048, 2048);
  hipMemcpyAsync(d_out, Cf, 67108864ull, hipMemcpyDeviceToDevice, stream);
}

// Round 5
// 1012.348 us; speedup vs baseline: 3.7922x; 1.2068x over previous
//
#include <hip/hip_runtime.h>
#include <stdint.h>

// ---------------------------------------------------------------------------
// GatedLinearAttention (b=4, T=2048, D=2048, H=8, dk=128, dv=256, CHUNK=128)
// Round: fp16 single-plane projection GEMMs. The bf16 hi/lo 3-combo pair GEMM
// (2^-16 rel err) was precision overkill: V/G are stored bf16 (4e-3) right
// after, and absmax is set by downstream o/OG rounding. fp16 inputs (2^-11)
// keep all those budgets while doing 3x less MFMA work and 2x less staging.
// ln_gate now writes OG as fp16 (finer than bf16), final GEMM is all-fp16.
//
// ws layout (112.5 MiB guard unchanged):
//   QK [0,64Mi)      fp32 [q | k/16] [8192][2048] -> interleaved decorated u32
//                    (gla_decor, in place) -> reused as final C
//   V  [64Mi,96Mi)   bf16 [8192][2048]
//   Wt [96Mi,104Mi)  weight^T fp16 single plane (serially reused)
//   dl  at [104Mi)   256KB fp32
//   xg1 [112Mi,+512K)
// d_out scratch timeline:
//   [0,32Mi):  xf fp16 (xcvt..g-gemm) -> Oh fp16 o -> OG fp16 (ln_gate..final)
//   [32Mi,64Mi): G bf16 (g-gemm..ln_gate)
//   final C memcpy'd over everything last.
// ---------------------------------------------------------------------------

typedef unsigned short u16;
typedef unsigned int u32;
typedef __bf16 bf16x8 __attribute__((ext_vector_type(8)));
typedef _Float16 f16x8 __attribute__((ext_vector_type(8)));
typedef float f32x4 __attribute__((ext_vector_type(4)));

__device__ __forceinline__ u16 f2bf(float f) {
  u32 u = __float_as_uint(f);
  u32 r = (u + 0x7fffu + ((u >> 16) & 1u)) >> 16;   // RNE
  return (u16)r;
}
__device__ __forceinline__ float bf2f(u16 s) {
  return __uint_as_float(((u32)s) << 16);
}
__device__ __forceinline__ u16 f2h(float f) {
  _Float16 h = (_Float16)f;                          // RNE fp32->fp16
  return __builtin_bit_cast(u16, h);
}
__device__ __forceinline__ float h2f(u16 u) {
  return (float)__builtin_bit_cast(_Float16, u);
}

// async global->LDS, 16B/lane. LDS dest = wave-uniform base + lane*16.
__device__ __forceinline__ void load_lds16(const void* g, void* l) {
  auto gp = (const __attribute__((address_space(1))) u32*)(uintptr_t)g;
  auto lp = (__attribute__((address_space(3))) u32*)(u32)(uintptr_t)l;
  __builtin_amdgcn_global_load_lds(gp, lp, 16, 0, 0);
}
__device__ __forceinline__ bf16x8 ldf(const u16* p) { return *(const bf16x8*)p; }
__device__ __forceinline__ f16x8 ldh(const u16* p) { return *(const f16x8*)p; }

// unpack 8 interleaved (hi,lo) u16 pairs (two uint4) -> hi/lo bf16x8 vectors
__device__ __forceinline__ void unpk(uint4 w0, uint4 w1, bf16x8& hi, bf16x8& lo) {
  union U { uint4 u; bf16x8 v; } a, b;
  a.u.x = __builtin_amdgcn_perm(w0.y, w0.x, 0x05040100u);
  a.u.y = __builtin_amdgcn_perm(w0.w, w0.z, 0x05040100u);
  a.u.z = __builtin_amdgcn_perm(w1.y, w1.x, 0x05040100u);
  a.u.w = __builtin_amdgcn_perm(w1.w, w1.z, 0x05040100u);
  b.u.x = __builtin_amdgcn_perm(w0.y, w0.x, 0x07060302u);
  b.u.y = __builtin_amdgcn_perm(w0.w, w0.z, 0x07060302u);
  b.u.z = __builtin_amdgcn_perm(w1.y, w1.x, 0x07060302u);
  b.u.w = __builtin_amdgcn_perm(w1.w, w1.z, 0x07060302u);
  hi = a.v;
  lo = b.v;
}

// ---------------------------------------------------------------------------
// xcvt: x fp32 -> fp16 plane (RNE), 8 elems/thread.
__global__ __launch_bounds__(256) void xcvt(const float* __restrict__ x,
                                            u16* __restrict__ xf) {
  const size_t i = ((size_t)blockIdx.x * 256 + threadIdx.x) * 8;
  float4 a = *(const float4*)&x[i];
  float4 b = *(const float4*)&x[i + 4];
  ushort4 h0, h1;
  h0.x = f2h(a.x); h0.y = f2h(a.y); h0.z = f2h(a.z); h0.w = f2h(a.w);
  h1.x = f2h(b.x); h1.y = f2h(b.y); h1.z = f2h(b.z); h1.w = f2h(b.w);
  *(ushort4*)&xf[i] = h0;
  *(ushort4*)&xf[i + 4] = h1;
}

// ---------------------------------------------------------------------------
// weight transpose -> fp16 single plane: dst[n][k] = f2h(src[k][n] * scale)
__global__ __launch_bounds__(256) void tpose_f16(const float* __restrict__ src,
                                                 u16* __restrict__ dst,
                                                 int srcRows, int srcStride,
                                                 float scale) {
  __shared__ float tile[32][33];
  const int tx = threadIdx.x, ty = threadIdx.y;     // block (32,8)
  const int n0 = blockIdx.x * 32, k0 = blockIdx.y * 32;
#pragma unroll
  for (int j = 0; j < 4; ++j) {
    int k = k0 + ty + j * 8;
    tile[ty + j * 8][tx] = src[(size_t)k * srcStride + n0 + tx] * scale;
  }
  __syncthreads();
#pragma unroll
  for (int j = 0; j < 4; ++j) {
    int n = n0 + ty + j * 8;
    float f = tile[tx][ty + j * 8];
    dst[(size_t)n * srcRows + k0 + tx] = f2h(f);
  }
}

// ---------------------------------------------------------------------------
// fp16 GEMM: C[M,N] = A_f16[M,K] @ Bt_f16[N,K]^T. 128x128 tile, BK=32,
// all staging via global_load_lds with chunk-XOR swizzle (2-way aliasing).
template <int OUTF32>
__global__ __launch_bounds__(256) void gemm_f16(const u16* __restrict__ A,
                                                const u16* __restrict__ Bt,
                                                void* __restrict__ C,
                                                int M, int N, int K) {
  __shared__ u16 As[128 * 32];
  __shared__ u16 Bs[128 * 32];
  const int tid = threadIdx.x;
  const int wave = tid >> 6, lane = tid & 63;
  const int wm = wave >> 1, wn = wave & 1;
  const int qu = lane >> 4, ln = lane & 15;
  const int m0 = blockIdx.y * 128, n0 = blockIdx.x * 128;
  const int crow = tid >> 2;
  const int csw = (((tid & 3) ^ ((crow >> 1) & 3)) << 3);   // swizzled src ofs
  f32x4 acc[4][4] = {};
  for (int kt = 0; kt < K; kt += 32) {
#pragma unroll
    for (int r = 0; r < 2; ++r) {
      const size_t ldst = (size_t)(r * 256 + wave * 64) * 8;
      load_lds16(A + (size_t)(m0 + crow + r * 64) * K + kt + csw, As + ldst);
      load_lds16(Bt + (size_t)(n0 + crow + r * 64) * K + kt + csw, Bs + ldst);
    }
    __syncthreads();
    f16x8 af[4], bfr[4];
#pragma unroll
    for (int t = 0; t < 4; ++t) {
      const int ia = wm * 64 + t * 16 + ln;
      const int ib = wn * 64 + t * 16 + ln;
      af[t] = ldh(&As[ia * 32 + ((qu ^ ((ia >> 1) & 3)) << 3)]);
      bfr[t] = ldh(&Bs[ib * 32 + ((qu ^ ((ib >> 1) & 3)) << 3)]);
    }
#pragma unroll
    for (int ti = 0; ti < 4; ++ti)
#pragma unroll
      for (int tj = 0; tj < 4; ++tj)
        acc[ti][tj] = __builtin_amdgcn_mfma_f32_16x16x32_f16(af[ti], bfr[tj], acc[ti][tj], 0, 0, 0);
    __syncthreads();
  }
#pragma unroll
  for (int ti = 0; ti < 4; ++ti)
#pragma unroll
    for (int tj = 0; tj < 4; ++tj) {
      const int rowb = m0 + wm * 64 + ti * 16 + qu * 4;   // C/D: row=(lane>>4)*4+reg
      const int col = n0 + wn * 64 + tj * 16 + ln;        //      col=lane&15
#pragma unroll
      for (int r = 0; r < 4; ++r) {
        size_t idx = (size_t)(rowb + r) * N + col;
        if (OUTF32) ((float*)C)[idx] = acc[ti][tj][r];
        else        ((u16*)C)[idx] = f2bf(acc[ti][tj][r]);
      }
    }
}

// ---------------------------------------------------------------------------
// xg1[8192,16] = x[8192,2048] @ Wkg1[2048,16]   (fp32, tiled)
__global__ __launch_bounds__(256) void xg1_gemm(const float* __restrict__ x,
                                                const float* __restrict__ W1,
                                                float* __restrict__ xg1) {
  __shared__ float xs[64][40];
  __shared__ float ws2[32][16];
  const int tid = threadIdx.x;
  const int r0 = blockIdx.x * 64;
  const int col = tid & 15, rsub = tid >> 4;
  float acc[4] = {0.f, 0.f, 0.f, 0.f};
  for (int kt = 0; kt < 2048; kt += 32) {
#pragma unroll
    for (int j = 0; j < 2; ++j) {
      int c = j * 256 + tid;
      int row = c >> 3, kk = (c & 7) << 2;
      *(float4*)&xs[row][kk] = *(const float4*)&x[(size_t)(r0 + row) * 2048 + kt + kk];
    }
#pragma unroll
    for (int j = 0; j < 2; ++j) {
      int c = j * 256 + tid;
      ws2[c >> 4][c & 15] = W1[(size_t)(kt + (c >> 4)) * 16 + (c & 15)];
    }
    __syncthreads();
#pragma unroll
    for (int kk = 0; kk < 32; ++kk) {
      float wv = ws2[kk][col];
#pragma unroll
      for (int j = 0; j < 4; ++j) acc[j] += xs[rsub + j * 16][kk] * wv;
    }
    __syncthreads();
  }
#pragma unroll
  for (int j = 0; j < 4; ++j) xg1[(size_t)(r0 + rsub + j * 16) * 16 + col] = acc[j];
}

// ---------------------------------------------------------------------------
// gla_decor: grid 512 = (b * 16 + n) * 8 + headgroup; 256 threads =
// 128 q-cols + 128 k-cols of that head. Each thread reads its fp32 value and
// overwrites THE SAME 4 bytes with (hi | lo<<16) -> fully race-free in-place.
__global__ __launch_bounds__(256) void gla_decor(float* __restrict__ QK,
                                                 const float* __restrict__ xg1,
                                                 const float* __restrict__ W2,
                                                 const float* __restrict__ b2,
                                                 float* __restrict__ dl) {
  __shared__ float xg1s[128][16];   // 8KB
  const int tid = threadIdx.x;
  const int bi = blockIdx.x;
  const int b = bi >> 7, n = (bi >> 3) & 15, g = bi & 7;
  const int t0 = b * 2048 + n * 128;
  const bool isK = tid >= 128;
  const int ci = tid & 127;
  const int col = g * 128 + ci;            // global col 0..1023
  u32* base = (u32*)QK + (size_t)t0 * 2048 + (isK ? 1024 : 0) + col;
  float w2r[16];
#pragma unroll
  for (int k = 0; k < 16; ++k) w2r[k] = W2[k * 1024 + col];
  const float b2r = b2[col];
  for (int e = tid; e < 2048; e += 256)
    xg1s[e >> 4][e & 15] = xg1[(size_t)(t0 + (e >> 4)) * 16 + (e & 15)];
  __syncthreads();
  float acc = 0.f;
  const float sgn = isK ? -1.f : 1.f;
  for (int s = 0; s < 128; s += 16) {
    float qv[16];
#pragma unroll
    for (int j = 0; j < 16; ++j) qv[j] = __uint_as_float(base[(size_t)(s + j) * 2048]);
    u32 ov[16];
#pragma unroll
    for (int j = 0; j < 16; ++j) {
      float z = b2r;
#pragma unroll
      for (int kk = 0; kk < 16; ++kk) z += xg1s[s + j][kk] * w2r[kk];
      float gk = (fminf(z, 0.f) - log1pf(expf(-fabsf(z)))) * 0.0625f;
      acc += gk;
      float e = expf(sgn * acc);
      float v = qv[j] * e;
      u16 h = f2bf(v);
      u16 l = f2bf(v - bf2f(h));
      ov[j] = (u32)h | ((u32)l << 16);
    }
#pragma unroll
    for (int j = 0; j < 16; ++j) base[(size_t)(s + j) * 2048] = ov[j];
  }
  if (isK) dl[((size_t)(b * 8 + g) * 16 + n) * 128 + ci] = expf(acc);
}

// ---------------------------------------------------------------------------
// gla_intra: per (b,h,chunk): A = tril(QD@KE^T) (3-combo), o_intra = A@V^T
// (2-combo) -> Oh fp16. Q/K staged as interleaved windows, source-swizzled
// (chunk ^ row&7); frag reads unpack hi/lo via v_perm (2-way bank aliasing).
__global__ __launch_bounds__(256) void gla_intra(const u16* __restrict__ QKu,
                                                 const u16* __restrict__ V,
                                                 u16* __restrict__ Oh) {
  // pool: stage Qi [0,8192) u16, Ki [8192,16384); Amh [0,16384) Aml [16384,32768);
  //       VTs [32768, 32768+7168) = [128][56] u16 pad
  __shared__ u16 pool[39936];   // 79872 B -> 2 blocks/CU
  const int tid = threadIdx.x;
  const int bi = blockIdx.x;
  const int n = bi & 15, h = (bi >> 4) & 7, b = bi >> 7;
  const int t0 = b * 2048 + n * 128;
  const int wave = tid >> 6, lane = tid & 63;
  const int wm = wave >> 1, wn = wave & 1;
  const int qu = lane >> 4, ln = lane & 15;
  const int srow = tid >> 3, schk = tid & 7;
  const int sc = ((schk ^ (srow & 7)) << 3);   // swizzled source u16 offset
  u16* Qi = pool;
  u16* Ki = pool + 8192;
  u16* Amh = pool;
  u16* Aml = pool + 16384;
  u16* VTs = pool + 32768;
  // ---- phase A: A = QD @ KE^T  (3-combo hi/lo)
  f32x4 acc[4][4] = {};
  for (int kt = 0; kt < 128; kt += 32) {
#pragma unroll
    for (int r = 0; r < 4; ++r) {
      const int row = srow + r * 32;
      const size_t gb = (size_t)(t0 + row) * 4096 + h * 256 + 2 * kt + sc;
      load_lds16(QKu + gb,        Qi + (r * 32 + wave * 8) * 64);
      load_lds16(QKu + gb + 2048, Ki + (r * 32 + wave * 8) * 64);
    }
    __syncthreads();
    bf16x8 ah[4], al[4], bh[4], bl[4];
#pragma unroll
    for (int t = 0; t < 4; ++t) {
      const int i = wm * 64 + t * 16 + ln;
      const u16* pQ = &Qi[i * 64];
      uint4 w0 = *(const uint4*)&pQ[((2 * qu) ^ (i & 7)) << 3];
      uint4 w1 = *(const uint4*)&pQ[((2 * qu + 1) ^ (i & 7)) << 3];
      unpk(w0, w1, ah[t], al[t]);
      const int j = wn * 64 + t * 16 + ln;
      const u16* pK = &Ki[j * 64];
      uint4 y0 = *(const uint4*)&pK[((2 * qu) ^ (j & 7)) << 3];
      uint4 y1 = *(const uint4*)&pK[((2 * qu + 1) ^ (j & 7)) << 3];
      unpk(y0, y1, bh[t], bl[t]);
    }
#pragma unroll
    for (int ti = 0; ti < 4; ++ti)
#pragma unroll
      for (int tj = 0; tj < 4; ++tj) {
        acc[ti][tj] = __builtin_amdgcn_mfma_f32_16x16x32_bf16(ah[ti], bh[tj], acc[ti][tj], 0, 0, 0);
        acc[ti][tj] = __builtin_amdgcn_mfma_f32_16x16x32_bf16(ah[ti], bl[tj], acc[ti][tj], 0, 0, 0);
        acc[ti][tj] = __builtin_amdgcn_mfma_f32_16x16x32_bf16(al[ti], bh[tj], acc[ti][tj], 0, 0, 0);
      }
    __syncthreads();
  }
  // ---- phase B: causal mask + hi/lo split -> Am (swizzled), aliases stage
#pragma unroll
  for (int ti = 0; ti < 4; ++ti)
#pragma unroll
    for (int tj = 0; tj < 4; ++tj) {
      const int ib = wm * 64 + ti * 16 + qu * 4;
      const int j = wn * 64 + tj * 16 + ln;
#pragma unroll
      for (int r = 0; r < 4; ++r) {
        const int i = ib + r;
        float v = (j <= i) ? acc[ti][tj][r] : 0.f;
        u16 hi = f2bf(v);
        const int idx = i * 128 + (j ^ ((i & 15) << 3));
        Amh[idx] = hi;
        Aml[idx] = f2bf(v - bf2f(hi));
      }
    }
  // ---- phase C: o_intra = Am @ V^T (2-combo), two dv-halves of 128
  for (int half = 0; half < 2; ++half) {
    f32x4 acc2[4][4] = {};
    for (int kt = 0; kt < 128; kt += 32) {
      __syncthreads();   // Am visible (first iter) / prev VTs reads done
      {  // stage VTs[dv][t] transposed from V, pad 56
        const int j = tid & 31, dvg = tid >> 5;
#pragma unroll
        for (int rr = 0; rr < 2; ++rr) {
          const int dg = dvg + rr * 8;
          uint4 pv = *(const uint4*)(V + (size_t)(t0 + kt + j) * 2048 + h * 256 + half * 128 + dg * 8);
          u16* dst = VTs + (dg * 8) * 56 + j;
          dst[0]      = (u16)pv.x; dst[56]      = (u16)(pv.x >> 16);
          dst[2 * 56] = (u16)pv.y; dst[3 * 56]  = (u16)(pv.y >> 16);
          dst[4 * 56] = (u16)pv.z; dst[5 * 56]  = (u16)(pv.z >> 16);
          dst[6 * 56] = (u16)pv.w; dst[7 * 56]  = (u16)(pv.w >> 16);
        }
      }
      __syncthreads();
      bf16x8 amh[4], aml[4], bv[4];
#pragma unroll
      for (int t = 0; t < 4; ++t) {
        const int i = wm * 64 + t * 16 + ln;
        const int cof = (kt + qu * 8) ^ ((i & 15) << 3);
        amh[t] = ldf(&Amh[i * 128 + cof]);
        aml[t] = ldf(&Aml[i * 128 + cof]);
        bv[t] = ldf(&VTs[(wn * 64 + t * 16 + ln) * 56 + qu * 8]);
      }
#pragma unroll
      for (int ti = 0; ti < 4; ++ti)
#pragma unroll
        for (int tj = 0; tj < 4; ++tj) {
          acc2[ti][tj] = __builtin_amdgcn_mfma_f32_16x16x32_bf16(amh[ti], bv[tj], acc2[ti][tj], 0, 0, 0);
          acc2[ti][tj] = __builtin_amdgcn_mfma_f32_16x16x32_bf16(aml[ti], bv[tj], acc2[ti][tj], 0, 0, 0);
        }
    }
#pragma unroll
    for (int ti = 0; ti < 4; ++ti)
#pragma unroll
      for (int tj = 0; tj < 4; ++tj)
#pragma unroll
        for (int r = 0; r < 4; ++r) {
          const int i = wm * 64 + ti * 16 + qu * 4 + r;
          const int col = half * 128 + wn * 64 + tj * 16 + ln;
          Oh[(size_t)(t0 + i) * 2048 + h * 256 + col] = f2h(acc2[ti][tj][r]);
        }
  }
}

// ---------------------------------------------------------------------------
// gla_inter: serial 16-chunk scan. Grid 256 = (dv-slice 0..7)x(b,h).
__global__ __launch_bounds__(256) void gla_inter(const u16* __restrict__ QKu,
                                                 const u16* __restrict__ V,
                                                 const float* __restrict__ dl,
                                                 u16* __restrict__ Oh) {
  __shared__ float STf[32 * 128];     // 16KB  S (fp32 master), [dv][d]
  __shared__ u16 STh[32 * 136];       // 8.5KB (pad 136 -> 2-way reads)
  __shared__ u16 STl[32 * 136];
  __shared__ u16 Qi2[128 * 64];       // 16KB interleaved QD window
  __shared__ u16 KTh[128 * 56];       // 14KB (pad 56)
  __shared__ u16 KTl[128 * 56];
  __shared__ u16 VTs2[32 * 56];       // 3.5KB
  __shared__ float dls[128];
  const int tid = threadIdx.x;
  const int bi = blockIdx.x;
  const int sl = bi >> 5, g = bi & 31, b = g >> 3, h = g & 7;
  const int wave = tid >> 6, lane = tid & 63;
  const int qu = lane >> 4, ln = lane & 15;
  const int srow = tid >> 3, schk = tid & 7;
  const int sc = ((schk ^ (srow & 7)) << 3);
  const int bh16 = (b * 8 + h) * 16;
  for (int e = tid; e < 4096; e += 256) STf[e] = 0.f;
  for (int c = 0; c < 16; ++c) {
    const int t0 = b * 2048 + c * 128;
    if (tid < 128) dls[tid] = dl[(size_t)(bh16 + c) * 128 + tid];
    __syncthreads();   // B1: dls + STf(zero/update) visible
    if (c > 0) {
      // split S -> hi/lo planes
      for (int e = tid; e < 4096; e += 256) {
        const int row = e >> 7, col = e & 127;
        float v = STf[e];
        u16 hi = f2bf(v);
        STh[row * 136 + col] = hi;
        STl[row * 136 + col] = f2bf(v - bf2f(hi));
      }
      __syncthreads();
      // o_inter = QD_c @ S_prev (3-combo)
      f32x4 aco[2][2] = {};
      for (int kt = 0; kt < 128; kt += 32) {
#pragma unroll
        for (int r = 0; r < 4; ++r) {
          const int row = srow + r * 32;
          load_lds16(QKu + (size_t)(t0 + row) * 4096 + h * 256 + 2 * kt + sc,
                     Qi2 + (r * 32 + wave * 8) * 64);
        }
        __syncthreads();
        bf16x8 qh[2], ql[2], sh[2], slo[2];
#pragma unroll
        for (int t = 0; t < 2; ++t) {
          const int ar = wave * 32 + t * 16 + ln;
          const u16* pQ = &Qi2[ar * 64];
          uint4 w0 = *(const uint4*)&pQ[((2 * qu) ^ (ar & 7)) << 3];
          uint4 w1 = *(const uint4*)&pQ[((2 * qu + 1) ^ (ar & 7)) << 3];
          unpk(w0, w1, qh[t], ql[t]);
          const int br = t * 16 + ln;
          sh[t]  = ldf(&STh[br * 136 + kt + qu * 8]);
          slo[t] = ldf(&STl[br * 136 + kt + qu * 8]);
        }
#pragma unroll
        for (int ti = 0; ti < 2; ++ti)
#pragma unroll
          for (int tj = 0; tj < 2; ++tj) {
            aco[ti][tj] = __builtin_amdgcn_mfma_f32_16x16x32_bf16(qh[ti], sh[tj], aco[ti][tj], 0, 0, 0);
            aco[ti][tj] = __builtin_amdgcn_mfma_f32_16x16x32_bf16(qh[ti], slo[tj], aco[ti][tj], 0, 0, 0);
            aco[ti][tj] = __builtin_amdgcn_mfma_f32_16x16x32_bf16(ql[ti], sh[tj], aco[ti][tj], 0, 0, 0);
          }
        __syncthreads();
      }
      // RMW Oh += o_inter (fp16; each cell owned by exactly one lane)
#pragma unroll
      for (int ti = 0; ti < 2; ++ti)
#pragma unroll
        for (int tj = 0; tj < 2; ++tj)
#pragma unroll
          for (int r = 0; r < 4; ++r) {
            const int i = wave * 32 + ti * 16 + qu * 4 + r;
            const int dv = tj * 16 + ln;
            u16* p = Oh + (size_t)(t0 + i) * 2048 + h * 256 + sl * 32 + dv;
            *p = f2h(h2f(*p) + aco[ti][tj][r]);
          }
    }
    // W^T = VT @ KET (2-combo), K = tokens
    f32x4 acw[2][2] = {};
    for (int kt = 0; kt < 128; kt += 32) {
      __syncthreads();   // prev frag reads done
      {  // stage KE (hi/lo from interleaved) transposed [d][t], pad 56
        const int t = tid & 31, dg0 = tid >> 5;
#pragma unroll
        for (int rr = 0; rr < 2; ++rr) {
          const int dg = dg0 + rr * 8;
          const size_t gb = (size_t)(t0 + kt + t) * 4096 + 2048 + h * 256 + dg * 16;
          uint4 w0 = *(const uint4*)(QKu + gb);
          uint4 w1 = *(const uint4*)(QKu + gb + 8);
          u16* dh = KTh + (dg * 8) * 56 + t;
          u16* dL = KTl + (dg * 8) * 56 + t;
          dh[0]      = (u16)w0.x; dL[0]      = (u16)(w0.x >> 16);
          dh[56]     = (u16)w0.y; dL[56]     = (u16)(w0.y >> 16);
          dh[2 * 56] = (u16)w0.z; dL[2 * 56] = (u16)(w0.z >> 16);
          dh[3 * 56] = (u16)w0.w; dL[3 * 56] = (u16)(w0.w >> 16);
          dh[4 * 56] = (u16)w1.x; dL[4 * 56] = (u16)(w1.x >> 16);
          dh[5 * 56] = (u16)w1.y; dL[5 * 56] = (u16)(w1.y >> 16);
          dh[6 * 56] = (u16)w1.z; dL[6 * 56] = (u16)(w1.z >> 16);
          dh[7 * 56] = (u16)w1.w; dL[7 * 56] = (u16)(w1.w >> 16);
        }
        if (tid < 128) {  // stage V slice transposed [dv][t]
          const int t2 = tid & 31, vg = tid >> 5;
          uint4 pv = *(const uint4*)(V + (size_t)(t0 + kt + t2) * 2048 + h * 256 + sl * 32 + vg * 8);
          u16* dst = VTs2 + (vg * 8) * 56 + t2;
          dst[0]      = (u16)pv.x; dst[56]     = (u16)(pv.x >> 16);
          dst[2 * 56] = (u16)pv.y; dst[3 * 56] = (u16)(pv.y >> 16);
          dst[4 * 56] = (u16)pv.z; dst[5 * 56] = (u16)(pv.z >> 16);
          dst[6 * 56] = (u16)pv.w; dst[7 * 56] = (u16)(pv.w >> 16);
        }
      }
      __syncthreads();
      bf16x8 av[2], kh[2], kl[2];
#pragma unroll
      for (int t = 0; t < 2; ++t) {
        av[t] = ldf(&VTs2[(t * 16 + ln) * 56 + qu * 8]);
        const int dr = wave * 32 + t * 16 + ln;
        kh[t] = ldf(&KTh[dr * 56 + qu * 8]);
        kl[t] = ldf(&KTl[dr * 56 + qu * 8]);
      }
#pragma unroll
      for (int ti = 0; ti < 2; ++ti)
#pragma unroll
        for (int tj = 0; tj < 2; ++tj) {
          acw[ti][tj] = __builtin_amdgcn_mfma_f32_16x16x32_bf16(av[ti], kh[tj], acw[ti][tj], 0, 0, 0);
          acw[ti][tj] = __builtin_amdgcn_mfma_f32_16x16x32_bf16(av[ti], kl[tj], acw[ti][tj], 0, 0, 0);
        }
    }
    // S = dl (.) (S + W)   (each (dv,d) owned by one lane)
#pragma unroll
    for (int ti = 0; ti < 2; ++ti)
#pragma unroll
      for (int tj = 0; tj < 2; ++tj)
#pragma unroll
        for (int r = 0; r < 4; ++r) {
          const int dv = ti * 16 + qu * 4 + r;
          const int d = wave * 32 + tj * 16 + ln;
          const int e = dv * 128 + d;
          STf[e] = dls[d] * (STf[e] + acw[ti][tj][r]);
        }
    __syncthreads();   // B4: S update visible before next chunk's split/dls
  }
}

// ---------------------------------------------------------------------------
// LayerNorm(256) + silu(g) gate; sums via segmented in-wave shuffles
// (head = 32-lane group). Reads o fp16, rewrites IN PLACE as OG fp16.
__global__ __launch_bounds__(256) void ln_gate(u16* __restrict__ O,
                                               const u16* __restrict__ G,
                                               const float* __restrict__ bg) {
  const int tglob = blockIdx.x;        // token row 0..8191
  const int tid = threadIdx.x;
  const int c0 = tid << 3;             // 8 elements per thread
  const size_t base = (size_t)tglob * 2048 + c0;
  ushort4 oa = *(const ushort4*)&O[base];
  ushort4 ob = *(const ushort4*)&O[base + 4];
  float f0 = h2f(oa.x), f1 = h2f(oa.y), f2 = h2f(oa.z), f3 = h2f(oa.w);
  float f4 = h2f(ob.x), f5 = h2f(ob.y), f6 = h2f(ob.z), f7 = h2f(ob.w);
  float s = f0 + f1 + f2 + f3 + f4 + f5 + f6 + f7;
  float ss = f0 * f0 + f1 * f1 + f2 * f2 + f3 * f3 + f4 * f4 + f5 * f5 + f6 * f6 + f7 * f7;
#pragma unroll
  for (int off = 1; off <= 16; off <<= 1) {
    s += __shfl_xor(s, off, 64);
    ss += __shfl_xor(ss, off, 64);
  }
  const float mean = s * (1.f / 256.f);
  const float rstd = rsqrtf(ss * (1.f / 256.f) - mean * mean + 1e-5f);
  ushort4 ga = *(const ushort4*)&G[base];
  ushort4 gb4 = *(const ushort4*)&G[base + 4];
  float4 bga = *(const float4*)&bg[c0];
  float4 bgb = *(const float4*)&bg[c0 + 4];
  auto one = [&](float ov, u16 gu, float bgv) -> u16 {
    float gg = bf2f(gu) + bgv;
    return f2h((ov - mean) * rstd * (gg / (1.f + expf(-gg))));
  };
  ushort4 ra, rb;
  ra.x = one(f0, ga.x, bga.x);  ra.y = one(f1, ga.y, bga.y);
  ra.z = one(f2, ga.z, bga.z);  ra.w = one(f3, ga.w, bga.w);
  rb.x = one(f4, gb4.x, bgb.x); rb.y = one(f5, gb4.y, bgb.y);
  rb.z = one(f6, gb4.z, bgb.z); rb.w = one(f7, gb4.w, bgb.w);
  *(ushort4*)&O[base] = ra;
  *(ushort4*)&O[base + 4] = rb;
}

// ---------------------------------------------------------------------------
extern "C" void kernel_launch(void* const* d_in, const int* in_sizes, int n_in,
                              void* d_out, int out_size, void* d_ws, size_t ws_size,
                              hipStream_t stream) {
  (void)in_sizes; (void)n_in; (void)out_size;
  if (ws_size < 117964800ull) return;   // fail soft

  const float* x    = (const float*)d_in[0];
  const float* Wq   = (const float*)d_in[1];
  const float* Wk   = (const float*)d_in[2];
  const float* Wkg1 = (const float*)d_in[3];
  const float* Wkg2 = (const float*)d_in[4];
  const float* bkg2 = (const float*)d_in[5];
  const float* Wv   = (const float*)d_in[6];
  const float* Wg   = (const float*)d_in[7];
  const float* bg   = (const float*)d_in[8];
  const float* Wo   = (const float*)d_in[9];

  char* ws = (char*)d_ws;
  float* QK  = (float*)(ws + 0);           // 64 MiB fp32 -> interleaved decorated
  u16*   QKu = (u16*)QK;
  u16*   V   = (u16*)(ws + 67108864);      // 32 MiB bf16
  u16*   Wt  = (u16*)(ws + 100663296);     //  8 MiB weight^T fp16 (serially reused)
  float* xg1 = (float*)(ws + 117440512);   // 0.5 MiB
  float* Cf  = QK;                         // final GEMM C (decorated dead by then)
  float* dl  = (float*)(ws + 109051904);   // 256 KiB (old WtB region, now free)

  // d_out scratch: xf fp16 [0,32Mi) -> Oh fp16 (after g-gemm); G bf16 [32Mi,64Mi)
  u16* xf = (u16*)d_out;
  u16* Oh = (u16*)d_out;                   // after g-gemm (xf dead)
  u16* G  = (u16*)d_out + 16777216;

  dim3 tb(32, 8);

  xg1_gemm<<<dim3(128), dim3(256), 0, stream>>>(x, Wkg1, xg1);
  xcvt<<<dim3(8192), dim3(256), 0, stream>>>(x, xf);

  // [q|k] projection, fp32 out (Wk folded with (D/H)^-0.5 = 1/16, exact pow2)
  tpose_f16<<<dim3(32, 64), tb, 0, stream>>>(Wq, Wt,               2048, 1024, 1.0f);
  tpose_f16<<<dim3(32, 64), tb, 0, stream>>>(Wk, Wt + 1024 * 2048, 2048, 1024, 0.0625f);
  gemm_f16<1><<<dim3(16, 64), dim3(256), 0, stream>>>(xf, Wt, (void*)QK, 8192, 2048, 2048);

  // v projection, bf16 out
  tpose_f16<<<dim3(64, 64), tb, 0, stream>>>(Wv, Wt, 2048, 2048, 1.0f);
  gemm_f16<0><<<dim3(16, 64), dim3(256), 0, stream>>>(xf, Wt, (void*)V, 8192, 2048, 2048);

  // g projection, bf16 out -> G
  tpose_f16<<<dim3(64, 64), tb, 0, stream>>>(Wg, Wt, 2048, 2048, 1.0f);
  gemm_f16<0><<<dim3(16, 64), dim3(256), 0, stream>>>(xf, Wt, (void*)G, 8192, 2048, 2048);

  // chunked GLA on MFMA (xf dead from here; Oh takes its region)
  gla_decor<<<dim3(512), dim3(256), 0, stream>>>(QK, xg1, Wkg2, bkg2, dl);
  gla_intra<<<dim3(512), dim3(256), 0, stream>>>(QKu, V, Oh);
  gla_inter<<<dim3(256), dim3(256), 0, stream>>>(QKu, V, dl, Oh);
  ln_gate<<<dim3(8192), dim3(256), 0, stream>>>(Oh, G, bg);

  // final projection: OG fp16 @ Wo^T fp16 -> fp32, then d2d to d_out
  tpose_f16<<<dim3(64, 64), tb, 0, stream>>>(Wo, Wt, 2048, 2048, 1.0f);
  gemm_f16<1><<<dim3(16, 64), dim3(256), 0, stream>>>(Oh, Wt, (void*)Cf, 8192, 2048, 2048);
  hipMemcpyAsync(d_out, Cf, 67108864ull, hipMemcpyDeviceToDevice, stream);
}

// Round 6
// 941.437 us; speedup vs baseline: 4.0778x; 1.0753x over previous
//
#include <hip/hip_runtime.h>
#include <stdint.h>

// ---------------------------------------------------------------------------
// GatedLinearAttention (b=4, T=2048, D=2048, H=8, dk=128, dv=256, CHUNK=128)
// Round: de-serialize the inter-chunk path.
//   gla_w (parallel, 512 blocks): W_c = KE_c^T @ V_c (2-combo), fp16, written
//     IN-PLACE over V's chunk slot (V dead after gla_intra; block-disjoint).
//   gla_scan (serial 16 chunks, 256 blocks): per chunk only 3 barriers:
//     W-prefetch(regs) | split S | stage FULL QD window | o_inter (4 dk-steps,
//     no inner barriers) | Oh RMW | S = dl (.) (S + W).
//   ln_gate writes OG to ws (dead QK region); final GEMM writes fp32 straight
//   to d_out -> 64MiB d2d memcpy removed. xcvt fused into xg1_gemm.
//
// ws layout (112.5 MiB guard unchanged):
//   QK [0,64Mi)      fp32 [q | k/16] -> interleaved decorated u32 (in-place)
//                    -> OG fp16 [0,32Mi) after ln_gate
//   V  [64Mi,96Mi)   bf16 v -> W fp16 (gla_w, in-place per chunk slot)
//   Wt [96Mi,104Mi)  weight^T fp16 single plane (serially reused)
//   dl  at [104Mi)   256KB fp32
//   xg1 [112Mi,+512K)
// d_out timeline: xf fp16 [0,32Mi) -> Oh fp16 (intra..ln_gate); G bf16
//   [32Mi,64Mi) (g-gemm..ln_gate); final C fp32 [0,64Mi) written by last GEMM.
// ---------------------------------------------------------------------------

typedef unsigned short u16;
typedef unsigned int u32;
typedef __bf16 bf16x8 __attribute__((ext_vector_type(8)));
typedef _Float16 f16x8 __attribute__((ext_vector_type(8)));
typedef float f32x4 __attribute__((ext_vector_type(4)));

__device__ __forceinline__ u16 f2bf(float f) {
  u32 u = __float_as_uint(f);
  u32 r = (u + 0x7fffu + ((u >> 16) & 1u)) >> 16;   // RNE
  return (u16)r;
}
__device__ __forceinline__ float bf2f(u16 s) {
  return __uint_as_float(((u32)s) << 16);
}
__device__ __forceinline__ u16 f2h(float f) {
  _Float16 h = (_Float16)f;                          // RNE fp32->fp16
  return __builtin_bit_cast(u16, h);
}
__device__ __forceinline__ float h2f(u16 u) {
  return (float)__builtin_bit_cast(_Float16, u);
}

// async global->LDS, 16B/lane. LDS dest = wave-uniform base + lane*16.
__device__ __forceinline__ void load_lds16(const void* g, void* l) {
  auto gp = (const __attribute__((address_space(1))) u32*)(uintptr_t)g;
  auto lp = (__attribute__((address_space(3))) u32*)(u32)(uintptr_t)l;
  __builtin_amdgcn_global_load_lds(gp, lp, 16, 0, 0);
}
__device__ __forceinline__ bf16x8 ldf(const u16* p) { return *(const bf16x8*)p; }
__device__ __forceinline__ f16x8 ldh(const u16* p) { return *(const f16x8*)p; }

// unpack 8 interleaved (hi,lo) u16 pairs (two uint4) -> hi/lo bf16x8 vectors
__device__ __forceinline__ void unpk(uint4 w0, uint4 w1, bf16x8& hi, bf16x8& lo) {
  union U { uint4 u; bf16x8 v; } a, b;
  a.u.x = __builtin_amdgcn_perm(w0.y, w0.x, 0x05040100u);
  a.u.y = __builtin_amdgcn_perm(w0.w, w0.z, 0x05040100u);
  a.u.z = __builtin_amdgcn_perm(w1.y, w1.x, 0x05040100u);
  a.u.w = __builtin_amdgcn_perm(w1.w, w1.z, 0x05040100u);
  b.u.x = __builtin_amdgcn_perm(w0.y, w0.x, 0x07060302u);
  b.u.y = __builtin_amdgcn_perm(w0.w, w0.z, 0x07060302u);
  b.u.z = __builtin_amdgcn_perm(w1.y, w1.x, 0x07060302u);
  b.u.w = __builtin_amdgcn_perm(w1.w, w1.z, 0x07060302u);
  hi = a.v;
  lo = b.v;
}

// ---------------------------------------------------------------------------
// weight transpose -> fp16 single plane: dst[n][k] = f2h(src[k][n] * scale)
__global__ __launch_bounds__(256) void tpose_f16(const float* __restrict__ src,
                                                 u16* __restrict__ dst,
                                                 int srcRows, int srcStride,
                                                 float scale) {
  __shared__ float tile[32][33];
  const int tx = threadIdx.x, ty = threadIdx.y;     // block (32,8)
  const int n0 = blockIdx.x * 32, k0 = blockIdx.y * 32;
#pragma unroll
  for (int j = 0; j < 4; ++j) {
    int k = k0 + ty + j * 8;
    tile[ty + j * 8][tx] = src[(size_t)k * srcStride + n0 + tx] * scale;
  }
  __syncthreads();
#pragma unroll
  for (int j = 0; j < 4; ++j) {
    int n = n0 + ty + j * 8;
    float f = tile[tx][ty + j * 8];
    dst[(size_t)n * srcRows + k0 + tx] = f2h(f);
  }
}

// ---------------------------------------------------------------------------
// fp16 GEMM: C[M,N] = A_f16[M,K] @ Bt_f16[N,K]^T. 128x128 tile, BK=32,
// all staging via global_load_lds with chunk-XOR swizzle (2-way aliasing).
template <int OUTF32>
__global__ __launch_bounds__(256) void gemm_f16(const u16* __restrict__ A,
                                                const u16* __restrict__ Bt,
                                                void* __restrict__ C,
                                                int M, int N, int K) {
  __shared__ u16 As[128 * 32];
  __shared__ u16 Bs[128 * 32];
  const int tid = threadIdx.x;
  const int wave = tid >> 6, lane = tid & 63;
  const int wm = wave >> 1, wn = wave & 1;
  const int qu = lane >> 4, ln = lane & 15;
  const int m0 = blockIdx.y * 128, n0 = blockIdx.x * 128;
  const int crow = tid >> 2;
  const int csw = (((tid & 3) ^ ((crow >> 1) & 3)) << 3);   // swizzled src ofs
  f32x4 acc[4][4] = {};
  for (int kt = 0; kt < K; kt += 32) {
#pragma unroll
    for (int r = 0; r < 2; ++r) {
      const size_t ldst = (size_t)(r * 256 + wave * 64) * 8;
      load_lds16(A + (size_t)(m0 + crow + r * 64) * K + kt + csw, As + ldst);
      load_lds16(Bt + (size_t)(n0 + crow + r * 64) * K + kt + csw, Bs + ldst);
    }
    __syncthreads();
    f16x8 af[4], bfr[4];
#pragma unroll
    for (int t = 0; t < 4; ++t) {
      const int ia = wm * 64 + t * 16 + ln;
      const int ib = wn * 64 + t * 16 + ln;
      af[t] = ldh(&As[ia * 32 + ((qu ^ ((ia >> 1) & 3)) << 3)]);
      bfr[t] = ldh(&Bs[ib * 32 + ((qu ^ ((ib >> 1) & 3)) << 3)]);
    }
#pragma unroll
    for (int ti = 0; ti < 4; ++ti)
#pragma unroll
      for (int tj = 0; tj < 4; ++tj)
        acc[ti][tj] = __builtin_amdgcn_mfma_f32_16x16x32_f16(af[ti], bfr[tj], acc[ti][tj], 0, 0, 0);
    __syncthreads();
  }
#pragma unroll
  for (int ti = 0; ti < 4; ++ti)
#pragma unroll
    for (int tj = 0; tj < 4; ++tj) {
      const int rowb = m0 + wm * 64 + ti * 16 + qu * 4;   // C/D: row=(lane>>4)*4+reg
      const int col = n0 + wn * 64 + tj * 16 + ln;        //      col=lane&15
#pragma unroll
      for (int r = 0; r < 4; ++r) {
        size_t idx = (size_t)(rowb + r) * N + col;
        if (OUTF32) ((float*)C)[idx] = acc[ti][tj][r];
        else        ((u16*)C)[idx] = f2bf(acc[ti][tj][r]);
      }
    }
}

// ---------------------------------------------------------------------------
// xg1[8192,16] = x[8192,2048] @ Wkg1[2048,16] (fp32, tiled), fused with
// x -> fp16 conversion (xf) from the staged registers (x read once).
__global__ __launch_bounds__(256) void xg1_gemm(const float* __restrict__ x,
                                                const float* __restrict__ W1,
                                                float* __restrict__ xg1,
                                                u16* __restrict__ xf) {
  __shared__ float xs[64][40];
  __shared__ float ws2[32][16];
  const int tid = threadIdx.x;
  const int r0 = blockIdx.x * 64;
  const int col = tid & 15, rsub = tid >> 4;
  float acc[4] = {0.f, 0.f, 0.f, 0.f};
  for (int kt = 0; kt < 2048; kt += 32) {
#pragma unroll
    for (int j = 0; j < 2; ++j) {
      int c = j * 256 + tid;
      int row = c >> 3, kk = (c & 7) << 2;
      float4 f4 = *(const float4*)&x[(size_t)(r0 + row) * 2048 + kt + kk];
      *(float4*)&xs[row][kk] = f4;
      ushort4 hq;
      hq.x = f2h(f4.x); hq.y = f2h(f4.y); hq.z = f2h(f4.z); hq.w = f2h(f4.w);
      *(ushort4*)&xf[(size_t)(r0 + row) * 2048 + kt + kk] = hq;
    }
#pragma unroll
    for (int j = 0; j < 2; ++j) {
      int c = j * 256 + tid;
      ws2[c >> 4][c & 15] = W1[(size_t)(kt + (c >> 4)) * 16 + (c & 15)];
    }
    __syncthreads();
#pragma unroll
    for (int kk = 0; kk < 32; ++kk) {
      float wv = ws2[kk][col];
#pragma unroll
      for (int j = 0; j < 4; ++j) acc[j] += xs[rsub + j * 16][kk] * wv;
    }
    __syncthreads();
  }
#pragma unroll
  for (int j = 0; j < 4; ++j) xg1[(size_t)(r0 + rsub + j * 16) * 16 + col] = acc[j];
}

// ---------------------------------------------------------------------------
// gla_decor: grid 512 = (b * 16 + n) * 8 + headgroup; 256 threads =
// 128 q-cols + 128 k-cols of that head. Each thread reads its fp32 value and
// overwrites THE SAME 4 bytes with (hi | lo<<16) -> fully race-free in-place.
__global__ __launch_bounds__(256) void gla_decor(float* __restrict__ QK,
                                                 const float* __restrict__ xg1,
                                                 const float* __restrict__ W2,
                                                 const float* __restrict__ b2,
                                                 float* __restrict__ dl) {
  __shared__ float xg1s[128][16];   // 8KB
  const int tid = threadIdx.x;
  const int bi = blockIdx.x;
  const int b = bi >> 7, n = (bi >> 3) & 15, g = bi & 7;
  const int t0 = b * 2048 + n * 128;
  const bool isK = tid >= 128;
  const int ci = tid & 127;
  const int col = g * 128 + ci;            // global col 0..1023
  u32* base = (u32*)QK + (size_t)t0 * 2048 + (isK ? 1024 : 0) + col;
  float w2r[16];
#pragma unroll
  for (int k = 0; k < 16; ++k) w2r[k] = W2[k * 1024 + col];
  const float b2r = b2[col];
  for (int e = tid; e < 2048; e += 256)
    xg1s[e >> 4][e & 15] = xg1[(size_t)(t0 + (e >> 4)) * 16 + (e & 15)];
  __syncthreads();
  float acc = 0.f;
  const float sgn = isK ? -1.f : 1.f;
  for (int s = 0; s < 128; s += 16) {
    float qv[16];
#pragma unroll
    for (int j = 0; j < 16; ++j) qv[j] = __uint_as_float(base[(size_t)(s + j) * 2048]);
    u32 ov[16];
#pragma unroll
    for (int j = 0; j < 16; ++j) {
      float z = b2r;
#pragma unroll
      for (int kk = 0; kk < 16; ++kk) z += xg1s[s + j][kk] * w2r[kk];
      float gk = (fminf(z, 0.f) - log1pf(expf(-fabsf(z)))) * 0.0625f;
      acc += gk;
      float e = expf(sgn * acc);
      float v = qv[j] * e;
      u16 h = f2bf(v);
      u16 l = f2bf(v - bf2f(h));
      ov[j] = (u32)h | ((u32)l << 16);
    }
#pragma unroll
    for (int j = 0; j < 16; ++j) base[(size_t)(s + j) * 2048] = ov[j];
  }
  if (isK) dl[((size_t)(b * 8 + g) * 16 + n) * 128 + ci] = expf(acc);
}

// ---------------------------------------------------------------------------
// gla_intra: per (b,h,chunk): A = tril(QD@KE^T) (3-combo), o_intra = A@V^T
// (2-combo) -> Oh fp16. Q/K staged as interleaved windows, source-swizzled
// (chunk ^ row&7); frag reads unpack hi/lo via v_perm (2-way bank aliasing).
__global__ __launch_bounds__(256) void gla_intra(const u16* __restrict__ QKu,
                                                 const u16* __restrict__ V,
                                                 u16* __restrict__ Oh) {
  // pool: stage Qi [0,8192) u16, Ki [8192,16384); Amh [0,16384) Aml [16384,32768);
  //       VTs [32768, 32768+7168) = [128][56] u16 pad
  __shared__ u16 pool[39936];   // 79872 B -> 2 blocks/CU
  const int tid = threadIdx.x;
  const int bi = blockIdx.x;
  const int n = bi & 15, h = (bi >> 4) & 7, b = bi >> 7;
  const int t0 = b * 2048 + n * 128;
  const int wave = tid >> 6, lane = tid & 63;
  const int wm = wave >> 1, wn = wave & 1;
  const int qu = lane >> 4, ln = lane & 15;
  const int srow = tid >> 3, schk = tid & 7;
  const int sc = ((schk ^ (srow & 7)) << 3);   // swizzled source u16 offset
  u16* Qi = pool;
  u16* Ki = pool + 8192;
  u16* Amh = pool;
  u16* Aml = pool + 16384;
  u16* VTs = pool + 32768;
  // ---- phase A: A = QD @ KE^T  (3-combo hi/lo)
  f32x4 acc[4][4] = {};
  for (int kt = 0; kt < 128; kt += 32) {
#pragma unroll
    for (int r = 0; r < 4; ++r) {
      const int row = srow + r * 32;
      const size_t gb = (size_t)(t0 + row) * 4096 + h * 256 + 2 * kt + sc;
      load_lds16(QKu + gb,        Qi + (r * 32 + wave * 8) * 64);
      load_lds16(QKu + gb + 2048, Ki + (r * 32 + wave * 8) * 64);
    }
    __syncthreads();
    bf16x8 ah[4], al[4], bh[4], bl[4];
#pragma unroll
    for (int t = 0; t < 4; ++t) {
      const int i = wm * 64 + t * 16 + ln;
      const u16* pQ = &Qi[i * 64];
      uint4 w0 = *(const uint4*)&pQ[((2 * qu) ^ (i & 7)) << 3];
      uint4 w1 = *(const uint4*)&pQ[((2 * qu + 1) ^ (i & 7)) << 3];
      unpk(w0, w1, ah[t], al[t]);
      const int j = wn * 64 + t * 16 + ln;
      const u16* pK = &Ki[j * 64];
      uint4 y0 = *(const uint4*)&pK[((2 * qu) ^ (j & 7)) << 3];
      uint4 y1 = *(const uint4*)&pK[((2 * qu + 1) ^ (j & 7)) << 3];
      unpk(y0, y1, bh[t], bl[t]);
    }
#pragma unroll
    for (int ti = 0; ti < 4; ++ti)
#pragma unroll
      for (int tj = 0; tj < 4; ++tj) {
        acc[ti][tj] = __builtin_amdgcn_mfma_f32_16x16x32_bf16(ah[ti], bh[tj], acc[ti][tj], 0, 0, 0);
        acc[ti][tj] = __builtin_amdgcn_mfma_f32_16x16x32_bf16(ah[ti], bl[tj], acc[ti][tj], 0, 0, 0);
        acc[ti][tj] = __builtin_amdgcn_mfma_f32_16x16x32_bf16(al[ti], bh[tj], acc[ti][tj], 0, 0, 0);
      }
    __syncthreads();
  }
  // ---- phase B: causal mask + hi/lo split -> Am (swizzled), aliases stage
#pragma unroll
  for (int ti = 0; ti < 4; ++ti)
#pragma unroll
    for (int tj = 0; tj < 4; ++tj) {
      const int ib = wm * 64 + ti * 16 + qu * 4;
      const int j = wn * 64 + tj * 16 + ln;
#pragma unroll
      for (int r = 0; r < 4; ++r) {
        const int i = ib + r;
        float v = (j <= i) ? acc[ti][tj][r] : 0.f;
        u16 hi = f2bf(v);
        const int idx = i * 128 + (j ^ ((i & 15) << 3));
        Amh[idx] = hi;
        Aml[idx] = f2bf(v - bf2f(hi));
      }
    }
  // ---- phase C: o_intra = Am @ V^T (2-combo), two dv-halves of 128
  for (int half = 0; half < 2; ++half) {
    f32x4 acc2[4][4] = {};
    for (int kt = 0; kt < 128; kt += 32) {
      __syncthreads();   // Am visible (first iter) / prev VTs reads done
      {  // stage VTs[dv][t] transposed from V, pad 56
        const int j = tid & 31, dvg = tid >> 5;
#pragma unroll
        for (int rr = 0; rr < 2; ++rr) {
          const int dg = dvg + rr * 8;
          uint4 pv = *(const uint4*)(V + (size_t)(t0 + kt + j) * 2048 + h * 256 + half * 128 + dg * 8);
          u16* dst = VTs + (dg * 8) * 56 + j;
          dst[0]      = (u16)pv.x; dst[56]      = (u16)(pv.x >> 16);
          dst[2 * 56] = (u16)pv.y; dst[3 * 56]  = (u16)(pv.y >> 16);
          dst[4 * 56] = (u16)pv.z; dst[5 * 56]  = (u16)(pv.z >> 16);
          dst[6 * 56] = (u16)pv.w; dst[7 * 56]  = (u16)(pv.w >> 16);
        }
      }
      __syncthreads();
      bf16x8 amh[4], aml[4], bv[4];
#pragma unroll
      for (int t = 0; t < 4; ++t) {
        const int i = wm * 64 + t * 16 + ln;
        const int cof = (kt + qu * 8) ^ ((i & 15) << 3);
        amh[t] = ldf(&Amh[i * 128 + cof]);
        aml[t] = ldf(&Aml[i * 128 + cof]);
        bv[t] = ldf(&VTs[(wn * 64 + t * 16 + ln) * 56 + qu * 8]);
      }
#pragma unroll
      for (int ti = 0; ti < 4; ++ti)
#pragma unroll
        for (int tj = 0; tj < 4; ++tj) {
          acc2[ti][tj] = __builtin_amdgcn_mfma_f32_16x16x32_bf16(amh[ti], bv[tj], acc2[ti][tj], 0, 0, 0);
          acc2[ti][tj] = __builtin_amdgcn_mfma_f32_16x16x32_bf16(aml[ti], bv[tj], acc2[ti][tj], 0, 0, 0);
        }
    }
#pragma unroll
    for (int ti = 0; ti < 4; ++ti)
#pragma unroll
      for (int tj = 0; tj < 4; ++tj)
#pragma unroll
        for (int r = 0; r < 4; ++r) {
          const int i = wm * 64 + ti * 16 + qu * 4 + r;
          const int col = half * 128 + wn * 64 + tj * 16 + ln;
          Oh[(size_t)(t0 + i) * 2048 + h * 256 + col] = f2h(acc2[ti][tj][r]);
        }
  }
}

// ---------------------------------------------------------------------------
// gla_w: per (b,h,chunk) parallel (512 blocks): W = KE^T @ V (2-combo on KE),
// fp32 acc, written fp16 IN PLACE over V's chunk slot. Block reads exactly
// the 64KB it overwrites; epilogue writes strictly after all V reads.
__global__ __launch_bounds__(256) void gla_w(const u16* __restrict__ QKu,
                                             u16* __restrict__ V) {
  __shared__ u16 KTh[128 * 40];   // 10KB  KE^T hi [d][t], pad 40
  __shared__ u16 KTl[128 * 40];   // 10KB
  __shared__ u16 VT[256 * 40];    // 20KB  V^T [dv][t], pad 40
  const int tid = threadIdx.x;
  const int bi = blockIdx.x;
  const int c = bi & 15, h = (bi >> 4) & 7, b = bi >> 7;
  const int t0 = b * 2048 + c * 128;
  const int wave = tid >> 6, lane = tid & 63;
  const int wm = wave >> 1, wn = wave & 1;
  const int qu = lane >> 4, ln = lane & 15;
  const int t = tid & 31, dg0 = tid >> 5;
  f32x4 acc[4][8] = {};
  for (int kt = 0; kt < 128; kt += 32) {
    // stage KE^T (hi/lo from interleaved) [d][t]
#pragma unroll
    for (int rr = 0; rr < 2; ++rr) {
      const int dg = dg0 + rr * 8;
      const size_t gb = (size_t)(t0 + kt + t) * 4096 + 2048 + h * 256 + dg * 16;
      uint4 w0 = *(const uint4*)(QKu + gb);
      uint4 w1 = *(const uint4*)(QKu + gb + 8);
      u16* dh = KTh + (dg * 8) * 40 + t;
      u16* dL = KTl + (dg * 8) * 40 + t;
      dh[0]      = (u16)w0.x; dL[0]      = (u16)(w0.x >> 16);
      dh[40]     = (u16)w0.y; dL[40]     = (u16)(w0.y >> 16);
      dh[2 * 40] = (u16)w0.z; dL[2 * 40] = (u16)(w0.z >> 16);
      dh[3 * 40] = (u16)w0.w; dL[3 * 40] = (u16)(w0.w >> 16);
      dh[4 * 40] = (u16)w1.x; dL[4 * 40] = (u16)(w1.x >> 16);
      dh[5 * 40] = (u16)w1.y; dL[5 * 40] = (u16)(w1.y >> 16);
      dh[6 * 40] = (u16)w1.z; dL[6 * 40] = (u16)(w1.z >> 16);
      dh[7 * 40] = (u16)w1.w; dL[7 * 40] = (u16)(w1.w >> 16);
    }
    // stage V^T [dv][t]
#pragma unroll
    for (int rr = 0; rr < 4; ++rr) {
      const int dvg = dg0 + rr * 8;
      uint4 pv = *(const uint4*)(V + (size_t)(t0 + kt + t) * 2048 + h * 256 + dvg * 8);
      u16* dst = VT + (dvg * 8) * 40 + t;
      dst[0]      = (u16)pv.x; dst[40]     = (u16)(pv.x >> 16);
      dst[2 * 40] = (u16)pv.y; dst[3 * 40] = (u16)(pv.y >> 16);
      dst[4 * 40] = (u16)pv.z; dst[5 * 40] = (u16)(pv.z >> 16);
      dst[6 * 40] = (u16)pv.w; dst[7 * 40] = (u16)(pv.w >> 16);
    }
    __syncthreads();
    bf16x8 kh[4], kl[4], bv[8];
#pragma unroll
    for (int ti = 0; ti < 4; ++ti) {
      const int d = wm * 64 + ti * 16 + ln;
      kh[ti] = ldf(&KTh[d * 40 + qu * 8]);
      kl[ti] = ldf(&KTl[d * 40 + qu * 8]);
    }
#pragma unroll
    for (int tj = 0; tj < 8; ++tj)
      bv[tj] = ldf(&VT[(wn * 128 + tj * 16 + ln) * 40 + qu * 8]);
#pragma unroll
    for (int ti = 0; ti < 4; ++ti)
#pragma unroll
      for (int tj = 0; tj < 8; ++tj) {
        acc[ti][tj] = __builtin_amdgcn_mfma_f32_16x16x32_bf16(kh[ti], bv[tj], acc[ti][tj], 0, 0, 0);
        acc[ti][tj] = __builtin_amdgcn_mfma_f32_16x16x32_bf16(kl[ti], bv[tj], acc[ti][tj], 0, 0, 0);
      }
    __syncthreads();
  }
  // epilogue: W[d][dv] fp16 over V slot (all V reads completed above)
#pragma unroll
  for (int ti = 0; ti < 4; ++ti)
#pragma unroll
    for (int tj = 0; tj < 8; ++tj)
#pragma unroll
      for (int r = 0; r < 4; ++r) {
        const int d = wm * 64 + ti * 16 + qu * 4 + r;
        const int dv = wn * 128 + tj * 16 + ln;
        V[(size_t)(t0 + d) * 2048 + h * 256 + dv] = f2h(acc[ti][tj][r]);
      }
}

// ---------------------------------------------------------------------------
// gla_scan: serial 16-chunk scan, 256 blocks = (dv-slice 0..7)x(b,h).
// Per chunk only 3 barriers: W-prefetch(regs) | split S + stage FULL QD
// window | barrier | o_inter (4 dk-steps, no inner barriers) | Oh RMW |
// S = dl (.) (S + W) | barrier.
__global__ __launch_bounds__(256) void gla_scan(const u16* __restrict__ QKu,
                                                const u16* __restrict__ W,
                                                const float* __restrict__ dl,
                                                u16* __restrict__ Oh) {
  __shared__ float STf[32 * 128];     // 16KB  S fp32 master [dv][d]
  __shared__ u16 STh[32 * 136];       // 8.5KB hi plane (pad 136)
  __shared__ u16 STl[32 * 136];
  __shared__ u16 Qi2[128 * 256];      // 64KB  full QD chunk, interleaved+swz
  __shared__ float dls[128];
  const int tid = threadIdx.x;
  const int bi = blockIdx.x;
  const int sl = bi >> 5, g = bi & 31, b = g >> 3, h = g & 7;
  const int wave = tid >> 6, lane = tid & 63;
  const int qu = lane >> 4, ln = lane & 15;
  const int bh16 = (b * 8 + h) * 16;
  for (int e = tid; e < 4096; e += 256) STf[e] = 0.f;
  for (int c = 0; c < 16; ++c) {
    const int t0 = b * 2048 + c * 128;
    if (tid < 128) dls[tid] = dl[(size_t)(bh16 + c) * 128 + tid];
    // W prefetch into regs (fp16, 4 x 8B per thread)
    uint2 wreg[2][2];
#pragma unroll
    for (int tj = 0; tj < 2; ++tj)
#pragma unroll
      for (int ti = 0; ti < 2; ++ti) {
        const int d = wave * 32 + tj * 16 + ln;
        const int dv = sl * 32 + ti * 16 + qu * 4;
        wreg[tj][ti] = *(const uint2*)(W + (size_t)(t0 + d) * 2048 + h * 256 + dv);
      }
    __syncthreads();   // B1: dls + STf(prev update / zero-init) visible
    if (c > 0) {
      // split S -> hi/lo planes (reads STf)
      for (int e = tid; e < 4096; e += 256) {
        const int row = e >> 7, col = e & 127;
        float v = STf[e];
        u16 hi = f2bf(v);
        STh[row * 136 + col] = hi;
        STl[row * 136 + col] = f2bf(v - bf2f(hi));
      }
      // stage FULL QD chunk: 128 rows x 256 u16, swizzled source (chk^row&7)
#pragma unroll
      for (int r = 0; r < 16; ++r) {
        const int idx = r * 256 + tid;
        const int row = idx >> 5, chk = idx & 31;
        load_lds16(QKu + (size_t)(t0 + row) * 4096 + h * 256 + ((chk ^ (row & 7)) << 3),
                   Qi2 + (size_t)idx * 8);
      }
      __syncthreads();
      // o_inter = QD_c @ S_prev (3-combo), no inner barriers
      f32x4 aco[2][2] = {};
#pragma unroll
      for (int kt = 0; kt < 4; ++kt) {
        bf16x8 qh[2], ql[2], sh[2], slo[2];
#pragma unroll
        for (int t = 0; t < 2; ++t) {
          const int ar = wave * 32 + t * 16 + ln;
          const u16* pQ = &Qi2[ar * 256];
          uint4 w0 = *(const uint4*)&pQ[((kt * 8 + 2 * qu) ^ (ar & 7)) << 3];
          uint4 w1 = *(const uint4*)&pQ[((kt * 8 + 2 * qu + 1) ^ (ar & 7)) << 3];
          unpk(w0, w1, qh[t], ql[t]);
          const int br = t * 16 + ln;
          sh[t]  = ldf(&STh[br * 136 + kt * 32 + qu * 8]);
          slo[t] = ldf(&STl[br * 136 + kt * 32 + qu * 8]);
        }
#pragma unroll
        for (int ti = 0; ti < 2; ++ti)
#pragma unroll
          for (int tj = 0; tj < 2; ++tj) {
            aco[ti][tj] = __builtin_amdgcn_mfma_f32_16x16x32_bf16(qh[ti], sh[tj], aco[ti][tj], 0, 0, 0);
            aco[ti][tj] = __builtin_amdgcn_mfma_f32_16x16x32_bf16(qh[ti], slo[tj], aco[ti][tj], 0, 0, 0);
            aco[ti][tj] = __builtin_amdgcn_mfma_f32_16x16x32_bf16(ql[ti], sh[tj], aco[ti][tj], 0, 0, 0);
          }
      }
      // RMW Oh += o_inter (each cell owned by exactly one lane)
#pragma unroll
      for (int ti = 0; ti < 2; ++ti)
#pragma unroll
        for (int tj = 0; tj < 2; ++tj)
#pragma unroll
          for (int r = 0; r < 4; ++r) {
            const int i = wave * 32 + ti * 16 + qu * 4 + r;
            const int dv = tj * 16 + ln;
            u16* p = Oh + (size_t)(t0 + i) * 2048 + h * 256 + sl * 32 + dv;
            *p = f2h(h2f(*p) + aco[ti][tj][r]);
          }
    }
    // S = dls (.) (S + W)
#pragma unroll
    for (int tj = 0; tj < 2; ++tj)
#pragma unroll
      for (int ti = 0; ti < 2; ++ti) {
        const int d = wave * 32 + tj * 16 + ln;
#pragma unroll
        for (int r = 0; r < 4; ++r) {
          const int dv = ti * 16 + qu * 4 + r;
          const u32 wu = (r & 2) ? wreg[tj][ti].y : wreg[tj][ti].x;
          const float wv = h2f((u16)((r & 1) ? (wu >> 16) : (wu & 0xffffu)));
          const int e = dv * 128 + d;
          STf[e] = dls[d] * (STf[e] + wv);
        }
      }
    __syncthreads();   // B4: S update + dls reads done before next chunk
  }
}

// ---------------------------------------------------------------------------
// LayerNorm(256) + silu(g) gate; sums via segmented in-wave shuffles
// (head = 32-lane group). Reads o fp16 (Oh), writes OG fp16 to ws.
__global__ __launch_bounds__(256) void ln_gate(const u16* __restrict__ O,
                                               const u16* __restrict__ G,
                                               const float* __restrict__ bg,
                                               u16* __restrict__ OG) {
  const int tglob = blockIdx.x;        // token row 0..8191
  const int tid = threadIdx.x;
  const int c0 = tid << 3;             // 8 elements per thread
  const size_t base = (size_t)tglob * 2048 + c0;
  ushort4 oa = *(const ushort4*)&O[base];
  ushort4 ob = *(const ushort4*)&O[base + 4];
  float f0 = h2f(oa.x), f1 = h2f(oa.y), f2 = h2f(oa.z), f3 = h2f(oa.w);
  float f4 = h2f(ob.x), f5 = h2f(ob.y), f6 = h2f(ob.z), f7 = h2f(ob.w);
  float s = f0 + f1 + f2 + f3 + f4 + f5 + f6 + f7;
  float ss = f0 * f0 + f1 * f1 + f2 * f2 + f3 * f3 + f4 * f4 + f5 * f5 + f6 * f6 + f7 * f7;
#pragma unroll
  for (int off = 1; off <= 16; off <<= 1) {
    s += __shfl_xor(s, off, 64);
    ss += __shfl_xor(ss, off, 64);
  }
  const float mean = s * (1.f / 256.f);
  const float rstd = rsqrtf(ss * (1.f / 256.f) - mean * mean + 1e-5f);
  ushort4 ga = *(const ushort4*)&G[base];
  ushort4 gb4 = *(const ushort4*)&G[base + 4];
  float4 bga = *(const float4*)&bg[c0];
  float4 bgb = *(const float4*)&bg[c0 + 4];
  auto one = [&](float ov, u16 gu, float bgv) -> u16 {
    float gg = bf2f(gu) + bgv;
    return f2h((ov - mean) * rstd * (gg / (1.f + expf(-gg))));
  };
  ushort4 ra, rb;
  ra.x = one(f0, ga.x, bga.x);  ra.y = one(f1, ga.y, bga.y);
  ra.z = one(f2, ga.z, bga.z);  ra.w = one(f3, ga.w, bga.w);
  rb.x = one(f4, gb4.x, bgb.x); rb.y = one(f5, gb4.y, bgb.y);
  rb.z = one(f6, gb4.z, bgb.z); rb.w = one(f7, gb4.w, bgb.w);
  *(ushort4*)&OG[base] = ra;
  *(ushort4*)&OG[base + 4] = rb;
}

// ---------------------------------------------------------------------------
extern "C" void kernel_launch(void* const* d_in, const int* in_sizes, int n_in,
                              void* d_out, int out_size, void* d_ws, size_t ws_size,
                              hipStream_t stream) {
  (void)in_sizes; (void)n_in; (void)out_size;
  if (ws_size < 117964800ull) return;   // fail soft

  const float* x    = (const float*)d_in[0];
  const float* Wq   = (const float*)d_in[1];
  const float* Wk   = (const float*)d_in[2];
  const float* Wkg1 = (const float*)d_in[3];
  const float* Wkg2 = (const float*)d_in[4];
  const float* bkg2 = (const float*)d_in[5];
  const float* Wv   = (const float*)d_in[6];
  const float* Wg   = (const float*)d_in[7];
  const float* bg   = (const float*)d_in[8];
  const float* Wo   = (const float*)d_in[9];

  char* ws = (char*)d_ws;
  float* QK  = (float*)(ws + 0);           // 64 MiB fp32 -> interleaved decorated
  u16*   QKu = (u16*)QK;
  u16*   V   = (u16*)(ws + 67108864);      // 32 MiB bf16 v -> W fp16 (gla_w)
  u16*   Wt  = (u16*)(ws + 100663296);     //  8 MiB weight^T fp16 (serially reused)
  float* xg1 = (float*)(ws + 117440512);   // 0.5 MiB
  float* dl  = (float*)(ws + 109051904);   // 256 KiB
  u16*   OG  = (u16*)(ws + 0);             // 32 MiB OG fp16 (QK dead after scan)

  // d_out scratch: xf fp16 [0,32Mi) -> Oh fp16 (after g-gemm); G bf16 [32Mi,64Mi)
  u16* xf = (u16*)d_out;
  u16* Oh = (u16*)d_out;                   // after g-gemm (xf dead)
  u16* G  = (u16*)d_out + 16777216;

  dim3 tb(32, 8);

  xg1_gemm<<<dim3(128), dim3(256), 0, stream>>>(x, Wkg1, xg1, xf);

  // [q|k] projection, fp32 out (Wk folded with (D/H)^-0.5 = 1/16, exact pow2)
  tpose_f16<<<dim3(32, 64), tb, 0, stream>>>(Wq, Wt,               2048, 1024, 1.0f);
  tpose_f16<<<dim3(32, 64), tb, 0, stream>>>(Wk, Wt + 1024 * 2048, 2048, 1024, 0.0625f);
  gemm_f16<1><<<dim3(16, 64), dim3(256), 0, stream>>>(xf, Wt, (void*)QK, 8192, 2048, 2048);

  // v projection, bf16 out
  tpose_f16<<<dim3(64, 64), tb, 0, stream>>>(Wv, Wt, 2048, 2048, 1.0f);
  gemm_f16<0><<<dim3(16, 64), dim3(256), 0, stream>>>(xf, Wt, (void*)V, 8192, 2048, 2048);

  // g projection, bf16 out -> G
  tpose_f16<<<dim3(64, 64), tb, 0, stream>>>(Wg, Wt, 2048, 2048, 1.0f);
  gemm_f16<0><<<dim3(16, 64), dim3(256), 0, stream>>>(xf, Wt, (void*)G, 8192, 2048, 2048);

  // chunked GLA on MFMA (xf dead from here; Oh takes its region)
  gla_decor<<<dim3(512), dim3(256), 0, stream>>>(QK, xg1, Wkg2, bkg2, dl);
  gla_intra<<<dim3(512), dim3(256), 0, stream>>>(QKu, V, Oh);
  gla_w<<<dim3(512), dim3(256), 0, stream>>>(QKu, V);          // V -> W in place
  gla_scan<<<dim3(256), dim3(256), 0, stream>>>(QKu, V, dl, Oh);
  ln_gate<<<dim3(8192), dim3(256), 0, stream>>>(Oh, G, bg, OG);

  // final projection: OG fp16 @ Wo^T fp16 -> fp32 straight into d_out
  tpose_f16<<<dim3(64, 64), tb, 0, stream>>>(Wo, Wt, 2048, 2048, 1.0f);
  gemm_f16<1><<<dim3(16, 64), dim3(256), 0, stream>>>(OG, Wt, d_out, 8192, 2048, 2048);
}

// Round 7
// 808.072 us; speedup vs baseline: 4.7508x; 1.1650x over previous
//
#include <hip/hip_runtime.h>
#include <stdint.h>

// ---------------------------------------------------------------------------
// GatedLinearAttention (b=4, T=2048, D=2048, H=8, dk=128, dv=256, CHUNK=128)
// Round: widen gemm_f16 wave tile 64x64 -> 64x128 (block 128x256, acc[4][8]):
// frag-reads/MFMA 0.5 -> 0.375 and 2x MFMA per barrier (the R6 profile showed
// MfmaUtil 24% / VALUBusy 45% -> LDS-read/issue-bound, not MFMA-bound).
// Plus exact triangle predication in gla_intra (skip all-zero MFMA frags) and
// 2x blocks for xg1_gemm. All changes bit-identical (absmax unchanged).
//
// ws layout (112.5 MiB guard unchanged):
//   QK [0,64Mi)      fp32 [q | k/16] -> interleaved decorated u32 (in-place)
//                    -> OG fp16 [0,32Mi) after ln_gate
//   V  [64Mi,96Mi)   bf16 v -> W fp16 (gla_w, in-place per chunk slot)
//   Wt [96Mi,104Mi)  weight^T fp16 single plane (serially reused)
//   dl  at [104Mi)   256KB fp32
//   xg1 [112Mi,+512K)
// d_out timeline: xf fp16 [0,32Mi) -> Oh fp16 (intra..ln_gate); G bf16
//   [32Mi,64Mi) (g-gemm..ln_gate); final C fp32 [0,64Mi) written by last GEMM.
// ---------------------------------------------------------------------------

typedef unsigned short u16;
typedef unsigned int u32;
typedef __bf16 bf16x8 __attribute__((ext_vector_type(8)));
typedef _Float16 f16x8 __attribute__((ext_vector_type(8)));
typedef float f32x4 __attribute__((ext_vector_type(4)));

__device__ __forceinline__ u16 f2bf(float f) {
  u32 u = __float_as_uint(f);
  u32 r = (u + 0x7fffu + ((u >> 16) & 1u)) >> 16;   // RNE
  return (u16)r;
}
__device__ __forceinline__ float bf2f(u16 s) {
  return __uint_as_float(((u32)s) << 16);
}
__device__ __forceinline__ u16 f2h(float f) {
  _Float16 h = (_Float16)f;                          // RNE fp32->fp16
  return __builtin_bit_cast(u16, h);
}
__device__ __forceinline__ float h2f(u16 u) {
  return (float)__builtin_bit_cast(_Float16, u);
}

// async global->LDS, 16B/lane. LDS dest = wave-uniform base + lane*16.
__device__ __forceinline__ void load_lds16(const void* g, void* l) {
  auto gp = (const __attribute__((address_space(1))) u32*)(uintptr_t)g;
  auto lp = (__attribute__((address_space(3))) u32*)(u32)(uintptr_t)l;
  __builtin_amdgcn_global_load_lds(gp, lp, 16, 0, 0);
}
__device__ __forceinline__ bf16x8 ldf(const u16* p) { return *(const bf16x8*)p; }
__device__ __forceinline__ f16x8 ldh(const u16* p) { return *(const f16x8*)p; }

// unpack 8 interleaved (hi,lo) u16 pairs (two uint4) -> hi/lo bf16x8 vectors
__device__ __forceinline__ void unpk(uint4 w0, uint4 w1, bf16x8& hi, bf16x8& lo) {
  union U { uint4 u; bf16x8 v; } a, b;
  a.u.x = __builtin_amdgcn_perm(w0.y, w0.x, 0x05040100u);
  a.u.y = __builtin_amdgcn_perm(w0.w, w0.z, 0x05040100u);
  a.u.z = __builtin_amdgcn_perm(w1.y, w1.x, 0x05040100u);
  a.u.w = __builtin_amdgcn_perm(w1.w, w1.z, 0x05040100u);
  b.u.x = __builtin_amdgcn_perm(w0.y, w0.x, 0x07060302u);
  b.u.y = __builtin_amdgcn_perm(w0.w, w0.z, 0x07060302u);
  b.u.z = __builtin_amdgcn_perm(w1.y, w1.x, 0x07060302u);
  b.u.w = __builtin_amdgcn_perm(w1.w, w1.z, 0x07060302u);
  hi = a.v;
  lo = b.v;
}

// ---------------------------------------------------------------------------
// weight transpose -> fp16 single plane: dst[n][k] = f2h(src[k][n] * scale)
__global__ __launch_bounds__(256) void tpose_f16(const float* __restrict__ src,
                                                 u16* __restrict__ dst,
                                                 int srcRows, int srcStride,
                                                 float scale) {
  __shared__ float tile[32][33];
  const int tx = threadIdx.x, ty = threadIdx.y;     // block (32,8)
  const int n0 = blockIdx.x * 32, k0 = blockIdx.y * 32;
#pragma unroll
  for (int j = 0; j < 4; ++j) {
    int k = k0 + ty + j * 8;
    tile[ty + j * 8][tx] = src[(size_t)k * srcStride + n0 + tx] * scale;
  }
  __syncthreads();
#pragma unroll
  for (int j = 0; j < 4; ++j) {
    int n = n0 + ty + j * 8;
    float f = tile[tx][ty + j * 8];
    dst[(size_t)n * srcRows + k0 + tx] = f2h(f);
  }
}

// ---------------------------------------------------------------------------
// fp16 GEMM: C[M,N] = A_f16[M,K] @ Bt_f16[N,K]^T. Block tile 128x256, BK=32,
// 4 waves, wave tile 64x128 (acc[4][8]): 12 frag reads / 32 MFMA per k-step.
// All staging via global_load_lds with chunk-XOR swizzle (conflict-free).
template <int OUTF32>
__global__ __launch_bounds__(256, 2) void gemm_f16(const u16* __restrict__ A,
                                                   const u16* __restrict__ Bt,
                                                   void* __restrict__ C,
                                                   int M, int N, int K) {
  __shared__ u16 As[128 * 32];   //  8 KB
  __shared__ u16 Bs[256 * 32];   // 16 KB
  const int tid = threadIdx.x;
  const int wave = tid >> 6, lane = tid & 63;
  const int wm = wave >> 1, wn = wave & 1;
  const int qu = lane >> 4, ln = lane & 15;
  const int m0 = blockIdx.y * 128, n0 = blockIdx.x * 256;
  f32x4 acc[4][8] = {};
  for (int kt = 0; kt < K; kt += 32) {
    // A: 512 load16 (2/thread)
#pragma unroll
    for (int r = 0; r < 2; ++r) {
      const int idx = r * 256 + tid;
      const int row = idx >> 2, chk = idx & 3;
      const int sc = ((chk ^ ((row >> 1) & 3)) << 3);
      load_lds16(A + (size_t)(m0 + row) * K + kt + sc, As + (size_t)idx * 8);
    }
    // B: 1024 load16 (4/thread)
#pragma unroll
    for (int r = 0; r < 4; ++r) {
      const int idx = r * 256 + tid;
      const int row = idx >> 2, chk = idx & 3;
      const int sc = ((chk ^ ((row >> 1) & 3)) << 3);
      load_lds16(Bt + (size_t)(n0 + row) * K + kt + sc, Bs + (size_t)idx * 8);
    }
    __syncthreads();
    f16x8 af[4], bfr[8];
#pragma unroll
    for (int t = 0; t < 4; ++t) {
      const int ia = wm * 64 + t * 16 + ln;
      af[t] = ldh(&As[ia * 32 + ((qu ^ ((ia >> 1) & 3)) << 3)]);
    }
#pragma unroll
    for (int t = 0; t < 8; ++t) {
      const int ib = wn * 128 + t * 16 + ln;
      bfr[t] = ldh(&Bs[ib * 32 + ((qu ^ ((ib >> 1) & 3)) << 3)]);
    }
#pragma unroll
    for (int ti = 0; ti < 4; ++ti)
#pragma unroll
      for (int tj = 0; tj < 8; ++tj)
        acc[ti][tj] = __builtin_amdgcn_mfma_f32_16x16x32_f16(af[ti], bfr[tj], acc[ti][tj], 0, 0, 0);
    __syncthreads();
  }
#pragma unroll
  for (int ti = 0; ti < 4; ++ti)
#pragma unroll
    for (int tj = 0; tj < 8; ++tj) {
      const int rowb = m0 + wm * 64 + ti * 16 + qu * 4;   // C/D: row=(lane>>4)*4+reg
      const int col = n0 + wn * 128 + tj * 16 + ln;       //      col=lane&15
#pragma unroll
      for (int r = 0; r < 4; ++r) {
        size_t idx = (size_t)(rowb + r) * N + col;
        if (OUTF32) ((float*)C)[idx] = acc[ti][tj][r];
        else        ((u16*)C)[idx] = f2bf(acc[ti][tj][r]);
      }
    }
}

// ---------------------------------------------------------------------------
// xg1[8192,16] = x[8192,2048] @ Wkg1[2048,16] (fp32, tiled), fused with
// x -> fp16 conversion (xf). 256 blocks x 32 rows.
__global__ __launch_bounds__(256) void xg1_gemm(const float* __restrict__ x,
                                                const float* __restrict__ W1,
                                                float* __restrict__ xg1,
                                                u16* __restrict__ xf) {
  __shared__ float xs[32][40];
  __shared__ float ws2[32][16];
  const int tid = threadIdx.x;
  const int r0 = blockIdx.x * 32;
  const int col = tid & 15, rsub = tid >> 4;
  float acc[2] = {0.f, 0.f};
  for (int kt = 0; kt < 2048; kt += 32) {
    {
      int row = tid >> 3, kk = (tid & 7) << 2;
      float4 f4 = *(const float4*)&x[(size_t)(r0 + row) * 2048 + kt + kk];
      *(float4*)&xs[row][kk] = f4;
      ushort4 hq;
      hq.x = f2h(f4.x); hq.y = f2h(f4.y); hq.z = f2h(f4.z); hq.w = f2h(f4.w);
      *(ushort4*)&xf[(size_t)(r0 + row) * 2048 + kt + kk] = hq;
    }
#pragma unroll
    for (int j = 0; j < 2; ++j) {
      int c = j * 256 + tid;
      ws2[c >> 4][c & 15] = W1[(size_t)(kt + (c >> 4)) * 16 + (c & 15)];
    }
    __syncthreads();
#pragma unroll
    for (int kk = 0; kk < 32; ++kk) {
      float wv = ws2[kk][col];
      acc[0] += xs[rsub][kk] * wv;
      acc[1] += xs[rsub + 16][kk] * wv;
    }
    __syncthreads();
  }
  xg1[(size_t)(r0 + rsub) * 16 + col] = acc[0];
  xg1[(size_t)(r0 + rsub + 16) * 16 + col] = acc[1];
}

// ---------------------------------------------------------------------------
// gla_decor: grid 512 = (b * 16 + n) * 8 + headgroup; 256 threads =
// 128 q-cols + 128 k-cols of that head. Each thread reads its fp32 value and
// overwrites THE SAME 4 bytes with (hi | lo<<16) -> fully race-free in-place.
__global__ __launch_bounds__(256) void gla_decor(float* __restrict__ QK,
                                                 const float* __restrict__ xg1,
                                                 const float* __restrict__ W2,
                                                 const float* __restrict__ b2,
                                                 float* __restrict__ dl) {
  __shared__ float xg1s[128][16];   // 8KB
  const int tid = threadIdx.x;
  const int bi = blockIdx.x;
  const int b = bi >> 7, n = (bi >> 3) & 15, g = bi & 7;
  const int t0 = b * 2048 + n * 128;
  const bool isK = tid >= 128;
  const int ci = tid & 127;
  const int col = g * 128 + ci;            // global col 0..1023
  u32* base = (u32*)QK + (size_t)t0 * 2048 + (isK ? 1024 : 0) + col;
  float w2r[16];
#pragma unroll
  for (int k = 0; k < 16; ++k) w2r[k] = W2[k * 1024 + col];
  const float b2r = b2[col];
  for (int e = tid; e < 2048; e += 256)
    xg1s[e >> 4][e & 15] = xg1[(size_t)(t0 + (e >> 4)) * 16 + (e & 15)];
  __syncthreads();
  float acc = 0.f;
  const float sgn = isK ? -1.f : 1.f;
  for (int s = 0; s < 128; s += 16) {
    float qv[16];
#pragma unroll
    for (int j = 0; j < 16; ++j) qv[j] = __uint_as_float(base[(size_t)(s + j) * 2048]);
    u32 ov[16];
#pragma unroll
    for (int j = 0; j < 16; ++j) {
      float z = b2r;
#pragma unroll
      for (int kk = 0; kk < 16; ++kk) z += xg1s[s + j][kk] * w2r[kk];
      float gk = (fminf(z, 0.f) - log1pf(expf(-fabsf(z)))) * 0.0625f;
      acc += gk;
      float e = expf(sgn * acc);
      float v = qv[j] * e;
      u16 h = f2bf(v);
      u16 l = f2bf(v - bf2f(h));
      ov[j] = (u32)h | ((u32)l << 16);
    }
#pragma unroll
    for (int j = 0; j < 16; ++j) base[(size_t)(s + j) * 2048] = ov[j];
  }
  if (isK) dl[((size_t)(b * 8 + g) * 16 + n) * 128 + ci] = expf(acc);
}

// ---------------------------------------------------------------------------
// gla_intra: per (b,h,chunk): A = tril(QD@KE^T) (3-combo), o_intra = A@V^T
// (2-combo) -> Oh fp16. Triangle-predicated: frag MFMAs whose A-region is
// entirely above the diagonal are skipped (they contribute exact zeros).
__global__ __launch_bounds__(256) void gla_intra(const u16* __restrict__ QKu,
                                                 const u16* __restrict__ V,
                                                 u16* __restrict__ Oh) {
  // pool: stage Qi [0,8192) u16, Ki [8192,16384); Amh [0,16384) Aml [16384,32768);
  //       VTs [32768, 32768+7168) = [128][56] u16 pad
  __shared__ u16 pool[39936];   // 79872 B -> 2 blocks/CU
  const int tid = threadIdx.x;
  const int bi = blockIdx.x;
  const int n = bi & 15, h = (bi >> 4) & 7, b = bi >> 7;
  const int t0 = b * 2048 + n * 128;
  const int wave = tid >> 6, lane = tid & 63;
  const int wm = wave >> 1, wn = wave & 1;
  const int qu = lane >> 4, ln = lane & 15;
  const int srow = tid >> 3, schk = tid & 7;
  const int sc = ((schk ^ (srow & 7)) << 3);   // swizzled source u16 offset
  u16* Qi = pool;
  u16* Ki = pool + 8192;
  u16* Amh = pool;
  u16* Aml = pool + 16384;
  u16* VTs = pool + 32768;
  // ---- phase A: A = QD @ KE^T  (3-combo hi/lo), upper-triangle-skipped
  const bool skipQuad = (wm == 0 && wn == 1);   // rows 0-63 x cols 64-127: all zero
  f32x4 acc[4][4] = {};
  for (int kt = 0; kt < 128; kt += 32) {
#pragma unroll
    for (int r = 0; r < 4; ++r) {
      const int row = srow + r * 32;
      const size_t gb = (size_t)(t0 + row) * 4096 + h * 256 + 2 * kt + sc;
      load_lds16(QKu + gb,        Qi + (r * 32 + wave * 8) * 64);
      load_lds16(QKu + gb + 2048, Ki + (r * 32 + wave * 8) * 64);
    }
    __syncthreads();
    if (!skipQuad) {
      bf16x8 ah[4], al[4], bh[4], bl[4];
#pragma unroll
      for (int t = 0; t < 4; ++t) {
        const int i = wm * 64 + t * 16 + ln;
        const u16* pQ = &Qi[i * 64];
        uint4 w0 = *(const uint4*)&pQ[((2 * qu) ^ (i & 7)) << 3];
        uint4 w1 = *(const uint4*)&pQ[((2 * qu + 1) ^ (i & 7)) << 3];
        unpk(w0, w1, ah[t], al[t]);
        const int j = wn * 64 + t * 16 + ln;
        const u16* pK = &Ki[j * 64];
        uint4 y0 = *(const uint4*)&pK[((2 * qu) ^ (j & 7)) << 3];
        uint4 y1 = *(const uint4*)&pK[((2 * qu + 1) ^ (j & 7)) << 3];
        unpk(y0, y1, bh[t], bl[t]);
      }
      const bool diag = (wm == wn);
#pragma unroll
      for (int ti = 0; ti < 4; ++ti)
#pragma unroll
        for (int tj = 0; tj < 4; ++tj) {
          if (diag && tj > ti) continue;   // frag entirely above diagonal
          acc[ti][tj] = __builtin_amdgcn_mfma_f32_16x16x32_bf16(ah[ti], bh[tj], acc[ti][tj], 0, 0, 0);
          acc[ti][tj] = __builtin_amdgcn_mfma_f32_16x16x32_bf16(ah[ti], bl[tj], acc[ti][tj], 0, 0, 0);
          acc[ti][tj] = __builtin_amdgcn_mfma_f32_16x16x32_bf16(al[ti], bh[tj], acc[ti][tj], 0, 0, 0);
        }
    }
    __syncthreads();
  }
  // ---- phase B: causal mask + hi/lo split -> Am (swizzled), aliases stage
#pragma unroll
  for (int ti = 0; ti < 4; ++ti)
#pragma unroll
    for (int tj = 0; tj < 4; ++tj) {
      const int ib = wm * 64 + ti * 16 + qu * 4;
      const int j = wn * 64 + tj * 16 + ln;
#pragma unroll
      for (int r = 0; r < 4; ++r) {
        const int i = ib + r;
        float v = (j <= i) ? acc[ti][tj][r] : 0.f;
        u16 hi = f2bf(v);
        const int idx = i * 128 + (j ^ ((i & 15) << 3));
        Amh[idx] = hi;
        Aml[idx] = f2bf(v - bf2f(hi));
      }
    }
  // ---- phase C: o_intra = Am @ V^T (2-combo), two dv-halves of 128;
  //      (frag,kt) pairs with kt > row_max have all-zero A -> skipped.
  for (int half = 0; half < 2; ++half) {
    f32x4 acc2[4][4] = {};
    for (int kt = 0; kt < 128; kt += 32) {
      __syncthreads();   // Am visible (first iter) / prev VTs reads done
      {  // stage VTs[dv][t] transposed from V, pad 56
        const int j = tid & 31, dvg = tid >> 5;
#pragma unroll
        for (int rr = 0; rr < 2; ++rr) {
          const int dg = dvg + rr * 8;
          uint4 pv = *(const uint4*)(V + (size_t)(t0 + kt + j) * 2048 + h * 256 + half * 128 + dg * 8);
          u16* dst = VTs + (dg * 8) * 56 + j;
          dst[0]      = (u16)pv.x; dst[56]      = (u16)(pv.x >> 16);
          dst[2 * 56] = (u16)pv.y; dst[3 * 56]  = (u16)(pv.y >> 16);
          dst[4 * 56] = (u16)pv.z; dst[5 * 56]  = (u16)(pv.z >> 16);
          dst[6 * 56] = (u16)pv.w; dst[7 * 56]  = (u16)(pv.w >> 16);
        }
      }
      __syncthreads();
      bf16x8 amh[4], aml[4], bv[4];
#pragma unroll
      for (int t = 0; t < 4; ++t) {
        if (kt <= wm * 64 + t * 16 + 15) {
          const int i = wm * 64 + t * 16 + ln;
          const int cof = (kt + qu * 8) ^ ((i & 15) << 3);
          amh[t] = ldf(&Amh[i * 128 + cof]);
          aml[t] = ldf(&Aml[i * 128 + cof]);
        }
        bv[t] = ldf(&VTs[(wn * 64 + t * 16 + ln) * 56 + qu * 8]);
      }
#pragma unroll
      for (int ti = 0; ti < 4; ++ti) {
        if (kt > wm * 64 + ti * 16 + 15) continue;   // A block entirely zero
#pragma unroll
        for (int tj = 0; tj < 4; ++tj) {
          acc2[ti][tj] = __builtin_amdgcn_mfma_f32_16x16x32_bf16(amh[ti], bv[tj], acc2[ti][tj], 0, 0, 0);
          acc2[ti][tj] = __builtin_amdgcn_mfma_f32_16x16x32_bf16(aml[ti], bv[tj], acc2[ti][tj], 0, 0, 0);
        }
      }
    }
#pragma unroll
    for (int ti = 0; ti < 4; ++ti)
#pragma unroll
      for (int tj = 0; tj < 4; ++tj)
#pragma unroll
        for (int r = 0; r < 4; ++r) {
          const int i = wm * 64 + ti * 16 + qu * 4 + r;
          const int col = half * 128 + wn * 64 + tj * 16 + ln;
          Oh[(size_t)(t0 + i) * 2048 + h * 256 + col] = f2h(acc2[ti][tj][r]);
        }
  }
}

// ---------------------------------------------------------------------------
// gla_w: per (b,h,chunk) parallel (512 blocks): W = KE^T @ V (2-combo on KE),
// fp32 acc, written fp16 IN PLACE over V's chunk slot. Block reads exactly
// the 64KB it overwrites; epilogue writes strictly after all V reads.
__global__ __launch_bounds__(256) void gla_w(const u16* __restrict__ QKu,
                                             u16* __restrict__ V) {
  __shared__ u16 KTh[128 * 40];   // 10KB  KE^T hi [d][t], pad 40
  __shared__ u16 KTl[128 * 40];   // 10KB
  __shared__ u16 VT[256 * 40];    // 20KB  V^T [dv][t], pad 40
  const int tid = threadIdx.x;
  const int bi = blockIdx.x;
  const int c = bi & 15, h = (bi >> 4) & 7, b = bi >> 7;
  const int t0 = b * 2048 + c * 128;
  const int wave = tid >> 6, lane = tid & 63;
  const int wm = wave >> 1, wn = wave & 1;
  const int qu = lane >> 4, ln = lane & 15;
  const int t = tid & 31, dg0 = tid >> 5;
  f32x4 acc[4][8] = {};
  for (int kt = 0; kt < 128; kt += 32) {
    // stage KE^T (hi/lo from interleaved) [d][t]
#pragma unroll
    for (int rr = 0; rr < 2; ++rr) {
      const int dg = dg0 + rr * 8;
      const size_t gb = (size_t)(t0 + kt + t) * 4096 + 2048 + h * 256 + dg * 16;
      uint4 w0 = *(const uint4*)(QKu + gb);
      uint4 w1 = *(const uint4*)(QKu + gb + 8);
      u16* dh = KTh + (dg * 8) * 40 + t;
      u16* dL = KTl + (dg * 8) * 40 + t;
      dh[0]      = (u16)w0.x; dL[0]      = (u16)(w0.x >> 16);
      dh[40]     = (u16)w0.y; dL[40]     = (u16)(w0.y >> 16);
      dh[2 * 40] = (u16)w0.z; dL[2 * 40] = (u16)(w0.z >> 16);
      dh[3 * 40] = (u16)w0.w; dL[3 * 40] = (u16)(w0.w >> 16);
      dh[4 * 40] = (u16)w1.x; dL[4 * 40] = (u16)(w1.x >> 16);
      dh[5 * 40] = (u16)w1.y; dL[5 * 40] = (u16)(w1.y >> 16);
      dh[6 * 40] = (u16)w1.z; dL[6 * 40] = (u16)(w1.z >> 16);
      dh[7 * 40] = (u16)w1.w; dL[7 * 40] = (u16)(w1.w >> 16);
    }
    // stage V^T [dv][t]
#pragma unroll
    for (int rr = 0; rr < 4; ++rr) {
      const int dvg = dg0 + rr * 8;
      uint4 pv = *(const uint4*)(V + (size_t)(t0 + kt + t) * 2048 + h * 256 + dvg * 8);
      u16* dst = VT + (dvg * 8) * 40 + t;
      dst[0]      = (u16)pv.x; dst[40]     = (u16)(pv.x >> 16);
      dst[2 * 40] = (u16)pv.y; dst[3 * 40] = (u16)(pv.y >> 16);
      dst[4 * 40] = (u16)pv.z; dst[5 * 40] = (u16)(pv.z >> 16);
      dst[6 * 40] = (u16)pv.w; dst[7 * 40] = (u16)(pv.w >> 16);
    }
    __syncthreads();
    bf16x8 kh[4], kl[4], bv[8];
#pragma unroll
    for (int ti = 0; ti < 4; ++ti) {
      const int d = wm * 64 + ti * 16 + ln;
      kh[ti] = ldf(&KTh[d * 40 + qu * 8]);
      kl[ti] = ldf(&KTl[d * 40 + qu * 8]);
    }
#pragma unroll
    for (int tj = 0; tj < 8; ++tj)
      bv[tj] = ldf(&VT[(wn * 128 + tj * 16 + ln) * 40 + qu * 8]);
#pragma unroll
    for (int ti = 0; ti < 4; ++ti)
#pragma unroll
      for (int tj = 0; tj < 8; ++tj) {
        acc[ti][tj] = __builtin_amdgcn_mfma_f32_16x16x32_bf16(kh[ti], bv[tj], acc[ti][tj], 0, 0, 0);
        acc[ti][tj] = __builtin_amdgcn_mfma_f32_16x16x32_bf16(kl[ti], bv[tj], acc[ti][tj], 0, 0, 0);
      }
    __syncthreads();
  }
  // epilogue: W[d][dv] fp16 over V slot (all V reads completed above)
#pragma unroll
  for (int ti = 0; ti < 4; ++ti)
#pragma unroll
    for (int tj = 0; tj < 8; ++tj)
#pragma unroll
      for (int r = 0; r < 4; ++r) {
        const int d = wm * 64 + ti * 16 + qu * 4 + r;
        const int dv = wn * 128 + tj * 16 + ln;
        V[(size_t)(t0 + d) * 2048 + h * 256 + dv] = f2h(acc[ti][tj][r]);
      }
}

// ---------------------------------------------------------------------------
// gla_scan: serial 16-chunk scan, 256 blocks = (dv-slice 0..7)x(b,h).
// Per chunk only 3 barriers: W-prefetch(regs) | split S + stage FULL QD
// window | barrier | o_inter (4 dk-steps, no inner barriers) | Oh RMW |
// S = dl (.) (S + W) | barrier.
__global__ __launch_bounds__(256) void gla_scan(const u16* __restrict__ QKu,
                                                const u16* __restrict__ W,
                                                const float* __restrict__ dl,
                                                u16* __restrict__ Oh) {
  __shared__ float STf[32 * 128];     // 16KB  S fp32 master [dv][d]
  __shared__ u16 STh[32 * 136];       // 8.5KB hi plane (pad 136)
  __shared__ u16 STl[32 * 136];
  __shared__ u16 Qi2[128 * 256];      // 64KB  full QD chunk, interleaved+swz
  __shared__ float dls[128];
  const int tid = threadIdx.x;
  const int bi = blockIdx.x;
  const int sl = bi >> 5, g = bi & 31, b = g >> 3, h = g & 7;
  const int wave = tid >> 6, lane = tid & 63;
  const int qu = lane >> 4, ln = lane & 15;
  const int bh16 = (b * 8 + h) * 16;
  for (int e = tid; e < 4096; e += 256) STf[e] = 0.f;
  for (int c = 0; c < 16; ++c) {
    const int t0 = b * 2048 + c * 128;
    if (tid < 128) dls[tid] = dl[(size_t)(bh16 + c) * 128 + tid];
    // W prefetch into regs (fp16, 4 x 8B per thread)
    uint2 wreg[2][2];
#pragma unroll
    for (int tj = 0; tj < 2; ++tj)
#pragma unroll
      for (int ti = 0; ti < 2; ++ti) {
        const int d = wave * 32 + tj * 16 + ln;
        const int dv = sl * 32 + ti * 16 + qu * 4;
        wreg[tj][ti] = *(const uint2*)(W + (size_t)(t0 + d) * 2048 + h * 256 + dv);
      }
    __syncthreads();   // B1: dls + STf(prev update / zero-init) visible
    if (c > 0) {
      // split S -> hi/lo planes (reads STf)
      for (int e = tid; e < 4096; e += 256) {
        const int row = e >> 7, col = e & 127;
        float v = STf[e];
        u16 hi = f2bf(v);
        STh[row * 136 + col] = hi;
        STl[row * 136 + col] = f2bf(v - bf2f(hi));
      }
      // stage FULL QD chunk: 128 rows x 256 u16, swizzled source (chk^row&7)
#pragma unroll
      for (int r = 0; r < 16; ++r) {
        const int idx = r * 256 + tid;
        const int row = idx >> 5, chk = idx & 31;
        load_lds16(QKu + (size_t)(t0 + row) * 4096 + h * 256 + ((chk ^ (row & 7)) << 3),
                   Qi2 + (size_t)idx * 8);
      }
      __syncthreads();
      // o_inter = QD_c @ S_prev (3-combo), no inner barriers
      f32x4 aco[2][2] = {};
#pragma unroll
      for (int kt = 0; kt < 4; ++kt) {
        bf16x8 qh[2], ql[2], sh[2], slo[2];
#pragma unroll
        for (int t = 0; t < 2; ++t) {
          const int ar = wave * 32 + t * 16 + ln;
          const u16* pQ = &Qi2[ar * 256];
          uint4 w0 = *(const uint4*)&pQ[((kt * 8 + 2 * qu) ^ (ar & 7)) << 3];
          uint4 w1 = *(const uint4*)&pQ[((kt * 8 + 2 * qu + 1) ^ (ar & 7)) << 3];
          unpk(w0, w1, qh[t], ql[t]);
          const int br = t * 16 + ln;
          sh[t]  = ldf(&STh[br * 136 + kt * 32 + qu * 8]);
          slo[t] = ldf(&STl[br * 136 + kt * 32 + qu * 8]);
        }
#pragma unroll
        for (int ti = 0; ti < 2; ++ti)
#pragma unroll
          for (int tj = 0; tj < 2; ++tj) {
            aco[ti][tj] = __builtin_amdgcn_mfma_f32_16x16x32_bf16(qh[ti], sh[tj], aco[ti][tj], 0, 0, 0);
            aco[ti][tj] = __builtin_amdgcn_mfma_f32_16x16x32_bf16(qh[ti], slo[tj], aco[ti][tj], 0, 0, 0);
            aco[ti][tj] = __builtin_amdgcn_mfma_f32_16x16x32_bf16(ql[ti], sh[tj], aco[ti][tj], 0, 0, 0);
          }
      }
      // RMW Oh += o_inter (each cell owned by exactly one lane)
#pragma unroll
      for (int ti = 0; ti < 2; ++ti)
#pragma unroll
        for (int tj = 0; tj < 2; ++tj)
#pragma unroll
          for (int r = 0; r < 4; ++r) {
            const int i = wave * 32 + ti * 16 + qu * 4 + r;
            const int dv = tj * 16 + ln;
            u16* p = Oh + (size_t)(t0 + i) * 2048 + h * 256 + sl * 32 + dv;
            *p = f2h(h2f(*p) + aco[ti][tj][r]);
          }
    }
    // S = dls (.) (S + W)
#pragma unroll
    for (int tj = 0; tj < 2; ++tj)
#pragma unroll
      for (int ti = 0; ti < 2; ++ti) {
        const int d = wave * 32 + tj * 16 + ln;
#pragma unroll
        for (int r = 0; r < 4; ++r) {
          const int dv = ti * 16 + qu * 4 + r;
          const u32 wu = (r & 2) ? wreg[tj][ti].y : wreg[tj][ti].x;
          const float wv = h2f((u16)((r & 1) ? (wu >> 16) : (wu & 0xffffu)));
          const int e = dv * 128 + d;
          STf[e] = dls[d] * (STf[e] + wv);
        }
      }
    __syncthreads();   // B4: S update + dls reads done before next chunk
  }
}

// ---------------------------------------------------------------------------
// LayerNorm(256) + silu(g) gate; sums via segmented in-wave shuffles
// (head = 32-lane group). Reads o fp16 (Oh), writes OG fp16 to ws.
__global__ __launch_bounds__(256) void ln_gate(const u16* __restrict__ O,
                                               const u16* __restrict__ G,
                                               const float* __restrict__ bg,
                                               u16* __restrict__ OG) {
  const int tglob = blockIdx.x;        // token row 0..8191
  const int tid = threadIdx.x;
  const int c0 = tid << 3;             // 8 elements per thread
  const size_t base = (size_t)tglob * 2048 + c0;
  ushort4 oa = *(const ushort4*)&O[base];
  ushort4 ob = *(const ushort4*)&O[base + 4];
  float f0 = h2f(oa.x), f1 = h2f(oa.y), f2 = h2f(oa.z), f3 = h2f(oa.w);
  float f4 = h2f(ob.x), f5 = h2f(ob.y), f6 = h2f(ob.z), f7 = h2f(ob.w);
  float s = f0 + f1 + f2 + f3 + f4 + f5 + f6 + f7;
  float ss = f0 * f0 + f1 * f1 + f2 * f2 + f3 * f3 + f4 * f4 + f5 * f5 + f6 * f6 + f7 * f7;
#pragma unroll
  for (int off = 1; off <= 16; off <<= 1) {
    s += __shfl_xor(s, off, 64);
    ss += __shfl_xor(ss, off, 64);
  }
  const float mean = s * (1.f / 256.f);
  const float rstd = rsqrtf(ss * (1.f / 256.f) - mean * mean + 1e-5f);
  ushort4 ga = *(const ushort4*)&G[base];
  ushort4 gb4 = *(const ushort4*)&G[base + 4];
  float4 bga = *(const float4*)&bg[c0];
  float4 bgb = *(const float4*)&bg[c0 + 4];
  auto one = [&](float ov, u16 gu, float bgv) -> u16 {
    float gg = bf2f(gu) + bgv;
    return f2h((ov - mean) * rstd * (gg / (1.f + expf(-gg))));
  };
  ushort4 ra, rb;
  ra.x = one(f0, ga.x, bga.x);  ra.y = one(f1, ga.y, bga.y);
  ra.z = one(f2, ga.z, bga.z);  ra.w = one(f3, ga.w, bga.w);
  rb.x = one(f4, gb4.x, bgb.x); rb.y = one(f5, gb4.y, bgb.y);
  rb.z = one(f6, gb4.z, bgb.z); rb.w = one(f7, gb4.w, bgb.w);
  *(ushort4*)&OG[base] = ra;
  *(ushort4*)&OG[base + 4] = rb;
}

// ---------------------------------------------------------------------------
extern "C" void kernel_launch(void* const* d_in, const int* in_sizes, int n_in,
                              void* d_out, int out_size, void* d_ws, size_t ws_size,
                              hipStream_t stream) {
  (void)in_sizes; (void)n_in; (void)out_size;
  if (ws_size < 117964800ull) return;   // fail soft

  const float* x    = (const float*)d_in[0];
  const float* Wq   = (const float*)d_in[1];
  const float* Wk   = (const float*)d_in[2];
  const float* Wkg1 = (const float*)d_in[3];
  const float* Wkg2 = (const float*)d_in[4];
  const float* bkg2 = (const float*)d_in[5];
  const float* Wv   = (const float*)d_in[6];
  const float* Wg   = (const float*)d_in[7];
  const float* bg   = (const float*)d_in[8];
  const float* Wo   = (const float*)d_in[9];

  char* ws = (char*)d_ws;
  float* QK  = (float*)(ws + 0);           // 64 MiB fp32 -> interleaved decorated
  u16*   QKu = (u16*)QK;
  u16*   V   = (u16*)(ws + 67108864);      // 32 MiB bf16 v -> W fp16 (gla_w)
  u16*   Wt  = (u16*)(ws + 100663296);     //  8 MiB weight^T fp16 (serially reused)
  float* xg1 = (float*)(ws + 117440512);   // 0.5 MiB
  float* dl  = (float*)(ws + 109051904);   // 256 KiB
  u16*   OG  = (u16*)(ws + 0);             // 32 MiB OG fp16 (QK dead after scan)

  // d_out scratch: xf fp16 [0,32Mi) -> Oh fp16 (after g-gemm); G bf16 [32Mi,64Mi)
  u16* xf = (u16*)d_out;
  u16* Oh = (u16*)d_out;                   // after g-gemm (xf dead)
  u16* G  = (u16*)d_out + 16777216;

  dim3 tb(32, 8);

  xg1_gemm<<<dim3(256), dim3(256), 0, stream>>>(x, Wkg1, xg1, xf);

  // [q|k] projection, fp32 out (Wk folded with (D/H)^-0.5 = 1/16, exact pow2)
  tpose_f16<<<dim3(32, 64), tb, 0, stream>>>(Wq, Wt,               2048, 1024, 1.0f);
  tpose_f16<<<dim3(32, 64), tb, 0, stream>>>(Wk, Wt + 1024 * 2048, 2048, 1024, 0.0625f);
  gemm_f16<1><<<dim3(8, 64), dim3(256), 0, stream>>>(xf, Wt, (void*)QK, 8192, 2048, 2048);

  // v projection, bf16 out
  tpose_f16<<<dim3(64, 64), tb, 0, stream>>>(Wv, Wt, 2048, 2048, 1.0f);
  gemm_f16<0><<<dim3(8, 64), dim3(256), 0, stream>>>(xf, Wt, (void*)V, 8192, 2048, 2048);

  // g projection, bf16 out -> G
  tpose_f16<<<dim3(64, 64), tb, 0, stream>>>(Wg, Wt, 2048, 2048, 1.0f);
  gemm_f16<0><<<dim3(8, 64), dim3(256), 0, stream>>>(xf, Wt, (void*)G, 8192, 2048, 2048);

  // chunked GLA on MFMA (xf dead from here; Oh takes its region)
  gla_decor<<<dim3(512), dim3(256), 0, stream>>>(QK, xg1, Wkg2, bkg2, dl);
  gla_intra<<<dim3(512), dim3(256), 0, stream>>>(QKu, V, Oh);
  gla_w<<<dim3(512), dim3(256), 0, stream>>>(QKu, V);          // V -> W in place
  gla_scan<<<dim3(256), dim3(256), 0, stream>>>(QKu, V, dl, Oh);
  ln_gate<<<dim3(8192), dim3(256), 0, stream>>>(Oh, G, bg, OG);

  // final projection: OG fp16 @ Wo^T fp16 -> fp32 straight into d_out
  tpose_f16<<<dim3(64, 64), tb, 0, stream>>>(Wo, Wt, 2048, 2048, 1.0f);
  gemm_f16<1><<<dim3(8, 64), dim3(256), 0, stream>>>(OG, Wt, d_out, 8192, 2048, 2048);
}

// Round 8
// 776.878 us; speedup vs baseline: 4.9415x; 1.0402x over previous
//
#include <hip/hip_runtime.h>
#include <stdint.h>

// ---------------------------------------------------------------------------
// GatedLinearAttention (b=4, T=2048, D=2048, H=8, dk=128, dv=256, CHUNK=128)
// Round: fix xg1 starvation (117us @ 8% VALU / 11% occ / 128 barriers).
// Split into: xcvt (streaming x->fp16), xg1p (K-split partials, 1024 blocks,
// no inner barriers, conflict-free LDS), xg1r (reduce 16 partials).
// Partials live in the idle Wt region (free until first tpose_f16).
//
// ws layout (112.5 MiB guard unchanged):
//   QK [0,64Mi)      fp32 [q | k/16] -> interleaved decorated u32 (in-place)
//                    -> OG fp16 [0,32Mi) after ln_gate
//   V  [64Mi,96Mi)   bf16 v -> W fp16 (gla_w, in-place per chunk slot)
//   Wt [96Mi,104Mi)  xg1 partials P fp32 (xg1p..xg1r) -> weight^T fp16
//   dl  at [104Mi)   256KB fp32
//   xg1 [112Mi,+512K)
// d_out timeline: xf fp16 [0,32Mi) -> Oh fp16 (intra..ln_gate); G bf16
//   [32Mi,64Mi) (g-gemm..ln_gate); final C fp32 [0,64Mi) written by last GEMM.
// ---------------------------------------------------------------------------

typedef unsigned short u16;
typedef unsigned int u32;
typedef __bf16 bf16x8 __attribute__((ext_vector_type(8)));
typedef _Float16 f16x8 __attribute__((ext_vector_type(8)));
typedef float f32x4 __attribute__((ext_vector_type(4)));

__device__ __forceinline__ u16 f2bf(float f) {
  u32 u = __float_as_uint(f);
  u32 r = (u + 0x7fffu + ((u >> 16) & 1u)) >> 16;   // RNE
  return (u16)r;
}
__device__ __forceinline__ float bf2f(u16 s) {
  return __uint_as_float(((u32)s) << 16);
}
__device__ __forceinline__ u16 f2h(float f) {
  _Float16 h = (_Float16)f;                          // RNE fp32->fp16
  return __builtin_bit_cast(u16, h);
}
__device__ __forceinline__ float h2f(u16 u) {
  return (float)__builtin_bit_cast(_Float16, u);
}

// async global->LDS, 16B/lane. LDS dest = wave-uniform base + lane*16.
__device__ __forceinline__ void load_lds16(const void* g, void* l) {
  auto gp = (const __attribute__((address_space(1))) u32*)(uintptr_t)g;
  auto lp = (__attribute__((address_space(3))) u32*)(u32)(uintptr_t)l;
  __builtin_amdgcn_global_load_lds(gp, lp, 16, 0, 0);
}
__device__ __forceinline__ bf16x8 ldf(const u16* p) { return *(const bf16x8*)p; }
__device__ __forceinline__ f16x8 ldh(const u16* p) { return *(const f16x8*)p; }

// unpack 8 interleaved (hi,lo) u16 pairs (two uint4) -> hi/lo bf16x8 vectors
__device__ __forceinline__ void unpk(uint4 w0, uint4 w1, bf16x8& hi, bf16x8& lo) {
  union U { uint4 u; bf16x8 v; } a, b;
  a.u.x = __builtin_amdgcn_perm(w0.y, w0.x, 0x05040100u);
  a.u.y = __builtin_amdgcn_perm(w0.w, w0.z, 0x05040100u);
  a.u.z = __builtin_amdgcn_perm(w1.y, w1.x, 0x05040100u);
  a.u.w = __builtin_amdgcn_perm(w1.w, w1.z, 0x05040100u);
  b.u.x = __builtin_amdgcn_perm(w0.y, w0.x, 0x07060302u);
  b.u.y = __builtin_amdgcn_perm(w0.w, w0.z, 0x07060302u);
  b.u.z = __builtin_amdgcn_perm(w1.y, w1.x, 0x07060302u);
  b.u.w = __builtin_amdgcn_perm(w1.w, w1.z, 0x07060302u);
  hi = a.v;
  lo = b.v;
}

// ---------------------------------------------------------------------------
// xcvt: x fp32 -> fp16 plane (RNE), 8 elems/thread, streaming.
__global__ __launch_bounds__(256) void xcvt(const float* __restrict__ x,
                                            u16* __restrict__ xf) {
  const size_t i = ((size_t)blockIdx.x * 256 + threadIdx.x) * 8;
  float4 a = *(const float4*)&x[i];
  float4 b = *(const float4*)&x[i + 4];
  ushort4 h0, h1;
  h0.x = f2h(a.x); h0.y = f2h(a.y); h0.z = f2h(a.z); h0.w = f2h(a.w);
  h1.x = f2h(b.x); h1.y = f2h(b.y); h1.z = f2h(b.z); h1.w = f2h(b.w);
  *(ushort4*)&xf[i] = h0;
  *(ushort4*)&xf[i + 4] = h1;
}

// ---------------------------------------------------------------------------
// xg1p: partial x@W1 over a 128-row x 128-k tile. Grid 1024 = 64 rb x 16 kb.
// No inner barriers; row = j*16 + rsub keeps rsub-groups on distinct bank
// quads (conflict-free b128). P[kb][row][col] fp32.
__global__ __launch_bounds__(256) void xg1p(const float* __restrict__ x,
                                            const float* __restrict__ W1,
                                            float* __restrict__ P) {
  __shared__ float xs[128][132];   // 67.6 KB (pad 132: rsub stride 132 -> +4 banks)
  __shared__ float w1t[16][128];   // 8 KB transposed W1 chunk
  const int tid = threadIdx.x;
  const int rb = blockIdx.x >> 4, kb = blockIdx.x & 15;
  const int r0 = rb * 128, k0 = kb * 128;
#pragma unroll
  for (int i = 0; i < 16; ++i) {
    int e = i * 256 + tid;           // float4 index, 4096 total
    int row = e >> 5, kq = e & 31;
    *(float4*)&xs[row][kq * 4] = *(const float4*)&x[(size_t)(r0 + row) * 2048 + k0 + kq * 4];
  }
#pragma unroll
  for (int i = 0; i < 8; ++i) {
    int e = i * 256 + tid;           // 2048 elems: col = e>>7, kk = e&127
    int col = e >> 7, kk = e & 127;
    w1t[col][kk] = W1[(size_t)(k0 + kk) * 16 + col];
  }
  __syncthreads();
  const int col = tid & 15, rsub = tid >> 4;   // rows rsub + 16*j, j=0..7
  float acc[8] = {};
  for (int kc = 0; kc < 128; kc += 16) {
    float w[16];
#pragma unroll
    for (int i = 0; i < 4; ++i)
      *(float4*)&w[i * 4] = *(const float4*)&w1t[col][kc + i * 4];
#pragma unroll
    for (int j = 0; j < 8; ++j) {
      const int row = j * 16 + rsub;
#pragma unroll
      for (int kk = 0; kk < 16; kk += 4) {
        float4 xv = *(const float4*)&xs[row][kc + kk];
        acc[j] += xv.x * w[kk] + xv.y * w[kk + 1] + xv.z * w[kk + 2] + xv.w * w[kk + 3];
      }
    }
  }
#pragma unroll
  for (int j = 0; j < 8; ++j)
    P[((size_t)kb * 8192 + r0 + j * 16 + rsub) * 16 + col] = acc[j];
}

// xg1r: xg1[i] = sum over 16 k-blocks of P[kb][i]
__global__ __launch_bounds__(256) void xg1r(const float* __restrict__ P,
                                            float* __restrict__ xg1) {
  const size_t i = (size_t)blockIdx.x * 256 + threadIdx.x;   // 131072 total
  float s = 0.f;
#pragma unroll
  for (int kb = 0; kb < 16; ++kb) s += P[(size_t)kb * 131072 + i];
  xg1[i] = s;
}

// ---------------------------------------------------------------------------
// weight transpose -> fp16 single plane: dst[n][k] = f2h(src[k][n] * scale)
__global__ __launch_bounds__(256) void tpose_f16(const float* __restrict__ src,
                                                 u16* __restrict__ dst,
                                                 int srcRows, int srcStride,
                                                 float scale) {
  __shared__ float tile[32][33];
  const int tx = threadIdx.x, ty = threadIdx.y;     // block (32,8)
  const int n0 = blockIdx.x * 32, k0 = blockIdx.y * 32;
#pragma unroll
  for (int j = 0; j < 4; ++j) {
    int k = k0 + ty + j * 8;
    tile[ty + j * 8][tx] = src[(size_t)k * srcStride + n0 + tx] * scale;
  }
  __syncthreads();
#pragma unroll
  for (int j = 0; j < 4; ++j) {
    int n = n0 + ty + j * 8;
    float f = tile[tx][ty + j * 8];
    dst[(size_t)n * srcRows + k0 + tx] = f2h(f);
  }
}

// ---------------------------------------------------------------------------
// fp16 GEMM: C[M,N] = A_f16[M,K] @ Bt_f16[N,K]^T. Block tile 128x256, BK=32,
// 4 waves, wave tile 64x128 (acc[4][8]): 12 frag reads / 32 MFMA per k-step.
template <int OUTF32>
__global__ __launch_bounds__(256, 2) void gemm_f16(const u16* __restrict__ A,
                                                   const u16* __restrict__ Bt,
                                                   void* __restrict__ C,
                                                   int M, int N, int K) {
  __shared__ u16 As[128 * 32];   //  8 KB
  __shared__ u16 Bs[256 * 32];   // 16 KB
  const int tid = threadIdx.x;
  const int wave = tid >> 6, lane = tid & 63;
  const int wm = wave >> 1, wn = wave & 1;
  const int qu = lane >> 4, ln = lane & 15;
  const int m0 = blockIdx.y * 128, n0 = blockIdx.x * 256;
  f32x4 acc[4][8] = {};
  for (int kt = 0; kt < K; kt += 32) {
#pragma unroll
    for (int r = 0; r < 2; ++r) {
      const int idx = r * 256 + tid;
      const int row = idx >> 2, chk = idx & 3;
      const int sc = ((chk ^ ((row >> 1) & 3)) << 3);
      load_lds16(A + (size_t)(m0 + row) * K + kt + sc, As + (size_t)idx * 8);
    }
#pragma unroll
    for (int r = 0; r < 4; ++r) {
      const int idx = r * 256 + tid;
      const int row = idx >> 2, chk = idx & 3;
      const int sc = ((chk ^ ((row >> 1) & 3)) << 3);
      load_lds16(Bt + (size_t)(n0 + row) * K + kt + sc, Bs + (size_t)idx * 8);
    }
    __syncthreads();
    f16x8 af[4], bfr[8];
#pragma unroll
    for (int t = 0; t < 4; ++t) {
      const int ia = wm * 64 + t * 16 + ln;
      af[t] = ldh(&As[ia * 32 + ((qu ^ ((ia >> 1) & 3)) << 3)]);
    }
#pragma unroll
    for (int t = 0; t < 8; ++t) {
      const int ib = wn * 128 + t * 16 + ln;
      bfr[t] = ldh(&Bs[ib * 32 + ((qu ^ ((ib >> 1) & 3)) << 3)]);
    }
#pragma unroll
    for (int ti = 0; ti < 4; ++ti)
#pragma unroll
      for (int tj = 0; tj < 8; ++tj)
        acc[ti][tj] = __builtin_amdgcn_mfma_f32_16x16x32_f16(af[ti], bfr[tj], acc[ti][tj], 0, 0, 0);
    __syncthreads();
  }
#pragma unroll
  for (int ti = 0; ti < 4; ++ti)
#pragma unroll
    for (int tj = 0; tj < 8; ++tj) {
      const int rowb = m0 + wm * 64 + ti * 16 + qu * 4;   // C/D: row=(lane>>4)*4+reg
      const int col = n0 + wn * 128 + tj * 16 + ln;       //      col=lane&15
#pragma unroll
      for (int r = 0; r < 4; ++r) {
        size_t idx = (size_t)(rowb + r) * N + col;
        if (OUTF32) ((float*)C)[idx] = acc[ti][tj][r];
        else        ((u16*)C)[idx] = f2bf(acc[ti][tj][r]);
      }
    }
}

// ---------------------------------------------------------------------------
// gla_decor: grid 512 = (b * 16 + n) * 8 + headgroup; 256 threads =
// 128 q-cols + 128 k-cols of that head. In-place interleaved hi/lo rewrite.
__global__ __launch_bounds__(256) void gla_decor(float* __restrict__ QK,
                                                 const float* __restrict__ xg1,
                                                 const float* __restrict__ W2,
                                                 const float* __restrict__ b2,
                                                 float* __restrict__ dl) {
  __shared__ float xg1s[128][16];   // 8KB
  const int tid = threadIdx.x;
  const int bi = blockIdx.x;
  const int b = bi >> 7, n = (bi >> 3) & 15, g = bi & 7;
  const int t0 = b * 2048 + n * 128;
  const bool isK = tid >= 128;
  const int ci = tid & 127;
  const int col = g * 128 + ci;            // global col 0..1023
  u32* base = (u32*)QK + (size_t)t0 * 2048 + (isK ? 1024 : 0) + col;
  float w2r[16];
#pragma unroll
  for (int k = 0; k < 16; ++k) w2r[k] = W2[k * 1024 + col];
  const float b2r = b2[col];
  for (int e = tid; e < 2048; e += 256)
    xg1s[e >> 4][e & 15] = xg1[(size_t)(t0 + (e >> 4)) * 16 + (e & 15)];
  __syncthreads();
  float acc = 0.f;
  const float sgn = isK ? -1.f : 1.f;
  for (int s = 0; s < 128; s += 16) {
    float qv[16];
#pragma unroll
    for (int j = 0; j < 16; ++j) qv[j] = __uint_as_float(base[(size_t)(s + j) * 2048]);
    u32 ov[16];
#pragma unroll
    for (int j = 0; j < 16; ++j) {
      float z = b2r;
#pragma unroll
      for (int kk = 0; kk < 16; ++kk) z += xg1s[s + j][kk] * w2r[kk];
      float gk = (fminf(z, 0.f) - log1pf(expf(-fabsf(z)))) * 0.0625f;
      acc += gk;
      float e = expf(sgn * acc);
      float v = qv[j] * e;
      u16 h = f2bf(v);
      u16 l = f2bf(v - bf2f(h));
      ov[j] = (u32)h | ((u32)l << 16);
    }
#pragma unroll
    for (int j = 0; j < 16; ++j) base[(size_t)(s + j) * 2048] = ov[j];
  }
  if (isK) dl[((size_t)(b * 8 + g) * 16 + n) * 128 + ci] = expf(acc);
}

// ---------------------------------------------------------------------------
// gla_intra: per (b,h,chunk): A = tril(QD@KE^T) (3-combo), o_intra = A@V^T
// (2-combo) -> Oh fp16. Triangle-predicated (exact zero-skips).
__global__ __launch_bounds__(256) void gla_intra(const u16* __restrict__ QKu,
                                                 const u16* __restrict__ V,
                                                 u16* __restrict__ Oh) {
  __shared__ u16 pool[39936];   // 79872 B -> 2 blocks/CU
  const int tid = threadIdx.x;
  const int bi = blockIdx.x;
  const int n = bi & 15, h = (bi >> 4) & 7, b = bi >> 7;
  const int t0 = b * 2048 + n * 128;
  const int wave = tid >> 6, lane = tid & 63;
  const int wm = wave >> 1, wn = wave & 1;
  const int qu = lane >> 4, ln = lane & 15;
  const int srow = tid >> 3, schk = tid & 7;
  const int sc = ((schk ^ (srow & 7)) << 3);   // swizzled source u16 offset
  u16* Qi = pool;
  u16* Ki = pool + 8192;
  u16* Amh = pool;
  u16* Aml = pool + 16384;
  u16* VTs = pool + 32768;
  // ---- phase A: A = QD @ KE^T  (3-combo hi/lo), upper-triangle-skipped
  const bool skipQuad = (wm == 0 && wn == 1);
  f32x4 acc[4][4] = {};
  for (int kt = 0; kt < 128; kt += 32) {
#pragma unroll
    for (int r = 0; r < 4; ++r) {
      const int row = srow + r * 32;
      const size_t gb = (size_t)(t0 + row) * 4096 + h * 256 + 2 * kt + sc;
      load_lds16(QKu + gb,        Qi + (r * 32 + wave * 8) * 64);
      load_lds16(QKu + gb + 2048, Ki + (r * 32 + wave * 8) * 64);
    }
    __syncthreads();
    if (!skipQuad) {
      bf16x8 ah[4], al[4], bh[4], bl[4];
#pragma unroll
      for (int t = 0; t < 4; ++t) {
        const int i = wm * 64 + t * 16 + ln;
        const u16* pQ = &Qi[i * 64];
        uint4 w0 = *(const uint4*)&pQ[((2 * qu) ^ (i & 7)) << 3];
        uint4 w1 = *(const uint4*)&pQ[((2 * qu + 1) ^ (i & 7)) << 3];
        unpk(w0, w1, ah[t], al[t]);
        const int j = wn * 64 + t * 16 + ln;
        const u16* pK = &Ki[j * 64];
        uint4 y0 = *(const uint4*)&pK[((2 * qu) ^ (j & 7)) << 3];
        uint4 y1 = *(const uint4*)&pK[((2 * qu + 1) ^ (j & 7)) << 3];
        unpk(y0, y1, bh[t], bl[t]);
      }
      const bool diag = (wm == wn);
#pragma unroll
      for (int ti = 0; ti < 4; ++ti)
#pragma unroll
        for (int tj = 0; tj < 4; ++tj) {
          if (diag && tj > ti) continue;
          acc[ti][tj] = __builtin_amdgcn_mfma_f32_16x16x32_bf16(ah[ti], bh[tj], acc[ti][tj], 0, 0, 0);
          acc[ti][tj] = __builtin_amdgcn_mfma_f32_16x16x32_bf16(ah[ti], bl[tj], acc[ti][tj], 0, 0, 0);
          acc[ti][tj] = __builtin_amdgcn_mfma_f32_16x16x32_bf16(al[ti], bh[tj], acc[ti][tj], 0, 0, 0);
        }
    }
    __syncthreads();
  }
  // ---- phase B: causal mask + hi/lo split -> Am (swizzled), aliases stage
#pragma unroll
  for (int ti = 0; ti < 4; ++ti)
#pragma unroll
    for (int tj = 0; tj < 4; ++tj) {
      const int ib = wm * 64 + ti * 16 + qu * 4;
      const int j = wn * 64 + tj * 16 + ln;
#pragma unroll
      for (int r = 0; r < 4; ++r) {
        const int i = ib + r;
        float v = (j <= i) ? acc[ti][tj][r] : 0.f;
        u16 hi = f2bf(v);
        const int idx = i * 128 + (j ^ ((i & 15) << 3));
        Amh[idx] = hi;
        Aml[idx] = f2bf(v - bf2f(hi));
      }
    }
  // ---- phase C: o_intra = Am @ V^T (2-combo), two dv-halves of 128
  for (int half = 0; half < 2; ++half) {
    f32x4 acc2[4][4] = {};
    for (int kt = 0; kt < 128; kt += 32) {
      __syncthreads();
      {
        const int j = tid & 31, dvg = tid >> 5;
#pragma unroll
        for (int rr = 0; rr < 2; ++rr) {
          const int dg = dvg + rr * 8;
          uint4 pv = *(const uint4*)(V + (size_t)(t0 + kt + j) * 2048 + h * 256 + half * 128 + dg * 8);
          u16* dst = VTs + (dg * 8) * 56 + j;
          dst[0]      = (u16)pv.x; dst[56]      = (u16)(pv.x >> 16);
          dst[2 * 56] = (u16)pv.y; dst[3 * 56]  = (u16)(pv.y >> 16);
          dst[4 * 56] = (u16)pv.z; dst[5 * 56]  = (u16)(pv.z >> 16);
          dst[6 * 56] = (u16)pv.w; dst[7 * 56]  = (u16)(pv.w >> 16);
        }
      }
      __syncthreads();
      bf16x8 amh[4], aml[4], bv[4];
#pragma unroll
      for (int t = 0; t < 4; ++t) {
        if (kt <= wm * 64 + t * 16 + 15) {
          const int i = wm * 64 + t * 16 + ln;
          const int cof = (kt + qu * 8) ^ ((i & 15) << 3);
          amh[t] = ldf(&Amh[i * 128 + cof]);
          aml[t] = ldf(&Aml[i * 128 + cof]);
        }
        bv[t] = ldf(&VTs[(wn * 64 + t * 16 + ln) * 56 + qu * 8]);
      }
#pragma unroll
      for (int ti = 0; ti < 4; ++ti) {
        if (kt > wm * 64 + ti * 16 + 15) continue;
#pragma unroll
        for (int tj = 0; tj < 4; ++tj) {
          acc2[ti][tj] = __builtin_amdgcn_mfma_f32_16x16x32_bf16(amh[ti], bv[tj], acc2[ti][tj], 0, 0, 0);
          acc2[ti][tj] = __builtin_amdgcn_mfma_f32_16x16x32_bf16(aml[ti], bv[tj], acc2[ti][tj], 0, 0, 0);
        }
      }
    }
#pragma unroll
    for (int ti = 0; ti < 4; ++ti)
#pragma unroll
      for (int tj = 0; tj < 4; ++tj)
#pragma unroll
        for (int r = 0; r < 4; ++r) {
          const int i = wm * 64 + ti * 16 + qu * 4 + r;
          const int col = half * 128 + wn * 64 + tj * 16 + ln;
          Oh[(size_t)(t0 + i) * 2048 + h * 256 + col] = f2h(acc2[ti][tj][r]);
        }
  }
}

// ---------------------------------------------------------------------------
// gla_w: per (b,h,chunk) parallel (512 blocks): W = KE^T @ V (2-combo on KE),
// fp32 acc, written fp16 IN PLACE over V's chunk slot.
__global__ __launch_bounds__(256) void gla_w(const u16* __restrict__ QKu,
                                             u16* __restrict__ V) {
  __shared__ u16 KTh[128 * 40];   // 10KB
  __shared__ u16 KTl[128 * 40];   // 10KB
  __shared__ u16 VT[256 * 40];    // 20KB
  const int tid = threadIdx.x;
  const int bi = blockIdx.x;
  const int c = bi & 15, h = (bi >> 4) & 7, b = bi >> 7;
  const int t0 = b * 2048 + c * 128;
  const int wave = tid >> 6, lane = tid & 63;
  const int wm = wave >> 1, wn = wave & 1;
  const int qu = lane >> 4, ln = lane & 15;
  const int t = tid & 31, dg0 = tid >> 5;
  f32x4 acc[4][8] = {};
  for (int kt = 0; kt < 128; kt += 32) {
#pragma unroll
    for (int rr = 0; rr < 2; ++rr) {
      const int dg = dg0 + rr * 8;
      const size_t gb = (size_t)(t0 + kt + t) * 4096 + 2048 + h * 256 + dg * 16;
      uint4 w0 = *(const uint4*)(QKu + gb);
      uint4 w1 = *(const uint4*)(QKu + gb + 8);
      u16* dh = KTh + (dg * 8) * 40 + t;
      u16* dL = KTl + (dg * 8) * 40 + t;
      dh[0]      = (u16)w0.x; dL[0]      = (u16)(w0.x >> 16);
      dh[40]     = (u16)w0.y; dL[40]     = (u16)(w0.y >> 16);
      dh[2 * 40] = (u16)w0.z; dL[2 * 40] = (u16)(w0.z >> 16);
      dh[3 * 40] = (u16)w0.w; dL[3 * 40] = (u16)(w0.w >> 16);
      dh[4 * 40] = (u16)w1.x; dL[4 * 40] = (u16)(w1.x >> 16);
      dh[5 * 40] = (u16)w1.y; dL[5 * 40] = (u16)(w1.y >> 16);
      dh[6 * 40] = (u16)w1.z; dL[6 * 40] = (u16)(w1.z >> 16);
      dh[7 * 40] = (u16)w1.w; dL[7 * 40] = (u16)(w1.w >> 16);
    }
#pragma unroll
    for (int rr = 0; rr < 4; ++rr) {
      const int dvg = dg0 + rr * 8;
      uint4 pv = *(const uint4*)(V + (size_t)(t0 + kt + t) * 2048 + h * 256 + dvg * 8);
      u16* dst = VT + (dvg * 8) * 40 + t;
      dst[0]      = (u16)pv.x; dst[40]     = (u16)(pv.x >> 16);
      dst[2 * 40] = (u16)pv.y; dst[3 * 40] = (u16)(pv.y >> 16);
      dst[4 * 40] = (u16)pv.z; dst[5 * 40] = (u16)(pv.z >> 16);
      dst[6 * 40] = (u16)pv.w; dst[7 * 40] = (u16)(pv.w >> 16);
    }
    __syncthreads();
    bf16x8 kh[4], kl[4], bv[8];
#pragma unroll
    for (int ti = 0; ti < 4; ++ti) {
      const int d = wm * 64 + ti * 16 + ln;
      kh[ti] = ldf(&KTh[d * 40 + qu * 8]);
      kl[ti] = ldf(&KTl[d * 40 + qu * 8]);
    }
#pragma unroll
    for (int tj = 0; tj < 8; ++tj)
      bv[tj] = ldf(&VT[(wn * 128 + tj * 16 + ln) * 40 + qu * 8]);
#pragma unroll
    for (int ti = 0; ti < 4; ++ti)
#pragma unroll
      for (int tj = 0; tj < 8; ++tj) {
        acc[ti][tj] = __builtin_amdgcn_mfma_f32_16x16x32_bf16(kh[ti], bv[tj], acc[ti][tj], 0, 0, 0);
        acc[ti][tj] = __builtin_amdgcn_mfma_f32_16x16x32_bf16(kl[ti], bv[tj], acc[ti][tj], 0, 0, 0);
      }
    __syncthreads();
  }
#pragma unroll
  for (int ti = 0; ti < 4; ++ti)
#pragma unroll
    for (int tj = 0; tj < 8; ++tj)
#pragma unroll
      for (int r = 0; r < 4; ++r) {
        const int d = wm * 64 + ti * 16 + qu * 4 + r;
        const int dv = wn * 128 + tj * 16 + ln;
        V[(size_t)(t0 + d) * 2048 + h * 256 + dv] = f2h(acc[ti][tj][r]);
      }
}

// ---------------------------------------------------------------------------
// gla_scan: serial 16-chunk scan, 256 blocks = (dv-slice 0..7)x(b,h).
// 3 barriers per chunk.
__global__ __launch_bounds__(256) void gla_scan(const u16* __restrict__ QKu,
                                                const u16* __restrict__ W,
                                                const float* __restrict__ dl,
                                                u16* __restrict__ Oh) {
  __shared__ float STf[32 * 128];     // 16KB
  __shared__ u16 STh[32 * 136];       // 8.5KB
  __shared__ u16 STl[32 * 136];
  __shared__ u16 Qi2[128 * 256];      // 64KB
  __shared__ float dls[128];
  const int tid = threadIdx.x;
  const int bi = blockIdx.x;
  const int sl = bi >> 5, g = bi & 31, b = g >> 3, h = g & 7;
  const int wave = tid >> 6, lane = tid & 63;
  const int qu = lane >> 4, ln = lane & 15;
  const int bh16 = (b * 8 + h) * 16;
  for (int e = tid; e < 4096; e += 256) STf[e] = 0.f;
  for (int c = 0; c < 16; ++c) {
    const int t0 = b * 2048 + c * 128;
    if (tid < 128) dls[tid] = dl[(size_t)(bh16 + c) * 128 + tid];
    uint2 wreg[2][2];
#pragma unroll
    for (int tj = 0; tj < 2; ++tj)
#pragma unroll
      for (int ti = 0; ti < 2; ++ti) {
        const int d = wave * 32 + tj * 16 + ln;
        const int dv = sl * 32 + ti * 16 + qu * 4;
        wreg[tj][ti] = *(const uint2*)(W + (size_t)(t0 + d) * 2048 + h * 256 + dv);
      }
    __syncthreads();   // B1
    if (c > 0) {
      for (int e = tid; e < 4096; e += 256) {
        const int row = e >> 7, col = e & 127;
        float v = STf[e];
        u16 hi = f2bf(v);
        STh[row * 136 + col] = hi;
        STl[row * 136 + col] = f2bf(v - bf2f(hi));
      }
#pragma unroll
      for (int r = 0; r < 16; ++r) {
        const int idx = r * 256 + tid;
        const int row = idx >> 5, chk = idx & 31;
        load_lds16(QKu + (size_t)(t0 + row) * 4096 + h * 256 + ((chk ^ (row & 7)) << 3),
                   Qi2 + (size_t)idx * 8);
      }
      __syncthreads();
      f32x4 aco[2][2] = {};
#pragma unroll
      for (int kt = 0; kt < 4; ++kt) {
        bf16x8 qh[2], ql[2], sh[2], slo[2];
#pragma unroll
        for (int t = 0; t < 2; ++t) {
          const int ar = wave * 32 + t * 16 + ln;
          const u16* pQ = &Qi2[ar * 256];
          uint4 w0 = *(const uint4*)&pQ[((kt * 8 + 2 * qu) ^ (ar & 7)) << 3];
          uint4 w1 = *(const uint4*)&pQ[((kt * 8 + 2 * qu + 1) ^ (ar & 7)) << 3];
          unpk(w0, w1, qh[t], ql[t]);
          const int br = t * 16 + ln;
          sh[t]  = ldf(&STh[br * 136 + kt * 32 + qu * 8]);
          slo[t] = ldf(&STl[br * 136 + kt * 32 + qu * 8]);
        }
#pragma unroll
        for (int ti = 0; ti < 2; ++ti)
#pragma unroll
          for (int tj = 0; tj < 2; ++tj) {
            aco[ti][tj] = __builtin_amdgcn_mfma_f32_16x16x32_bf16(qh[ti], sh[tj], aco[ti][tj], 0, 0, 0);
            aco[ti][tj] = __builtin_amdgcn_mfma_f32_16x16x32_bf16(qh[ti], slo[tj], aco[ti][tj], 0, 0, 0);
            aco[ti][tj] = __builtin_amdgcn_mfma_f32_16x16x32_bf16(ql[ti], sh[tj], aco[ti][tj], 0, 0, 0);
          }
      }
#pragma unroll
      for (int ti = 0; ti < 2; ++ti)
#pragma unroll
        for (int tj = 0; tj < 2; ++tj)
#pragma unroll
          for (int r = 0; r < 4; ++r) {
            const int i = wave * 32 + ti * 16 + qu * 4 + r;
            const int dv = tj * 16 + ln;
            u16* p = Oh + (size_t)(t0 + i) * 2048 + h * 256 + sl * 32 + dv;
            *p = f2h(h2f(*p) + aco[ti][tj][r]);
          }
    }
#pragma unroll
    for (int tj = 0; tj < 2; ++tj)
#pragma unroll
      for (int ti = 0; ti < 2; ++ti) {
        const int d = wave * 32 + tj * 16 + ln;
#pragma unroll
        for (int r = 0; r < 4; ++r) {
          const int dv = ti * 16 + qu * 4 + r;
          const u32 wu = (r & 2) ? wreg[tj][ti].y : wreg[tj][ti].x;
          const float wv = h2f((u16)((r & 1) ? (wu >> 16) : (wu & 0xffffu)));
          const int e = dv * 128 + d;
          STf[e] = dls[d] * (STf[e] + wv);
        }
      }
    __syncthreads();   // B4
  }
}

// ---------------------------------------------------------------------------
// LayerNorm(256) + silu(g) gate. Reads o fp16 (Oh), writes OG fp16 to ws.
__global__ __launch_bounds__(256) void ln_gate(const u16* __restrict__ O,
                                               const u16* __restrict__ G,
                                               const float* __restrict__ bg,
                                               u16* __restrict__ OG) {
  const int tglob = blockIdx.x;
  const int tid = threadIdx.x;
  const int c0 = tid << 3;
  const size_t base = (size_t)tglob * 2048 + c0;
  ushort4 oa = *(const ushort4*)&O[base];
  ushort4 ob = *(const ushort4*)&O[base + 4];
  float f0 = h2f(oa.x), f1 = h2f(oa.y), f2 = h2f(oa.z), f3 = h2f(oa.w);
  float f4 = h2f(ob.x), f5 = h2f(ob.y), f6 = h2f(ob.z), f7 = h2f(ob.w);
  float s = f0 + f1 + f2 + f3 + f4 + f5 + f6 + f7;
  float ss = f0 * f0 + f1 * f1 + f2 * f2 + f3 * f3 + f4 * f4 + f5 * f5 + f6 * f6 + f7 * f7;
#pragma unroll
  for (int off = 1; off <= 16; off <<= 1) {
    s += __shfl_xor(s, off, 64);
    ss += __shfl_xor(ss, off, 64);
  }
  const float mean = s * (1.f / 256.f);
  const float rstd = rsqrtf(ss * (1.f / 256.f) - mean * mean + 1e-5f);
  ushort4 ga = *(const ushort4*)&G[base];
  ushort4 gb4 = *(const ushort4*)&G[base + 4];
  float4 bga = *(const float4*)&bg[c0];
  float4 bgb = *(const float4*)&bg[c0 + 4];
  auto one = [&](float ov, u16 gu, float bgv) -> u16 {
    float gg = bf2f(gu) + bgv;
    return f2h((ov - mean) * rstd * (gg / (1.f + expf(-gg))));
  };
  ushort4 ra, rb;
  ra.x = one(f0, ga.x, bga.x);  ra.y = one(f1, ga.y, bga.y);
  ra.z = one(f2, ga.z, bga.z);  ra.w = one(f3, ga.w, bga.w);
  rb.x = one(f4, gb4.x, bgb.x); rb.y = one(f5, gb4.y, bgb.y);
  rb.z = one(f6, gb4.z, bgb.z); rb.w = one(f7, gb4.w, bgb.w);
  *(ushort4*)&OG[base] = ra;
  *(ushort4*)&OG[base + 4] = rb;
}

// ---------------------------------------------------------------------------
extern "C" void kernel_launch(void* const* d_in, const int* in_sizes, int n_in,
                              void* d_out, int out_size, void* d_ws, size_t ws_size,
                              hipStream_t stream) {
  (void)in_sizes; (void)n_in; (void)out_size;
  if (ws_size < 117964800ull) return;   // fail soft

  const float* x    = (const float*)d_in[0];
  const float* Wq   = (const float*)d_in[1];
  const float* Wk   = (const float*)d_in[2];
  const float* Wkg1 = (const float*)d_in[3];
  const float* Wkg2 = (const float*)d_in[4];
  const float* bkg2 = (const float*)d_in[5];
  const float* Wv   = (const float*)d_in[6];
  const float* Wg   = (const float*)d_in[7];
  const float* bg   = (const float*)d_in[8];
  const float* Wo   = (const float*)d_in[9];

  char* ws = (char*)d_ws;
  float* QK  = (float*)(ws + 0);           // 64 MiB fp32 -> interleaved decorated
  u16*   QKu = (u16*)QK;
  u16*   V   = (u16*)(ws + 67108864);      // 32 MiB bf16 v -> W fp16 (gla_w)
  u16*   Wt  = (u16*)(ws + 100663296);     //  8 MiB weight^T fp16 (serially reused)
  float* P   = (float*)(ws + 100663296);   //  8 MiB xg1 partials (before tposes)
  float* xg1 = (float*)(ws + 117440512);   // 0.5 MiB
  float* dl  = (float*)(ws + 109051904);   // 256 KiB
  u16*   OG  = (u16*)(ws + 0);             // 32 MiB OG fp16 (QK dead after scan)

  // d_out scratch: xf fp16 [0,32Mi) -> Oh fp16 (after g-gemm); G bf16 [32Mi,64Mi)
  u16* xf = (u16*)d_out;
  u16* Oh = (u16*)d_out;                   // after g-gemm (xf dead)
  u16* G  = (u16*)d_out + 16777216;

  dim3 tb(32, 8);

  xcvt<<<dim3(8192), dim3(256), 0, stream>>>(x, xf);
  xg1p<<<dim3(1024), dim3(256), 0, stream>>>(x, Wkg1, P);
  xg1r<<<dim3(512), dim3(256), 0, stream>>>(P, xg1);

  // [q|k] projection, fp32 out (Wk folded with (D/H)^-0.5 = 1/16, exact pow2)
  tpose_f16<<<dim3(32, 64), tb, 0, stream>>>(Wq, Wt,               2048, 1024, 1.0f);
  tpose_f16<<<dim3(32, 64), tb, 0, stream>>>(Wk, Wt + 1024 * 2048, 2048, 1024, 0.0625f);
  gemm_f16<1><<<dim3(8, 64), dim3(256), 0, stream>>>(xf, Wt, (void*)QK, 8192, 2048, 2048);

  // v projection, bf16 out
  tpose_f16<<<dim3(64, 64), tb, 0, stream>>>(Wv, Wt, 2048, 2048, 1.0f);
  gemm_f16<0><<<dim3(8, 64), dim3(256), 0, stream>>>(xf, Wt, (void*)V, 8192, 2048, 2048);

  // g projection, bf16 out -> G
  tpose_f16<<<dim3(64, 64), tb, 0, stream>>>(Wg, Wt, 2048, 2048, 1.0f);
  gemm_f16<0><<<dim3(8, 64), dim3(256), 0, stream>>>(xf, Wt, (void*)G, 8192, 2048, 2048);

  // chunked GLA on MFMA (xf dead from here; Oh takes its region)
  gla_decor<<<dim3(512), dim3(256), 0, stream>>>(QK, xg1, Wkg2, bkg2, dl);
  gla_intra<<<dim3(512), dim3(256), 0, stream>>>(QKu, V, Oh);
  gla_w<<<dim3(512), dim3(256), 0, stream>>>(QKu, V);          // V -> W in place
  gla_scan<<<dim3(256), dim3(256), 0, stream>>>(QKu, V, dl, Oh);
  ln_gate<<<dim3(8192), dim3(256), 0, stream>>>(Oh, G, bg, OG);

  // final projection: OG fp16 @ Wo^T fp16 -> fp32 straight into d_out
  tpose_f16<<<dim3(64, 64), tb, 0, stream>>>(Wo, Wt, 2048, 2048, 1.0f);
  gemm_f16<1><<<dim3(8, 64), dim3(256), 0, stream>>>(OG, Wt, d_out, 8192, 2048, 2048);
}

// Round 9
// 689.560 us; speedup vs baseline: 5.5673x; 1.1266x over previous
//
#include <hip/hip_runtime.h>
#include <stdint.h>

// ---------------------------------------------------------------------------
// GatedLinearAttention (b=4, T=2048, D=2048, H=8, dk=128, dv=256, CHUNK=128)
// Round: gla_decor VALU diet. R8 showed decor at 97us / VALUBusy 76% -- libm
// expf/log1pf (~40-50 inst each) + scalar RNE bf16 packing dominate. Replace
// with hardware v_exp/v_log (__expf/__logf, <=2ulp; log1p->log(1+e) loses
// <=6e-8 abs in gk, invisible under fp16 storage) and v_cvt_pk_bf16_f32 pair
// packing (lo plane absorbs any hi rounding-mode nuance). xcvt folded into
// xg1p (each x tile staged exactly once -> emit fp16 from registers).
//
// ws layout (112.5 MiB guard unchanged):
//   QK [0,64Mi)      fp32 [q | k/16] -> interleaved decorated u32 (in-place)
//                    -> OG fp16 [0,32Mi) after ln_gate
//   V  [64Mi,96Mi)   bf16 v -> W fp16 (gla_w, in-place per chunk slot)
//   Wt [96Mi,104Mi)  xg1 partials P fp32 (xg1p..xg1r) -> weight^T fp16
//   dl  at [104Mi)   256KB fp32
//   xg1 [112Mi,+512K)
// d_out timeline: xf fp16 [0,32Mi) -> Oh fp16 (intra..ln_gate); G bf16
//   [32Mi,64Mi) (g-gemm..ln_gate); final C fp32 [0,64Mi) written by last GEMM.
// ---------------------------------------------------------------------------

typedef unsigned short u16;
typedef unsigned int u32;
typedef __bf16 bf16x8 __attribute__((ext_vector_type(8)));
typedef _Float16 f16x8 __attribute__((ext_vector_type(8)));
typedef float f32x4 __attribute__((ext_vector_type(4)));

__device__ __forceinline__ u16 f2bf(float f) {
  u32 u = __float_as_uint(f);
  u32 r = (u + 0x7fffu + ((u >> 16) & 1u)) >> 16;   // RNE
  return (u16)r;
}
__device__ __forceinline__ float bf2f(u16 s) {
  return __uint_as_float(((u32)s) << 16);
}
__device__ __forceinline__ u16 f2h(float f) {
  _Float16 h = (_Float16)f;                          // RNE fp32->fp16
  return __builtin_bit_cast(u16, h);
}
__device__ __forceinline__ float h2f(u16 u) {
  return (float)__builtin_bit_cast(_Float16, u);
}

// async global->LDS, 16B/lane. LDS dest = wave-uniform base + lane*16.
__device__ __forceinline__ void load_lds16(const void* g, void* l) {
  auto gp = (const __attribute__((address_space(1))) u32*)(uintptr_t)g;
  auto lp = (__attribute__((address_space(3))) u32*)(u32)(uintptr_t)l;
  __builtin_amdgcn_global_load_lds(gp, lp, 16, 0, 0);
}
__device__ __forceinline__ bf16x8 ldf(const u16* p) { return *(const bf16x8*)p; }
__device__ __forceinline__ f16x8 ldh(const u16* p) { return *(const f16x8*)p; }

// unpack 8 interleaved (hi,lo) u16 pairs (two uint4) -> hi/lo bf16x8 vectors
__device__ __forceinline__ void unpk(uint4 w0, uint4 w1, bf16x8& hi, bf16x8& lo) {
  union U { uint4 u; bf16x8 v; } a, b;
  a.u.x = __builtin_amdgcn_perm(w0.y, w0.x, 0x05040100u);
  a.u.y = __builtin_amdgcn_perm(w0.w, w0.z, 0x05040100u);
  a.u.z = __builtin_amdgcn_perm(w1.y, w1.x, 0x05040100u);
  a.u.w = __builtin_amdgcn_perm(w1.w, w1.z, 0x05040100u);
  b.u.x = __builtin_amdgcn_perm(w0.y, w0.x, 0x07060302u);
  b.u.y = __builtin_amdgcn_perm(w0.w, w0.z, 0x07060302u);
  b.u.z = __builtin_amdgcn_perm(w1.y, w1.x, 0x07060302u);
  b.u.w = __builtin_amdgcn_perm(w1.w, w1.z, 0x07060302u);
  hi = a.v;
  lo = b.v;
}

// ---------------------------------------------------------------------------
// xg1p: partial x@W1 over a 128-row x 128-k tile. Grid 1024 = 64 rb x 16 kb.
// Also emits xf fp16 (each x element staged by exactly one block; converted
// from the load registers -> xcvt kernel eliminated). P[kb][row][col] fp32.
__global__ __launch_bounds__(256) void xg1p(const float* __restrict__ x,
                                            const float* __restrict__ W1,
                                            float* __restrict__ P,
                                            u16* __restrict__ xf) {
  __shared__ float xs[128][132];   // 67.6 KB (pad 132)
  __shared__ float w1t[16][128];   // 8 KB transposed W1 chunk
  const int tid = threadIdx.x;
  const int rb = blockIdx.x >> 4, kb = blockIdx.x & 15;
  const int r0 = rb * 128, k0 = kb * 128;
#pragma unroll
  for (int i = 0; i < 16; ++i) {
    int e = i * 256 + tid;           // float4 index, 4096 total
    int row = e >> 5, kq = e & 31;
    float4 f4 = *(const float4*)&x[(size_t)(r0 + row) * 2048 + k0 + kq * 4];
    *(float4*)&xs[row][kq * 4] = f4;
    ushort4 hq;
    hq.x = f2h(f4.x); hq.y = f2h(f4.y); hq.z = f2h(f4.z); hq.w = f2h(f4.w);
    *(ushort4*)&xf[(size_t)(r0 + row) * 2048 + k0 + kq * 4] = hq;
  }
#pragma unroll
  for (int i = 0; i < 8; ++i) {
    int e = i * 256 + tid;           // 2048 elems: col = e>>7, kk = e&127
    int col = e >> 7, kk = e & 127;
    w1t[col][kk] = W1[(size_t)(k0 + kk) * 16 + col];
  }
  __syncthreads();
  const int col = tid & 15, rsub = tid >> 4;   // rows rsub + 16*j, j=0..7
  float acc[8] = {};
  for (int kc = 0; kc < 128; kc += 16) {
    float w[16];
#pragma unroll
    for (int i = 0; i < 4; ++i)
      *(float4*)&w[i * 4] = *(const float4*)&w1t[col][kc + i * 4];
#pragma unroll
    for (int j = 0; j < 8; ++j) {
      const int row = j * 16 + rsub;
#pragma unroll
      for (int kk = 0; kk < 16; kk += 4) {
        float4 xv = *(const float4*)&xs[row][kc + kk];
        acc[j] += xv.x * w[kk] + xv.y * w[kk + 1] + xv.z * w[kk + 2] + xv.w * w[kk + 3];
      }
    }
  }
#pragma unroll
  for (int j = 0; j < 8; ++j)
    P[((size_t)kb * 8192 + r0 + j * 16 + rsub) * 16 + col] = acc[j];
}

// xg1r: xg1[i] = sum over 16 k-blocks of P[kb][i]
__global__ __launch_bounds__(256) void xg1r(const float* __restrict__ P,
                                            float* __restrict__ xg1) {
  const size_t i = (size_t)blockIdx.x * 256 + threadIdx.x;   // 131072 total
  float s = 0.f;
#pragma unroll
  for (int kb = 0; kb < 16; ++kb) s += P[(size_t)kb * 131072 + i];
  xg1[i] = s;
}

// ---------------------------------------------------------------------------
// weight transpose -> fp16 single plane: dst[n][k] = f2h(src[k][n] * scale)
__global__ __launch_bounds__(256) void tpose_f16(const float* __restrict__ src,
                                                 u16* __restrict__ dst,
                                                 int srcRows, int srcStride,
                                                 float scale) {
  __shared__ float tile[32][33];
  const int tx = threadIdx.x, ty = threadIdx.y;     // block (32,8)
  const int n0 = blockIdx.x * 32, k0 = blockIdx.y * 32;
#pragma unroll
  for (int j = 0; j < 4; ++j) {
    int k = k0 + ty + j * 8;
    tile[ty + j * 8][tx] = src[(size_t)k * srcStride + n0 + tx] * scale;
  }
  __syncthreads();
#pragma unroll
  for (int j = 0; j < 4; ++j) {
    int n = n0 + ty + j * 8;
    float f = tile[tx][ty + j * 8];
    dst[(size_t)n * srcRows + k0 + tx] = f2h(f);
  }
}

// ---------------------------------------------------------------------------
// fp16 GEMM: C[M,N] = A_f16[M,K] @ Bt_f16[N,K]^T. Block tile 128x256, BK=32,
// 4 waves, wave tile 64x128 (acc[4][8]): 12 frag reads / 32 MFMA per k-step.
template <int OUTF32>
__global__ __launch_bounds__(256, 2) void gemm_f16(const u16* __restrict__ A,
                                                   const u16* __restrict__ Bt,
                                                   void* __restrict__ C,
                                                   int M, int N, int K) {
  __shared__ u16 As[128 * 32];   //  8 KB
  __shared__ u16 Bs[256 * 32];   // 16 KB
  const int tid = threadIdx.x;
  const int wave = tid >> 6, lane = tid & 63;
  const int wm = wave >> 1, wn = wave & 1;
  const int qu = lane >> 4, ln = lane & 15;
  const int m0 = blockIdx.y * 128, n0 = blockIdx.x * 256;
  f32x4 acc[4][8] = {};
  for (int kt = 0; kt < K; kt += 32) {
#pragma unroll
    for (int r = 0; r < 2; ++r) {
      const int idx = r * 256 + tid;
      const int row = idx >> 2, chk = idx & 3;
      const int sc = ((chk ^ ((row >> 1) & 3)) << 3);
      load_lds16(A + (size_t)(m0 + row) * K + kt + sc, As + (size_t)idx * 8);
    }
#pragma unroll
    for (int r = 0; r < 4; ++r) {
      const int idx = r * 256 + tid;
      const int row = idx >> 2, chk = idx & 3;
      const int sc = ((chk ^ ((row >> 1) & 3)) << 3);
      load_lds16(Bt + (size_t)(n0 + row) * K + kt + sc, Bs + (size_t)idx * 8);
    }
    __syncthreads();
    f16x8 af[4], bfr[8];
#pragma unroll
    for (int t = 0; t < 4; ++t) {
      const int ia = wm * 64 + t * 16 + ln;
      af[t] = ldh(&As[ia * 32 + ((qu ^ ((ia >> 1) & 3)) << 3)]);
    }
#pragma unroll
    for (int t = 0; t < 8; ++t) {
      const int ib = wn * 128 + t * 16 + ln;
      bfr[t] = ldh(&Bs[ib * 32 + ((qu ^ ((ib >> 1) & 3)) << 3)]);
    }
#pragma unroll
    for (int ti = 0; ti < 4; ++ti)
#pragma unroll
      for (int tj = 0; tj < 8; ++tj)
        acc[ti][tj] = __builtin_amdgcn_mfma_f32_16x16x32_f16(af[ti], bfr[tj], acc[ti][tj], 0, 0, 0);
    __syncthreads();
  }
#pragma unroll
  for (int ti = 0; ti < 4; ++ti)
#pragma unroll
    for (int tj = 0; tj < 8; ++tj) {
      const int rowb = m0 + wm * 64 + ti * 16 + qu * 4;   // C/D: row=(lane>>4)*4+reg
      const int col = n0 + wn * 128 + tj * 16 + ln;       //      col=lane&15
#pragma unroll
      for (int r = 0; r < 4; ++r) {
        size_t idx = (size_t)(rowb + r) * N + col;
        if (OUTF32) ((float*)C)[idx] = acc[ti][tj][r];
        else        ((u16*)C)[idx] = f2bf(acc[ti][tj][r]);
      }
    }
}

// ---------------------------------------------------------------------------
// gla_decor: grid 512 = (b * 16 + n) * 8 + headgroup; 256 threads =
// 128 q-cols + 128 k-cols of that head. In-place interleaved hi/lo rewrite.
// Hardware transcendentals (v_exp/v_log) + v_cvt_pk_bf16_f32 pair packing.
__global__ __launch_bounds__(256) void gla_decor(float* __restrict__ QK,
                                                 const float* __restrict__ xg1,
                                                 const float* __restrict__ W2,
                                                 const float* __restrict__ b2,
                                                 float* __restrict__ dl) {
  __shared__ float xg1s[128][16];   // 8KB
  const int tid = threadIdx.x;
  const int bi = blockIdx.x;
  const int b = bi >> 7, n = (bi >> 3) & 15, g = bi & 7;
  const int t0 = b * 2048 + n * 128;
  const bool isK = tid >= 128;
  const int ci = tid & 127;
  const int col = g * 128 + ci;            // global col 0..1023
  u32* base = (u32*)QK + (size_t)t0 * 2048 + (isK ? 1024 : 0) + col;
  float w2r[16];
#pragma unroll
  for (int k = 0; k < 16; ++k) w2r[k] = W2[k * 1024 + col];
  const float b2r = b2[col];
  for (int e = tid; e < 2048; e += 256)
    xg1s[e >> 4][e & 15] = xg1[(size_t)(t0 + (e >> 4)) * 16 + (e & 15)];
  __syncthreads();
  float acc = 0.f;
  const float sgn = isK ? -1.f : 1.f;
  for (int s = 0; s < 128; s += 16) {
    float qv[16];
#pragma unroll
    for (int j = 0; j < 16; ++j) qv[j] = __uint_as_float(base[(size_t)(s + j) * 2048]);
    float vv[16];
#pragma unroll
    for (int j = 0; j < 16; ++j) {
      float z = b2r;
#pragma unroll
      for (int kk = 0; kk < 16; ++kk) z += xg1s[s + j][kk] * w2r[kk];
      // log_sigmoid via hw exp/log: err <= ~1e-7, invisible under fp16 storage
      float ls = fminf(z, 0.f) - __logf(1.f + __expf(-fabsf(z)));
      acc += ls * 0.0625f;
      vv[j] = qv[j] * __expf(sgn * acc);
    }
    u32 ov[16];
#pragma unroll
    for (int j = 0; j < 16; j += 2) {
      u32 hp, lp;
      asm("v_cvt_pk_bf16_f32 %0, %1, %2" : "=v"(hp) : "v"(vv[j]), "v"(vv[j + 1]));
      float l0 = vv[j]     - __uint_as_float(hp << 16);
      float l1 = vv[j + 1] - __uint_as_float(hp & 0xffff0000u);
      asm("v_cvt_pk_bf16_f32 %0, %1, %2" : "=v"(lp) : "v"(l0), "v"(l1));
      ov[j]     = __builtin_amdgcn_perm(lp, hp, 0x05040100u);   // h0 | l0<<16
      ov[j + 1] = __builtin_amdgcn_perm(lp, hp, 0x07060302u);   // h1 | l1<<16
    }
#pragma unroll
    for (int j = 0; j < 16; ++j) base[(size_t)(s + j) * 2048] = ov[j];
  }
  if (isK) dl[((size_t)(b * 8 + g) * 16 + n) * 128 + ci] = __expf(acc);
}

// ---------------------------------------------------------------------------
// gla_intra: per (b,h,chunk): A = tril(QD@KE^T) (3-combo), o_intra = A@V^T
// (2-combo) -> Oh fp16. Triangle-predicated (exact zero-skips).
__global__ __launch_bounds__(256) void gla_intra(const u16* __restrict__ QKu,
                                                 const u16* __restrict__ V,
                                                 u16* __restrict__ Oh) {
  __shared__ u16 pool[39936];   // 79872 B -> 2 blocks/CU
  const int tid = threadIdx.x;
  const int bi = blockIdx.x;
  const int n = bi & 15, h = (bi >> 4) & 7, b = bi >> 7;
  const int t0 = b * 2048 + n * 128;
  const int wave = tid >> 6, lane = tid & 63;
  const int wm = wave >> 1, wn = wave & 1;
  const int qu = lane >> 4, ln = lane & 15;
  const int srow = tid >> 3, schk = tid & 7;
  const int sc = ((schk ^ (srow & 7)) << 3);   // swizzled source u16 offset
  u16* Qi = pool;
  u16* Ki = pool + 8192;
  u16* Amh = pool;
  u16* Aml = pool + 16384;
  u16* VTs = pool + 32768;
  // ---- phase A: A = QD @ KE^T  (3-combo hi/lo), upper-triangle-skipped
  const bool skipQuad = (wm == 0 && wn == 1);
  f32x4 acc[4][4] = {};
  for (int kt = 0; kt < 128; kt += 32) {
#pragma unroll
    for (int r = 0; r < 4; ++r) {
      const int row = srow + r * 32;
      const size_t gb = (size_t)(t0 + row) * 4096 + h * 256 + 2 * kt + sc;
      load_lds16(QKu + gb,        Qi + (r * 32 + wave * 8) * 64);
      load_lds16(QKu + gb + 2048, Ki + (r * 32 + wave * 8) * 64);
    }
    __syncthreads();
    if (!skipQuad) {
      bf16x8 ah[4], al[4], bh[4], bl[4];
#pragma unroll
      for (int t = 0; t < 4; ++t) {
        const int i = wm * 64 + t * 16 + ln;
        const u16* pQ = &Qi[i * 64];
        uint4 w0 = *(const uint4*)&pQ[((2 * qu) ^ (i & 7)) << 3];
        uint4 w1 = *(const uint4*)&pQ[((2 * qu + 1) ^ (i & 7)) << 3];
        unpk(w0, w1, ah[t], al[t]);
        const int j = wn * 64 + t * 16 + ln;
        const u16* pK = &Ki[j * 64];
        uint4 y0 = *(const uint4*)&pK[((2 * qu) ^ (j & 7)) << 3];
        uint4 y1 = *(const uint4*)&pK[((2 * qu + 1) ^ (j & 7)) << 3];
        unpk(y0, y1, bh[t], bl[t]);
      }
      const bool diag = (wm == wn);
#pragma unroll
      for (int ti = 0; ti < 4; ++ti)
#pragma unroll
        for (int tj = 0; tj < 4; ++tj) {
          if (diag && tj > ti) continue;
          acc[ti][tj] = __builtin_amdgcn_mfma_f32_16x16x32_bf16(ah[ti], bh[tj], acc[ti][tj], 0, 0, 0);
          acc[ti][tj] = __builtin_amdgcn_mfma_f32_16x16x32_bf16(ah[ti], bl[tj], acc[ti][tj], 0, 0, 0);
          acc[ti][tj] = __builtin_amdgcn_mfma_f32_16x16x32_bf16(al[ti], bh[tj], acc[ti][tj], 0, 0, 0);
        }
    }
    __syncthreads();
  }
  // ---- phase B: causal mask + hi/lo split -> Am (swizzled), aliases stage
#pragma unroll
  for (int ti = 0; ti < 4; ++ti)
#pragma unroll
    for (int tj = 0; tj < 4; ++tj) {
      const int ib = wm * 64 + ti * 16 + qu * 4;
      const int j = wn * 64 + tj * 16 + ln;
#pragma unroll
      for (int r = 0; r < 4; ++r) {
        const int i = ib + r;
        float v = (j <= i) ? acc[ti][tj][r] : 0.f;
        u16 hi = f2bf(v);
        const int idx = i * 128 + (j ^ ((i & 15) << 3));
        Amh[idx] = hi;
        Aml[idx] = f2bf(v - bf2f(hi));
      }
    }
  // ---- phase C: o_intra = Am @ V^T (2-combo), two dv-halves of 128
  for (int half = 0; half < 2; ++half) {
    f32x4 acc2[4][4] = {};
    for (int kt = 0; kt < 128; kt += 32) {
      __syncthreads();
      {
        const int j = tid & 31, dvg = tid >> 5;
#pragma unroll
        for (int rr = 0; rr < 2; ++rr) {
          const int dg = dvg + rr * 8;
          uint4 pv = *(const uint4*)(V + (size_t)(t0 + kt + j) * 2048 + h * 256 + half * 128 + dg * 8);
          u16* dst = VTs + (dg * 8) * 56 + j;
          dst[0]      = (u16)pv.x; dst[56]      = (u16)(pv.x >> 16);
          dst[2 * 56] = (u16)pv.y; dst[3 * 56]  = (u16)(pv.y >> 16);
          dst[4 * 56] = (u16)pv.z; dst[5 * 56]  = (u16)(pv.z >> 16);
          dst[6 * 56] = (u16)pv.w; dst[7 * 56]  = (u16)(pv.w >> 16);
        }
      }
      __syncthreads();
      bf16x8 amh[4], aml[4], bv[4];
#pragma unroll
      for (int t = 0; t < 4; ++t) {
        if (kt <= wm * 64 + t * 16 + 15) {
          const int i = wm * 64 + t * 16 + ln;
          const int cof = (kt + qu * 8) ^ ((i & 15) << 3);
          amh[t] = ldf(&Amh[i * 128 + cof]);
          aml[t] = ldf(&Aml[i * 128 + cof]);
        }
        bv[t] = ldf(&VTs[(wn * 64 + t * 16 + ln) * 56 + qu * 8]);
      }
#pragma unroll
      for (int ti = 0; ti < 4; ++ti) {
        if (kt > wm * 64 + ti * 16 + 15) continue;
#pragma unroll
        for (int tj = 0; tj < 4; ++tj) {
          acc2[ti][tj] = __builtin_amdgcn_mfma_f32_16x16x32_bf16(amh[ti], bv[tj], acc2[ti][tj], 0, 0, 0);
          acc2[ti][tj] = __builtin_amdgcn_mfma_f32_16x16x32_bf16(aml[ti], bv[tj], acc2[ti][tj], 0, 0, 0);
        }
      }
    }
#pragma unroll
    for (int ti = 0; ti < 4; ++ti)
#pragma unroll
      for (int tj = 0; tj < 4; ++tj)
#pragma unroll
        for (int r = 0; r < 4; ++r) {
          const int i = wm * 64 + ti * 16 + qu * 4 + r;
          const int col = half * 128 + wn * 64 + tj * 16 + ln;
          Oh[(size_t)(t0 + i) * 2048 + h * 256 + col] = f2h(acc2[ti][tj][r]);
        }
  }
}

// ---------------------------------------------------------------------------
// gla_w: per (b,h,chunk) parallel (512 blocks): W = KE^T @ V (2-combo on KE),
// fp32 acc, written fp16 IN PLACE over V's chunk slot.
__global__ __launch_bounds__(256) void gla_w(const u16* __restrict__ QKu,
                                             u16* __restrict__ V) {
  __shared__ u16 KTh[128 * 40];   // 10KB
  __shared__ u16 KTl[128 * 40];   // 10KB
  __shared__ u16 VT[256 * 40];    // 20KB
  const int tid = threadIdx.x;
  const int bi = blockIdx.x;
  const int c = bi & 15, h = (bi >> 4) & 7, b = bi >> 7;
  const int t0 = b * 2048 + c * 128;
  const int wave = tid >> 6, lane = tid & 63;
  const int wm = wave >> 1, wn = wave & 1;
  const int qu = lane >> 4, ln = lane & 15;
  const int t = tid & 31, dg0 = tid >> 5;
  f32x4 acc[4][8] = {};
  for (int kt = 0; kt < 128; kt += 32) {
#pragma unroll
    for (int rr = 0; rr < 2; ++rr) {
      const int dg = dg0 + rr * 8;
      const size_t gb = (size_t)(t0 + kt + t) * 4096 + 2048 + h * 256 + dg * 16;
      uint4 w0 = *(const uint4*)(QKu + gb);
      uint4 w1 = *(const uint4*)(QKu + gb + 8);
      u16* dh = KTh + (dg * 8) * 40 + t;
      u16* dL = KTl + (dg * 8) * 40 + t;
      dh[0]      = (u16)w0.x; dL[0]      = (u16)(w0.x >> 16);
      dh[40]     = (u16)w0.y; dL[40]     = (u16)(w0.y >> 16);
      dh[2 * 40] = (u16)w0.z; dL[2 * 40] = (u16)(w0.z >> 16);
      dh[3 * 40] = (u16)w0.w; dL[3 * 40] = (u16)(w0.w >> 16);
      dh[4 * 40] = (u16)w1.x; dL[4 * 40] = (u16)(w1.x >> 16);
      dh[5 * 40] = (u16)w1.y; dL[5 * 40] = (u16)(w1.y >> 16);
      dh[6 * 40] = (u16)w1.z; dL[6 * 40] = (u16)(w1.z >> 16);
      dh[7 * 40] = (u16)w1.w; dL[7 * 40] = (u16)(w1.w >> 16);
    }
#pragma unroll
    for (int rr = 0; rr < 4; ++rr) {
      const int dvg = dg0 + rr * 8;
      uint4 pv = *(const uint4*)(V + (size_t)(t0 + kt + t) * 2048 + h * 256 + dvg * 8);
      u16* dst = VT + (dvg * 8) * 40 + t;
      dst[0]      = (u16)pv.x; dst[40]     = (u16)(pv.x >> 16);
      dst[2 * 40] = (u16)pv.y; dst[3 * 40] = (u16)(pv.y >> 16);
      dst[4 * 40] = (u16)pv.z; dst[5 * 40] = (u16)(pv.z >> 16);
      dst[6 * 40] = (u16)pv.w; dst[7 * 40] = (u16)(pv.w >> 16);
    }
    __syncthreads();
    bf16x8 kh[4], kl[4], bv[8];
#pragma unroll
    for (int ti = 0; ti < 4; ++ti) {
      const int d = wm * 64 + ti * 16 + ln;
      kh[ti] = ldf(&KTh[d * 40 + qu * 8]);
      kl[ti] = ldf(&KTl[d * 40 + qu * 8]);
    }
#pragma unroll
    for (int tj = 0; tj < 8; ++tj)
      bv[tj] = ldf(&VT[(wn * 128 + tj * 16 + ln) * 40 + qu * 8]);
#pragma unroll
    for (int ti = 0; ti < 4; ++ti)
#pragma unroll
      for (int tj = 0; tj < 8; ++tj) {
        acc[ti][tj] = __builtin_amdgcn_mfma_f32_16x16x32_bf16(kh[ti], bv[tj], acc[ti][tj], 0, 0, 0);
        acc[ti][tj] = __builtin_amdgcn_mfma_f32_16x16x32_bf16(kl[ti], bv[tj], acc[ti][tj], 0, 0, 0);
      }
    __syncthreads();
  }
#pragma unroll
  for (int ti = 0; ti < 4; ++ti)
#pragma unroll
    for (int tj = 0; tj < 8; ++tj)
#pragma unroll
      for (int r = 0; r < 4; ++r) {
        const int d = wm * 64 + ti * 16 + qu * 4 + r;
        const int dv = wn * 128 + tj * 16 + ln;
        V[(size_t)(t0 + d) * 2048 + h * 256 + dv] = f2h(acc[ti][tj][r]);
      }
}

// ---------------------------------------------------------------------------
// gla_scan: serial 16-chunk scan, 256 blocks = (dv-slice 0..7)x(b,h).
// 3 barriers per chunk.
__global__ __launch_bounds__(256) void gla_scan(const u16* __restrict__ QKu,
                                                const u16* __restrict__ W,
                                                const float* __restrict__ dl,
                                                u16* __restrict__ Oh) {
  __shared__ float STf[32 * 128];     // 16KB
  __shared__ u16 STh[32 * 136];       // 8.5KB
  __shared__ u16 STl[32 * 136];
  __shared__ u16 Qi2[128 * 256];      // 64KB
  __shared__ float dls[128];
  const int tid = threadIdx.x;
  const int bi = blockIdx.x;
  const int sl = bi >> 5, g = bi & 31, b = g >> 3, h = g & 7;
  const int wave = tid >> 6, lane = tid & 63;
  const int qu = lane >> 4, ln = lane & 15;
  const int bh16 = (b * 8 + h) * 16;
  for (int e = tid; e < 4096; e += 256) STf[e] = 0.f;
  for (int c = 0; c < 16; ++c) {
    const int t0 = b * 2048 + c * 128;
    if (tid < 128) dls[tid] = dl[(size_t)(bh16 + c) * 128 + tid];
    uint2 wreg[2][2];
#pragma unroll
    for (int tj = 0; tj < 2; ++tj)
#pragma unroll
      for (int ti = 0; ti < 2; ++ti) {
        const int d = wave * 32 + tj * 16 + ln;
        const int dv = sl * 32 + ti * 16 + qu * 4;
        wreg[tj][ti] = *(const uint2*)(W + (size_t)(t0 + d) * 2048 + h * 256 + dv);
      }
    __syncthreads();   // B1
    if (c > 0) {
      for (int e = tid; e < 4096; e += 256) {
        const int row = e >> 7, col = e & 127;
        float v = STf[e];
        u16 hi = f2bf(v);
        STh[row * 136 + col] = hi;
        STl[row * 136 + col] = f2bf(v - bf2f(hi));
      }
#pragma unroll
      for (int r = 0; r < 16; ++r) {
        const int idx = r * 256 + tid;
        const int row = idx >> 5, chk = idx & 31;
        load_lds16(QKu + (size_t)(t0 + row) * 4096 + h * 256 + ((chk ^ (row & 7)) << 3),
                   Qi2 + (size_t)idx * 8);
      }
      __syncthreads();
      f32x4 aco[2][2] = {};
#pragma unroll
      for (int kt = 0; kt < 4; ++kt) {
        bf16x8 qh[2], ql[2], sh[2], slo[2];
#pragma unroll
        for (int t = 0; t < 2; ++t) {
          const int ar = wave * 32 + t * 16 + ln;
          const u16* pQ = &Qi2[ar * 256];
          uint4 w0 = *(const uint4*)&pQ[((kt * 8 + 2 * qu) ^ (ar & 7)) << 3];
          uint4 w1 = *(const uint4*)&pQ[((kt * 8 + 2 * qu + 1) ^ (ar & 7)) << 3];
          unpk(w0, w1, qh[t], ql[t]);
          const int br = t * 16 + ln;
          sh[t]  = ldf(&STh[br * 136 + kt * 32 + qu * 8]);
          slo[t] = ldf(&STl[br * 136 + kt * 32 + qu * 8]);
        }
#pragma unroll
        for (int ti = 0; ti < 2; ++ti)
#pragma unroll
          for (int tj = 0; tj < 2; ++tj) {
            aco[ti][tj] = __builtin_amdgcn_mfma_f32_16x16x32_bf16(qh[ti], sh[tj], aco[ti][tj], 0, 0, 0);
            aco[ti][tj] = __builtin_amdgcn_mfma_f32_16x16x32_bf16(qh[ti], slo[tj], aco[ti][tj], 0, 0, 0);
            aco[ti][tj] = __builtin_amdgcn_mfma_f32_16x16x32_bf16(ql[ti], sh[tj], aco[ti][tj], 0, 0, 0);
          }
      }
#pragma unroll
      for (int ti = 0; ti < 2; ++ti)
#pragma unroll
        for (int tj = 0; tj < 2; ++tj)
#pragma unroll
          for (int r = 0; r < 4; ++r) {
            const int i = wave * 32 + ti * 16 + qu * 4 + r;
            const int dv = tj * 16 + ln;
            u16* p = Oh + (size_t)(t0 + i) * 2048 + h * 256 + sl * 32 + dv;
            *p = f2h(h2f(*p) + aco[ti][tj][r]);
          }
    }
#pragma unroll
    for (int tj = 0; tj < 2; ++tj)
#pragma unroll
      for (int ti = 0; ti < 2; ++ti) {
        const int d = wave * 32 + tj * 16 + ln;
#pragma unroll
        for (int r = 0; r < 4; ++r) {
          const int dv = ti * 16 + qu * 4 + r;
          const u32 wu = (r & 2) ? wreg[tj][ti].y : wreg[tj][ti].x;
          const float wv = h2f((u16)((r & 1) ? (wu >> 16) : (wu & 0xffffu)));
          const int e = dv * 128 + d;
          STf[e] = dls[d] * (STf[e] + wv);
        }
      }
    __syncthreads();   // B4
  }
}

// ---------------------------------------------------------------------------
// LayerNorm(256) + silu(g) gate. Reads o fp16 (Oh), writes OG fp16 to ws.
__global__ __launch_bounds__(256) void ln_gate(const u16* __restrict__ O,
                                               const u16* __restrict__ G,
                                               const float* __restrict__ bg,
                                               u16* __restrict__ OG) {
  const int tglob = blockIdx.x;
  const int tid = threadIdx.x;
  const int c0 = tid << 3;
  const size_t base = (size_t)tglob * 2048 + c0;
  ushort4 oa = *(const ushort4*)&O[base];
  ushort4 ob = *(const ushort4*)&O[base + 4];
  float f0 = h2f(oa.x), f1 = h2f(oa.y), f2 = h2f(oa.z), f3 = h2f(oa.w);
  float f4 = h2f(ob.x), f5 = h2f(ob.y), f6 = h2f(ob.z), f7 = h2f(ob.w);
  float s = f0 + f1 + f2 + f3 + f4 + f5 + f6 + f7;
  float ss = f0 * f0 + f1 * f1 + f2 * f2 + f3 * f3 + f4 * f4 + f5 * f5 + f6 * f6 + f7 * f7;
#pragma unroll
  for (int off = 1; off <= 16; off <<= 1) {
    s += __shfl_xor(s, off, 64);
    ss += __shfl_xor(ss, off, 64);
  }
  const float mean = s * (1.f / 256.f);
  const float rstd = rsqrtf(ss * (1.f / 256.f) - mean * mean + 1e-5f);
  ushort4 ga = *(const ushort4*)&G[base];
  ushort4 gb4 = *(const ushort4*)&G[base + 4];
  float4 bga = *(const float4*)&bg[c0];
  float4 bgb = *(const float4*)&bg[c0 + 4];
  auto one = [&](float ov, u16 gu, float bgv) -> u16 {
    float gg = bf2f(gu) + bgv;
    return f2h((ov - mean) * rstd * (gg / (1.f + __expf(-gg))));
  };
  ushort4 ra, rb;
  ra.x = one(f0, ga.x, bga.x);  ra.y = one(f1, ga.y, bga.y);
  ra.z = one(f2, ga.z, bga.z);  ra.w = one(f3, ga.w, bga.w);
  rb.x = one(f4, gb4.x, bgb.x); rb.y = one(f5, gb4.y, bgb.y);
  rb.z = one(f6, gb4.z, bgb.z); rb.w = one(f7, gb4.w, bgb.w);
  *(ushort4*)&OG[base] = ra;
  *(ushort4*)&OG[base + 4] = rb;
}

// ---------------------------------------------------------------------------
extern "C" void kernel_launch(void* const* d_in, const int* in_sizes, int n_in,
                              void* d_out, int out_size, void* d_ws, size_t ws_size,
                              hipStream_t stream) {
  (void)in_sizes; (void)n_in; (void)out_size;
  if (ws_size < 117964800ull) return;   // fail soft

  const float* x    = (const float*)d_in[0];
  const float* Wq   = (const float*)d_in[1];
  const float* Wk   = (const float*)d_in[2];
  const float* Wkg1 = (const float*)d_in[3];
  const float* Wkg2 = (const float*)d_in[4];
  const float* bkg2 = (const float*)d_in[5];
  const float* Wv   = (const float*)d_in[6];
  const float* Wg   = (const float*)d_in[7];
  const float* bg   = (const float*)d_in[8];
  const float* Wo   = (const float*)d_in[9];

  char* ws = (char*)d_ws;
  float* QK  = (float*)(ws + 0);           // 64 MiB fp32 -> interleaved decorated
  u16*   QKu = (u16*)QK;
  u16*   V   = (u16*)(ws + 67108864);      // 32 MiB bf16 v -> W fp16 (gla_w)
  u16*   Wt  = (u16*)(ws + 100663296);     //  8 MiB weight^T fp16 (serially reused)
  float* P   = (float*)(ws + 100663296);   //  8 MiB xg1 partials (before tposes)
  float* xg1 = (float*)(ws + 117440512);   // 0.5 MiB
  float* dl  = (float*)(ws + 109051904);   // 256 KiB
  u16*   OG  = (u16*)(ws + 0);             // 32 MiB OG fp16 (QK dead after scan)

  // d_out scratch: xf fp16 [0,32Mi) -> Oh fp16 (after g-gemm); G bf16 [32Mi,64Mi)
  u16* xf = (u16*)d_out;
  u16* Oh = (u16*)d_out;                   // after g-gemm (xf dead)
  u16* G  = (u16*)d_out + 16777216;

  dim3 tb(32, 8);

  xg1p<<<dim3(1024), dim3(256), 0, stream>>>(x, Wkg1, P, xf);
  xg1r<<<dim3(512), dim3(256), 0, stream>>>(P, xg1);

  // [q|k] projection, fp32 out (Wk folded with (D/H)^-0.5 = 1/16, exact pow2)
  tpose_f16<<<dim3(32, 64), tb, 0, stream>>>(Wq, Wt,               2048, 1024, 1.0f);
  tpose_f16<<<dim3(32, 64), tb, 0, stream>>>(Wk, Wt + 1024 * 2048, 2048, 1024, 0.0625f);
  gemm_f16<1><<<dim3(8, 64), dim3(256), 0, stream>>>(xf, Wt, (void*)QK, 8192, 2048, 2048);

  // v projection, bf16 out
  tpose_f16<<<dim3(64, 64), tb, 0, stream>>>(Wv, Wt, 2048, 2048, 1.0f);
  gemm_f16<0><<<dim3(8, 64), dim3(256), 0, stream>>>(xf, Wt, (void*)V, 8192, 2048, 2048);

  // g projection, bf16 out -> G
  tpose_f16<<<dim3(64, 64), tb, 0, stream>>>(Wg, Wt, 2048, 2048, 1.0f);
  gemm_f16<0><<<dim3(8, 64), dim3(256), 0, stream>>>(xf, Wt, (void*)G, 8192, 2048, 2048);

  // chunked GLA on MFMA (xf dead from here; Oh takes its region)
  gla_decor<<<dim3(512), dim3(256), 0, stream>>>(QK, xg1, Wkg2, bkg2, dl);
  gla_intra<<<dim3(512), dim3(256), 0, stream>>>(QKu, V, Oh);
  gla_w<<<dim3(512), dim3(256), 0, stream>>>(QKu, V);          // V -> W in place
  gla_scan<<<dim3(256), dim3(256), 0, stream>>>(QKu, V, dl, Oh);
  ln_gate<<<dim3(8192), dim3(256), 0, stream>>>(Oh, G, bg, OG);

  // final projection: OG fp16 @ Wo^T fp16 -> fp32 straight into d_out
  tpose_f16<<<dim3(64, 64), tb, 0, stream>>>(Wo, Wt, 2048, 2048, 1.0f);
  gemm_f16<1><<<dim3(8, 64), dim3(256), 0, stream>>>(OG, Wt, d_out, 8192, 2048, 2048);
}